// Round 7
// baseline (5499.243 us; speedup 1.0000x reference)
//
#include <hip/hip_runtime.h>
#include <math.h>

#define B_ 8
#define N_ 1024
#define D_ 512
#define BAND_ELEMS (B_ * N_ * D_)          // 4194304 = 2^22
#define OUT_MAIN (8L * BAND_ELEMS)         // 33554432
#define NCALLS 19

struct Ptrs8 { const float* p[8]; };
struct CallTab { int qi[NCALLS]; int ki[NCALLS]; };
struct MergeTab { int ncalls[8]; int calls[8][3]; int kis[NCALLS]; float wts[NCALLS]; };

typedef __attribute__((ext_vector_type(8))) short bf16x8;
typedef __attribute__((ext_vector_type(8))) ushort ushort8;
typedef __attribute__((ext_vector_type(4))) float f32x4;

// ---------------------------------------------------------------------------
// fp32 GEMM core (VERBATIM R5/R6 — bit-exact contract: sequential-k fp32 fma
// chain per output). Used ONLY for the projections now.
// ---------------------------------------------------------------------------
#define BM 128
#define BN 128
#define BK 16
#define LDP 132

__device__ __forceinline__ int bgran(int g) {
  return (g & ~7) | ((g + (g >> 3)) & 7);
}

__device__ __forceinline__ void gemm_core(const float* __restrict__ A,
                                          const float* __restrict__ Bm,
                                          int m0, int n0, int K,
                                          float (&acc)[8][8]) {
  __shared__ float As[BK * LDP];
  __shared__ float Bs[BK * LDP];

  const int t = threadIdx.x;
  const int tx = t & 15, ty = t >> 4;
  const int rs = t >> 2;
  const int cs = t & 3;

  float4 pa[2], pb[2];
#pragma unroll
  for (int it = 0; it < 2; ++it) {
    pa[it] = *(const float4*)(A + (long)(m0 + rs + 64 * it) * K + cs * 4);
    pb[it] = *(const float4*)(Bm + (long)(n0 + rs + 64 * it) * K + cs * 4);
  }

  for (int k0 = 0; k0 < K; k0 += BK) {
    __syncthreads();
    {
      const int sa = ((cs & 1) << 2);
      const int base = cs * 4 * LDP;
#pragma unroll
      for (int it = 0; it < 2; ++it) {
        const int r = rs + 64 * it;
        const int ra = r ^ sa;
        As[base + 0 * LDP + ra] = pa[it].x;
        As[base + 1 * LDP + ra] = pa[it].y;
        As[base + 2 * LDP + ra] = pa[it].z;
        As[base + 3 * LDP + ra] = pa[it].w;
        const int rb = bgran(r >> 2) * 4 + (r & 3);
        Bs[base + 0 * LDP + rb] = pb[it].x;
        Bs[base + 1 * LDP + rb] = pb[it].y;
        Bs[base + 2 * LDP + rb] = pb[it].z;
        Bs[base + 3 * LDP + rb] = pb[it].w;
      }
    }
    __syncthreads();

    if (k0 + BK < K) {
#pragma unroll
      for (int it = 0; it < 2; ++it) {
        pa[it] = *(const float4*)(A + (long)(m0 + rs + 64 * it) * K + k0 + BK + cs * 4);
        pb[it] = *(const float4*)(Bm + (long)(n0 + rs + 64 * it) * K + k0 + BK + cs * 4);
      }
    }

#pragma unroll
    for (int kk = 0; kk < BK; ++kk) {
      const int c1 = (kk >> 2) & 1;
      float a[8], b[8];
      {
        float4 u = *(const float4*)&As[kk * LDP + ty * 8 + c1 * 4];
        float4 v = *(const float4*)&As[kk * LDP + ty * 8 + 4 - c1 * 4];
        a[0] = u.x; a[1] = u.y; a[2] = u.z; a[3] = u.w;
        a[4] = v.x; a[5] = v.y; a[6] = v.z; a[7] = v.w;
        float4 p = *(const float4*)&Bs[kk * LDP + bgran(2 * tx) * 4];
        float4 q = *(const float4*)&Bs[kk * LDP + bgran(2 * tx + 1) * 4];
        b[0] = p.x; b[1] = p.y; b[2] = p.z; b[3] = p.w;
        b[4] = q.x; b[5] = q.y; b[6] = q.z; b[7] = q.w;
      }
#pragma unroll
      for (int i = 0; i < 8; ++i)
#pragma unroll
        for (int j = 0; j < 8; ++j) acc[i][j] = fmaf(a[i], b[j], acc[i][j]);
    }
  }
}

// ---- all 24 projections in one launch: z = mat*8 + band (VERBATIM R6) ------
__global__ __launch_bounds__(256) void gemm_proj_all(Ptrs8 bands,
                                                     const float* __restrict__ qW,
                                                     const float* __restrict__ kW,
                                                     const float* __restrict__ vW,
                                                     const float* __restrict__ qb,
                                                     const float* __restrict__ kb,
                                                     const float* __restrict__ vb,
                                                     float* __restrict__ Qn,
                                                     float* __restrict__ Kn,
                                                     float* __restrict__ V) {
  const int mat = blockIdx.z >> 3, band = blockIdx.z & 7;
  const float* W = (mat == 0) ? qW : (mat == 1) ? kW : vW;
  const float* bvec = (mat == 0) ? qb : (mat == 1) ? kb : vb;
  float* dst = (mat == 0) ? Qn : (mat == 1) ? Kn : V;
  W += (long)band * D_ * D_;
  bvec += band * D_;
  dst += (long)band * BAND_ELEMS;

  const int m0 = blockIdx.y * BM, n0 = blockIdx.x * BN;
  float acc[8][8] = {};
  gemm_core(bands.p[band], W, m0, n0, D_, acc);

  const int t = threadIdx.x;
  const int tx = t & 15, ty = t >> 4;
#pragma unroll
  for (int i = 0; i < 8; ++i) {
    float* crow = dst + (long)(m0 + ty * 8 + i) * D_ + n0 + tx * 8;
    const float* bp = bvec + n0 + tx * 8;
    float4 r0, r1;
    r0.x = acc[i][0] + bp[0]; r0.y = acc[i][1] + bp[1];
    r0.z = acc[i][2] + bp[2]; r0.w = acc[i][3] + bp[3];
    r1.x = acc[i][4] + bp[4]; r1.y = acc[i][5] + bp[5];
    r1.z = acc[i][6] + bp[6]; r1.w = acc[i][7] + bp[7];
    ((float4*)crow)[0] = r0;
    ((float4*)crow)[1] = r1;
  }
}

// ---- L2 normalization (VERBATIM R6) ----------------------------------------
__global__ __launch_bounds__(256) void l2norm_rows(float* __restrict__ X) {
  const long row = (long)blockIdx.x * 4 + (threadIdx.x >> 6);
  const int lane = threadIdx.x & 63;
  float* p = X + row * D_;
  float4 a = ((float4*)p)[lane];
  float4 b = ((float4*)p)[lane + 64];
  float s = a.x * a.x + a.y * a.y + a.z * a.z + a.w * a.w +
            b.x * b.x + b.y * b.y + b.z * b.z + b.w * b.w;
#pragma unroll
  for (int m = 1; m < 64; m <<= 1) s += __shfl_xor(s, m);
  const float inv = 1.0f / fmaxf(sqrtf(s), 1e-12f);
  a.x *= inv; a.y *= inv; a.z *= inv; a.w *= inv;
  b.x *= inv; b.y *= inv; b.z *= inv; b.w *= inv;
  ((float4*)p)[lane] = a;
  ((float4*)p)[lane + 64] = b;
}

// ---------------------------------------------------------------------------
// STAGE 1: bf16(hi) MFMA approx scores + per-tile top-8 candidate extraction.
// Tiles 128x128, BK=32, 4 waves, wave tile 32x128 (acc[2][8] of 16x16x32).
// A/B frag layout (validated on-device in R2): lane&15 = row/col within frag,
// lane>>4 = k-octet; C/D: col = lane&15, row = (lane>>4)*4 + reg.
// ---------------------------------------------------------------------------
#define SBM 128
#define SBN 128
#define SBK 32
#define HPAD 132   // granule-row pad per k-octet plane

__device__ __forceinline__ ushort f2bf_rne(float x) {
  uint u = __float_as_uint(x);
  return (ushort)((u + 0x7fffu + ((u >> 16) & 1u)) >> 16);
}

__global__ __launch_bounds__(256) void mfma_extract(const float* __restrict__ Qn,
                                                    const float* __restrict__ Kn,
                                                    float* __restrict__ candv,
                                                    ushort* __restrict__ candi,
                                                    CallTab tab) {
  __shared__ ushort ldsA[4 * HPAD * 8];
  __shared__ ushort ldsB[4 * HPAD * 8];

  const int z = blockIdx.z;
  const int c = z >> 3, b = z & 7;
  const float* A = Qn + (long)tab.qi[c] * BAND_ELEMS + (long)b * N_ * D_;
  const float* Bm = Kn + (long)tab.ki[c] * BAND_ELEMS + (long)b * N_ * D_;
  const int m0 = blockIdx.y * SBM, n0 = blockIdx.x * SBN;

  const int t = threadIdx.x;
  const int lane = t & 63;
  const int wm = t >> 6;                 // wave tile: rows wm*32..wm*32+31
  const int fr = lane & 15, fh = lane >> 4;

  f32x4 acc[2][8] = {};

  const int sg_r[2] = {t >> 2, (t + 256) >> 2};
  const int sg_h = t & 3;

  for (int k0 = 0; k0 < D_; k0 += SBK) {
    uint4 ga[2][2], gb[2][2];
#pragma unroll
    for (int it = 0; it < 2; ++it) {
      const float* pa = A + (long)(m0 + sg_r[it]) * D_ + k0 + sg_h * 8;
      ga[it][0] = *(const uint4*)pa;
      ga[it][1] = *(const uint4*)(pa + 4);
      const float* pb = Bm + (long)(n0 + sg_r[it]) * D_ + k0 + sg_h * 8;
      gb[it][0] = *(const uint4*)pb;
      gb[it][1] = *(const uint4*)(pb + 4);
    }
    __syncthreads();   // previous iteration done reading LDS
#pragma unroll
    for (int it = 0; it < 2; ++it) {
      uint wa[8] = {ga[it][0].x, ga[it][0].y, ga[it][0].z, ga[it][0].w,
                    ga[it][1].x, ga[it][1].y, ga[it][1].z, ga[it][1].w};
      uint wb[8] = {gb[it][0].x, gb[it][0].y, gb[it][0].z, gb[it][0].w,
                    gb[it][1].x, gb[it][1].y, gb[it][1].z, gb[it][1].w};
      ushort8 va, vb;
#pragma unroll
      for (int e = 0; e < 8; ++e) {
        va[e] = f2bf_rne(__uint_as_float(wa[e]));
        vb[e] = f2bf_rne(__uint_as_float(wb[e]));
      }
      const int dst = (sg_h * HPAD + sg_r[it]) * 8;
      *(ushort8*)&ldsA[dst] = va;
      *(ushort8*)&ldsB[dst] = vb;
    }
    __syncthreads();

    bf16x8 af[2], bf[8];
#pragma unroll
    for (int i = 0; i < 2; ++i)
      af[i] = *(const bf16x8*)&ldsA[(fh * HPAD + wm * 32 + i * 16 + fr) * 8];
#pragma unroll
    for (int j = 0; j < 8; ++j)
      bf[j] = *(const bf16x8*)&ldsB[(fh * HPAD + j * 16 + fr) * 8];

#pragma unroll
    for (int i = 0; i < 2; ++i)
#pragma unroll
      for (int j = 0; j < 8; ++j)
        acc[i][j] = __builtin_amdgcn_mfma_f32_16x16x32_bf16(af[i], bf[j], acc[i][j], 0, 0, 0);
  }

  // ---- per-tile top-8 extraction (approx values, exact (val desc, idx asc)) ----
#pragma unroll
  for (int i = 0; i < 2; ++i)
#pragma unroll
    for (int rr = 0; rr < 4; ++rr) {
      const int R = b * N_ + m0 + wm * 32 + i * 16 + fh * 4 + rr;
      const long base = (((long)c * 8192 + R) * 8 + blockIdx.x) * 8;
#pragma unroll
      for (int it = 0; it < 8; ++it) {
        float lv = acc[i][0][rr]; int lj = 0;
#pragma unroll
        for (int j = 1; j < 8; ++j)
          if (acc[i][j][rr] > lv) { lv = acc[i][j][rr]; lj = j; }
        int li = lj * 16 + fr;     // local col 0..127
#pragma unroll
        for (int m = 1; m < 16; m <<= 1) {
          float ov = __shfl_xor(lv, m);
          int oi = __shfl_xor(li, m);
          if (ov > lv || (ov == lv && oi < li)) { lv = ov; li = oi; }
        }
        if (fr == it) { candv[base + it] = lv; candi[base + it] = (ushort)(n0 + li); }
        if (fr == (li & 15)) {
#pragma unroll
          for (int j = 0; j < 8; ++j)
            if (j == (li >> 4)) acc[i][j][rr] = -INFINITY;
        }
      }
    }
}

// ---------------------------------------------------------------------------
// STAGE 2: approx-top-16 filter of 64 candidates, then EXACT fp32 dots
// (sequential-k fma chain — bit-identical to the R6 GEMM chain), top-8,
// softmax + entropy (bitwise-identical ops to the R6 merge), store finals.
// One wave per (call, row).
// ---------------------------------------------------------------------------
__global__ __launch_bounds__(256) void rerank_exact(const float* __restrict__ Qn,
                                                    const float* __restrict__ Kn,
                                                    const float* __restrict__ candv,
                                                    const ushort* __restrict__ candi,
                                                    float* __restrict__ fp,
                                                    int* __restrict__ fi,
                                                    float* __restrict__ out,
                                                    CallTab tab) {
  const int w = threadIdx.x >> 6, lane = threadIdx.x & 63;
  const long gr = (long)blockIdx.x * 4 + w;      // 0..19*8192-1
  const int c = (int)(gr >> 13);
  const int R = (int)(gr & 8191);
  const int b = R >> 10;

  const long cb = gr * 64;
  float cv = candv[cb + lane];
  int ci = (int)candi[cb + lane];

  // approx top-16 of the 64 candidates; lane (l&15)==it keeps candidate it
  int myi = 0;
#pragma unroll
  for (int it = 0; it < 16; ++it) {
    float lv = cv; int gi = ci;
#pragma unroll
    for (int m = 1; m < 64; m <<= 1) {
      float ov = __shfl_xor(lv, m);
      int oi = __shfl_xor(gi, m);
      if (ov > lv || (ov == lv && oi < gi)) { lv = ov; gi = oi; }
    }
    if ((lane & 15) == it) myi = gi;
    if (ci == gi) cv = -INFINITY;
  }

  // exact dot for candidate (lane&15): sequential-k fp32 fma chain
  const float* qrow = Qn + (long)tab.qi[c] * BAND_ELEMS + (long)R * D_;
  const float* krow = Kn + (long)tab.ki[c] * BAND_ELEMS + ((long)(b << 10) + myi) * D_;
  float acc = 0.f;
#pragma unroll 8
  for (int k = 0; k < D_; k += 4) {
    float4 qv = *(const float4*)(qrow + k);
    float4 kv = *(const float4*)(krow + k);
    acc = fmaf(qv.x, kv.x, acc);
    acc = fmaf(qv.y, kv.y, acc);
    acc = fmaf(qv.z, kv.z, acc);
    acc = fmaf(qv.w, kv.w, acc);
  }

  // top-8 by exact value (candidates duplicated 4x across lanes — retire by idx)
  float ev = acc; int ei = myi;
  float sv[8]; int si[8];
#pragma unroll
  for (int it = 0; it < 8; ++it) {
    float lv = ev; int gi = ei;
#pragma unroll
    for (int m = 1; m < 64; m <<= 1) {
      float ov = __shfl_xor(lv, m);
      int oi = __shfl_xor(gi, m);
      if (ov > lv || (ov == lv && oi < gi)) { lv = ov; gi = oi; }
    }
    sv[it] = lv; si[it] = gi;
    if (ei == gi) ev = -INFINITY;
  }

  // softmax + entropy (identical float ops to R6)
  float p[8], sum = 0.f;
#pragma unroll
  for (int j = 0; j < 8; ++j) { p[j] = expf(sv[j] - sv[0]); sum += p[j]; }
  const float isum = 1.0f / sum;
  float H = 0.f;
#pragma unroll
  for (int j = 0; j < 8; ++j) { p[j] *= isum; H -= p[j] * logf(p[j] + 1e-9f); }

  if (lane == 0) {
    atomicAdd(out + OUT_MAIN + (long)c * B_ + b, H * (1.0f / (float)N_));
#pragma unroll
    for (int j = 0; j < 8; ++j) { fp[gr * 8 + j] = p[j]; fi[gr * 8 + j] = si[j]; }
  }
}

// ---- merge finals + PV + band add + out write -------------------------------
__global__ __launch_bounds__(256) void merge_pv(Ptrs8 bands,
                                                const float* __restrict__ fp,
                                                const int* __restrict__ fi,
                                                const float* __restrict__ V,
                                                float* __restrict__ out,
                                                MergeTab mt) {
  const int bb = blockIdx.y;
  const int w = threadIdx.x >> 6, lane = threadIdx.x & 63;
  const long R = (long)blockIdx.x * 4 + w;   // 0..8191
  const int b = (int)(R >> 10);

  float4 o0 = {0, 0, 0, 0}, o1 = {0, 0, 0, 0};
  const int nc = mt.ncalls[bb];
  for (int s = 0; s < nc; ++s) {
    const int c = mt.calls[bb][s];
    const float wt = mt.wts[c];
    const int ki = mt.kis[c];
    const long fb = ((long)c * 8192 + R) * 8;
    float4 p0 = *(const float4*)(fp + fb);
    float4 p1 = *(const float4*)(fp + fb + 4);
    int4 i0 = *(const int4*)(fi + fb);
    int4 i1 = *(const int4*)(fi + fb + 4);
    float pj[8] = {p0.x, p0.y, p0.z, p0.w, p1.x, p1.y, p1.z, p1.w};
    int ij[8] = {i0.x, i0.y, i0.z, i0.w, i1.x, i1.y, i1.z, i1.w};
#pragma unroll
    for (int j = 0; j < 8; ++j) {
      const float pw = pj[j] * wt;
      const float4* vr = (const float4*)(V + (long)ki * BAND_ELEMS +
                                         ((long)(b << 10) + ij[j]) * D_);
      float4 x0 = vr[lane * 2], x1 = vr[lane * 2 + 1];
      o0.x += pw * x0.x; o0.y += pw * x0.y; o0.z += pw * x0.z; o0.w += pw * x0.w;
      o1.x += pw * x1.x; o1.y += pw * x1.y; o1.z += pw * x1.z; o1.w += pw * x1.w;
    }
  }

  const float4* src = (const float4*)(bands.p[bb] + R * D_);
  float4 s0 = src[lane * 2], s1 = src[lane * 2 + 1];
  s0.x += o0.x; s0.y += o0.y; s0.z += o0.z; s0.w += o0.w;
  s1.x += o1.x; s1.y += o1.y; s1.z += o1.z; s1.w += o1.w;
  float4* dst = (float4*)(out + (long)bb * BAND_ELEMS + R * D_);
  dst[lane * 2] = s0;
  dst[lane * 2 + 1] = s1;
}

// ---- zero the 152 entropy slots ---------------------------------------------
__global__ void init_eps(float* __restrict__ out) {
  if (threadIdx.x < NCALLS * B_) out[OUT_MAIN + threadIdx.x] = 0.f;
}

// --------------------------------------------------------------------------------
extern "C" void kernel_launch(void* const* d_in, const int* in_sizes, int n_in,
                              void* d_out, int out_size, void* d_ws, size_t ws_size,
                              hipStream_t stream) {
  Ptrs8 bands;
  for (int i = 0; i < 8; ++i) bands.p[i] = (const float*)d_in[i];
  const float* qW = (const float*)d_in[8];
  const float* qb = (const float*)d_in[9];
  const float* kW = (const float*)d_in[10];
  const float* kb = (const float*)d_in[11];
  const float* vW = (const float*)d_in[12];
  const float* vb = (const float*)d_in[13];
  float* out = (float*)d_out;
  float* ws = (float*)d_ws;

  float* Qn = ws;                                        // 134 MB
  float* Kn = ws + (long)8 * BAND_ELEMS;                 // 134 MB
  float* V  = ws + (long)16 * BAND_ELEMS;                // 134 MB
  float* candv = ws + (long)24 * BAND_ELEMS;             // 19*8192*64 f32 = 39.8 MB
  ushort* candi = (ushort*)(candv + (long)NCALLS * 8192 * 64);  // 19.9 MB
  float* fp = (float*)(candi + (long)NCALLS * 8192 * 64);       // 5 MB
  int* fi = (int*)(fp + (long)NCALLS * 8192 * 8);               // 5 MB

  static const int calls[NCALLS][2] = {
      {6, 0}, {0, 6}, {5, 1}, {1, 5}, {4, 2}, {2, 4},
      {0, 3}, {1, 3}, {2, 3}, {4, 3}, {5, 3}, {6, 3},
      {0, 7}, {1, 7}, {2, 7}, {3, 7}, {4, 7}, {5, 7}, {6, 7}};

  CallTab tab;
  MergeTab mt;
  for (int i = 0; i < 8; ++i) mt.ncalls[i] = 0;
  for (int c = 0; c < NCALLS; ++c) {
    tab.qi[c] = calls[c][0];
    tab.ki[c] = calls[c][1];
    mt.kis[c] = calls[c][1];
    mt.wts[c] = (c < 6) ? 1.0f : 0.5f;
    int q = calls[c][0];
    mt.calls[q][mt.ncalls[q]++] = c;   // ascending c == reference add order
  }

  hipLaunchKernelGGL(init_eps, dim3(1), dim3(256), 0, stream, out);

  dim3 gp(D_ / BN, (B_ * N_) / BM, 24);          // (4, 64, 24)
  hipLaunchKernelGGL(gemm_proj_all, gp, dim3(256), 0, stream,
                     bands, qW, kW, vW, qb, kb, vb, Qn, Kn, V);

  hipLaunchKernelGGL(l2norm_rows, dim3(2 * 8 * B_ * N_ / 4), dim3(256), 0, stream, Qn);

  dim3 gs(N_ / SBN, N_ / SBM, NCALLS * 8);       // (8, 8, 152)
  hipLaunchKernelGGL(mfma_extract, gs, dim3(256), 0, stream, Qn, Kn, candv, candi, tab);

  hipLaunchKernelGGL(rerank_exact, dim3(NCALLS * 8192 / 4), dim3(256), 0, stream,
                     Qn, Kn, candv, candi, fp, fi, out, tab);

  hipLaunchKernelGGL(merge_pv, dim3(B_ * N_ / 4, 8), dim3(256), 0, stream,
                     bands, fp, fi, V, out, mt);
}

// Round 8
// 4999.179 us; speedup vs baseline: 1.1000x; 1.1000x over previous
//
#include <hip/hip_runtime.h>
#include <math.h>

#define B_ 8
#define N_ 1024
#define D_ 512
#define BAND_ELEMS (B_ * N_ * D_)          // 4194304 = 2^22
#define OUT_MAIN (8L * BAND_ELEMS)         // 33554432
#define NCALLS 19

struct Ptrs8 { const float* p[8]; };
struct CallTab { int qi[NCALLS]; int ki[NCALLS]; };
struct MergeTab { int ncalls[8]; int calls[8][3]; int kis[NCALLS]; float wts[NCALLS]; };

typedef __attribute__((ext_vector_type(8))) short bf16x8;
typedef __attribute__((ext_vector_type(8))) ushort ushort8;
typedef __attribute__((ext_vector_type(4))) float f32x4;

// ---------------------------------------------------------------------------
// fp32 GEMM core (VERBATIM R5/R6 — bit-exact contract: sequential-k fp32 fma
// chain per output). Used ONLY for the projections.
// ---------------------------------------------------------------------------
#define BM 128
#define BN 128
#define BK 16
#define LDP 132

__device__ __forceinline__ int bgran(int g) {
  return (g & ~7) | ((g + (g >> 3)) & 7);
}

__device__ __forceinline__ void gemm_core(const float* __restrict__ A,
                                          const float* __restrict__ Bm,
                                          int m0, int n0, int K,
                                          float (&acc)[8][8]) {
  __shared__ float As[BK * LDP];
  __shared__ float Bs[BK * LDP];

  const int t = threadIdx.x;
  const int tx = t & 15, ty = t >> 4;
  const int rs = t >> 2;
  const int cs = t & 3;

  float4 pa[2], pb[2];
#pragma unroll
  for (int it = 0; it < 2; ++it) {
    pa[it] = *(const float4*)(A + (long)(m0 + rs + 64 * it) * K + cs * 4);
    pb[it] = *(const float4*)(Bm + (long)(n0 + rs + 64 * it) * K + cs * 4);
  }

  for (int k0 = 0; k0 < K; k0 += BK) {
    __syncthreads();
    {
      const int sa = ((cs & 1) << 2);
      const int base = cs * 4 * LDP;
#pragma unroll
      for (int it = 0; it < 2; ++it) {
        const int r = rs + 64 * it;
        const int ra = r ^ sa;
        As[base + 0 * LDP + ra] = pa[it].x;
        As[base + 1 * LDP + ra] = pa[it].y;
        As[base + 2 * LDP + ra] = pa[it].z;
        As[base + 3 * LDP + ra] = pa[it].w;
        const int rb = bgran(r >> 2) * 4 + (r & 3);
        Bs[base + 0 * LDP + rb] = pb[it].x;
        Bs[base + 1 * LDP + rb] = pb[it].y;
        Bs[base + 2 * LDP + rb] = pb[it].z;
        Bs[base + 3 * LDP + rb] = pb[it].w;
      }
    }
    __syncthreads();

    if (k0 + BK < K) {
#pragma unroll
      for (int it = 0; it < 2; ++it) {
        pa[it] = *(const float4*)(A + (long)(m0 + rs + 64 * it) * K + k0 + BK + cs * 4);
        pb[it] = *(const float4*)(Bm + (long)(n0 + rs + 64 * it) * K + k0 + BK + cs * 4);
      }
    }

#pragma unroll
    for (int kk = 0; kk < BK; ++kk) {
      const int c1 = (kk >> 2) & 1;
      float a[8], b[8];
      {
        float4 u = *(const float4*)&As[kk * LDP + ty * 8 + c1 * 4];
        float4 v = *(const float4*)&As[kk * LDP + ty * 8 + 4 - c1 * 4];
        a[0] = u.x; a[1] = u.y; a[2] = u.z; a[3] = u.w;
        a[4] = v.x; a[5] = v.y; a[6] = v.z; a[7] = v.w;
        float4 p = *(const float4*)&Bs[kk * LDP + bgran(2 * tx) * 4];
        float4 q = *(const float4*)&Bs[kk * LDP + bgran(2 * tx + 1) * 4];
        b[0] = p.x; b[1] = p.y; b[2] = p.z; b[3] = p.w;
        b[4] = q.x; b[5] = q.y; b[6] = q.z; b[7] = q.w;
      }
#pragma unroll
      for (int i = 0; i < 8; ++i)
#pragma unroll
        for (int j = 0; j < 8; ++j) acc[i][j] = fmaf(a[i], b[j], acc[i][j]);
    }
  }
}

// ---- all 24 projections in one launch: z = mat*8 + band (VERBATIM R6) ------
__global__ __launch_bounds__(256) void gemm_proj_all(Ptrs8 bands,
                                                     const float* __restrict__ qW,
                                                     const float* __restrict__ kW,
                                                     const float* __restrict__ vW,
                                                     const float* __restrict__ qb,
                                                     const float* __restrict__ kb,
                                                     const float* __restrict__ vb,
                                                     float* __restrict__ Qn,
                                                     float* __restrict__ Kn,
                                                     float* __restrict__ V) {
  const int mat = blockIdx.z >> 3, band = blockIdx.z & 7;
  const float* W = (mat == 0) ? qW : (mat == 1) ? kW : vW;
  const float* bvec = (mat == 0) ? qb : (mat == 1) ? kb : vb;
  float* dst = (mat == 0) ? Qn : (mat == 1) ? Kn : V;
  W += (long)band * D_ * D_;
  bvec += band * D_;
  dst += (long)band * BAND_ELEMS;

  const int m0 = blockIdx.y * BM, n0 = blockIdx.x * BN;
  float acc[8][8] = {};
  gemm_core(bands.p[band], W, m0, n0, D_, acc);

  const int t = threadIdx.x;
  const int tx = t & 15, ty = t >> 4;
#pragma unroll
  for (int i = 0; i < 8; ++i) {
    float* crow = dst + (long)(m0 + ty * 8 + i) * D_ + n0 + tx * 8;
    const float* bp = bvec + n0 + tx * 8;
    float4 r0, r1;
    r0.x = acc[i][0] + bp[0]; r0.y = acc[i][1] + bp[1];
    r0.z = acc[i][2] + bp[2]; r0.w = acc[i][3] + bp[3];
    r1.x = acc[i][4] + bp[4]; r1.y = acc[i][5] + bp[5];
    r1.z = acc[i][6] + bp[6]; r1.w = acc[i][7] + bp[7];
    ((float4*)crow)[0] = r0;
    ((float4*)crow)[1] = r1;
  }
}

// ---- L2 normalization (VERBATIM R6) ----------------------------------------
__global__ __launch_bounds__(256) void l2norm_rows(float* __restrict__ X) {
  const long row = (long)blockIdx.x * 4 + (threadIdx.x >> 6);
  const int lane = threadIdx.x & 63;
  float* p = X + row * D_;
  float4 a = ((float4*)p)[lane];
  float4 b = ((float4*)p)[lane + 64];
  float s = a.x * a.x + a.y * a.y + a.z * a.z + a.w * a.w +
            b.x * b.x + b.y * b.y + b.z * b.z + b.w * b.w;
#pragma unroll
  for (int m = 1; m < 64; m <<= 1) s += __shfl_xor(s, m);
  const float inv = 1.0f / fmaxf(sqrtf(s), 1e-12f);
  a.x *= inv; a.y *= inv; a.z *= inv; a.w *= inv;
  b.x *= inv; b.y *= inv; b.z *= inv; b.w *= inv;
  ((float4*)p)[lane] = a;
  ((float4*)p)[lane + 64] = b;
}

// ---------------------------------------------------------------------------
// STAGE 1: bf16(hi) MFMA approx scores + per-tile top-8 extraction (VERBATIM R7)
// ---------------------------------------------------------------------------
#define SBM 128
#define SBN 128
#define SBK 32
#define HPAD 132

__device__ __forceinline__ ushort f2bf_rne(float x) {
  uint u = __float_as_uint(x);
  return (ushort)((u + 0x7fffu + ((u >> 16) & 1u)) >> 16);
}

__global__ __launch_bounds__(256) void mfma_extract(const float* __restrict__ Qn,
                                                    const float* __restrict__ Kn,
                                                    float* __restrict__ candv,
                                                    ushort* __restrict__ candi,
                                                    CallTab tab) {
  __shared__ ushort ldsA[4 * HPAD * 8];
  __shared__ ushort ldsB[4 * HPAD * 8];

  const int z = blockIdx.z;
  const int c = z >> 3, b = z & 7;
  const float* A = Qn + (long)tab.qi[c] * BAND_ELEMS + (long)b * N_ * D_;
  const float* Bm = Kn + (long)tab.ki[c] * BAND_ELEMS + (long)b * N_ * D_;
  const int m0 = blockIdx.y * SBM, n0 = blockIdx.x * SBN;

  const int t = threadIdx.x;
  const int lane = t & 63;
  const int wm = t >> 6;
  const int fr = lane & 15, fh = lane >> 4;

  f32x4 acc[2][8] = {};

  const int sg_r[2] = {t >> 2, (t + 256) >> 2};
  const int sg_h = t & 3;

  for (int k0 = 0; k0 < D_; k0 += SBK) {
    uint4 ga[2][2], gb[2][2];
#pragma unroll
    for (int it = 0; it < 2; ++it) {
      const float* pa = A + (long)(m0 + sg_r[it]) * D_ + k0 + sg_h * 8;
      ga[it][0] = *(const uint4*)pa;
      ga[it][1] = *(const uint4*)(pa + 4);
      const float* pb = Bm + (long)(n0 + sg_r[it]) * D_ + k0 + sg_h * 8;
      gb[it][0] = *(const uint4*)pb;
      gb[it][1] = *(const uint4*)(pb + 4);
    }
    __syncthreads();
#pragma unroll
    for (int it = 0; it < 2; ++it) {
      uint wa[8] = {ga[it][0].x, ga[it][0].y, ga[it][0].z, ga[it][0].w,
                    ga[it][1].x, ga[it][1].y, ga[it][1].z, ga[it][1].w};
      uint wb[8] = {gb[it][0].x, gb[it][0].y, gb[it][0].z, gb[it][0].w,
                    gb[it][1].x, gb[it][1].y, gb[it][1].z, gb[it][1].w};
      ushort8 va, vb;
#pragma unroll
      for (int e = 0; e < 8; ++e) {
        va[e] = f2bf_rne(__uint_as_float(wa[e]));
        vb[e] = f2bf_rne(__uint_as_float(wb[e]));
      }
      const int dst = (sg_h * HPAD + sg_r[it]) * 8;
      *(ushort8*)&ldsA[dst] = va;
      *(ushort8*)&ldsB[dst] = vb;
    }
    __syncthreads();

    bf16x8 af[2], bf[8];
#pragma unroll
    for (int i = 0; i < 2; ++i)
      af[i] = *(const bf16x8*)&ldsA[(fh * HPAD + wm * 32 + i * 16 + fr) * 8];
#pragma unroll
    for (int j = 0; j < 8; ++j)
      bf[j] = *(const bf16x8*)&ldsB[(fh * HPAD + j * 16 + fr) * 8];

#pragma unroll
    for (int i = 0; i < 2; ++i)
#pragma unroll
      for (int j = 0; j < 8; ++j)
        acc[i][j] = __builtin_amdgcn_mfma_f32_16x16x32_bf16(af[i], bf[j], acc[i][j], 0, 0, 0);
  }

#pragma unroll
  for (int i = 0; i < 2; ++i)
#pragma unroll
    for (int rr = 0; rr < 4; ++rr) {
      const int R = b * N_ + m0 + wm * 32 + i * 16 + fh * 4 + rr;
      const long base = (((long)c * 8192 + R) * 8 + blockIdx.x) * 8;
#pragma unroll
      for (int it = 0; it < 8; ++it) {
        float lv = acc[i][0][rr]; int lj = 0;
#pragma unroll
        for (int j = 1; j < 8; ++j)
          if (acc[i][j][rr] > lv) { lv = acc[i][j][rr]; lj = j; }
        int li = lj * 16 + fr;
#pragma unroll
        for (int m = 1; m < 16; m <<= 1) {
          float ov = __shfl_xor(lv, m);
          int oi = __shfl_xor(li, m);
          if (ov > lv || (ov == lv && oi < li)) { lv = ov; li = oi; }
        }
        if (fr == it) { candv[base + it] = lv; candi[base + it] = (ushort)(n0 + li); }
        if (fr == (li & 15)) {
#pragma unroll
          for (int j = 0; j < 8; ++j)
            if (j == (li >> 4)) acc[i][j][rr] = -INFINITY;
        }
      }
    }
}

// ---------------------------------------------------------------------------
// STAGE 2 v2: approx-top-16 filter, then exact fp32 chains fed from LDS-staged
// candidate rows (coalesced). Chain order IDENTICAL to R7 (sequential k,
// x,y,z,w within float4) -> bit-identical dot values -> identical selection.
// One wave per (call,row), 4 waves/block. LDS: 16 rows x 68 floats per wave.
// ---------------------------------------------------------------------------
#define KROW 68   // LDS row stride (floats): 16B-aligned, 2-way banks (free)

__global__ __launch_bounds__(256) void rerank_exact(const float* __restrict__ Qn,
                                                    const float* __restrict__ Kn,
                                                    const float* __restrict__ candv,
                                                    const ushort* __restrict__ candi,
                                                    float* __restrict__ fp,
                                                    int* __restrict__ fi,
                                                    float* __restrict__ out,
                                                    CallTab tab) {
  __shared__ float kbuf[4][16 * KROW];
  __shared__ float qbuf[4][64];

  const int w = threadIdx.x >> 6, lane = threadIdx.x & 63;
  const long gr = (long)blockIdx.x * 4 + w;      // 0..19*8192-1
  const int c = (int)(gr >> 13);
  const int R = (int)(gr & 8191);
  const int b = R >> 10;

  const long cb = gr * 64;
  float cv = candv[cb + lane];
  int ci = (int)candi[cb + lane];

  // approx top-16 of the 64 candidates (comparator & retire verbatim R7)
  int myi = 0;
#pragma unroll
  for (int it = 0; it < 16; ++it) {
    float lv = cv; int gi = ci;
#pragma unroll
    for (int m = 1; m < 64; m <<= 1) {
      float ov = __shfl_xor(lv, m);
      int oi = __shfl_xor(gi, m);
      if (ov > lv || (ov == lv && oi < gi)) { lv = ov; gi = oi; }
    }
    if ((lane & 15) == it) myi = gi;
    if (ci == gi) cv = -INFINITY;
  }

  // broadcast the 16 filtered indices (lane s holds slot s for s<16)
  int idx16[16];
#pragma unroll
  for (int s = 0; s < 16; ++s) idx16[s] = __shfl(myi, s);

  const float* qrow = Qn + (long)tab.qi[c] * BAND_ELEMS + (long)R * D_;
  const float* kband = Kn + (long)tab.ki[c] * BAND_ELEMS + ((long)(b << 10)) * D_;

  const int srow = lane >> 2;          // staged row slot 0..15
  const int sqt = lane & 3;            // quarter: 16 floats each
  const float* ksrc = kband + (long)idx16[srow] * D_ + sqt * 16;
  const int mycand = lane & 15;        // candidate for this lane's chain

  // prefetch chunk 0
  float4 pk[4];
  float pq;
#pragma unroll
  for (int j = 0; j < 4; ++j) pk[j] = *(const float4*)(ksrc + j * 4);
  pq = qrow[lane];

  float acc = 0.f;
  for (int ch = 0; ch < 8; ++ch) {
    __syncthreads();   // previous chunk's readers done
    // store staged chunk
#pragma unroll
    for (int j = 0; j < 4; ++j)
      *(float4*)&kbuf[w][srow * KROW + sqt * 16 + j * 4] = pk[j];
    qbuf[w][lane] = pq;
    __syncthreads();
    // prefetch next chunk
    if (ch < 7) {
#pragma unroll
      for (int j = 0; j < 4; ++j) pk[j] = *(const float4*)(ksrc + (ch + 1) * 64 + j * 4);
      pq = qrow[(ch + 1) * 64 + lane];
    }
    // exact chain: 64 floats in order (same fmaf sequence as R7)
    const float* kr = &kbuf[w][mycand * KROW];
    const float* qc = qbuf[w];
#pragma unroll
    for (int k = 0; k < 64; k += 4) {
      float4 qv = *(const float4*)(qc + k);
      float4 kv = *(const float4*)(kr + k);
      acc = fmaf(qv.x, kv.x, acc);
      acc = fmaf(qv.y, kv.y, acc);
      acc = fmaf(qv.z, kv.z, acc);
      acc = fmaf(qv.w, kv.w, acc);
    }
  }

  // top-8 by exact value (verbatim R7: dup lanes tie exactly, retire by idx)
  float ev = acc; int ei = idx16[mycand];
  float sv[8]; int si[8];
#pragma unroll
  for (int it = 0; it < 8; ++it) {
    float lv = ev; int gi = ei;
#pragma unroll
    for (int m = 1; m < 64; m <<= 1) {
      float ov = __shfl_xor(lv, m);
      int oi = __shfl_xor(gi, m);
      if (ov > lv || (ov == lv && oi < gi)) { lv = ov; gi = oi; }
    }
    sv[it] = lv; si[it] = gi;
    if (ei == gi) ev = -INFINITY;
  }

  // softmax + entropy (verbatim R7)
  float p[8], sum = 0.f;
#pragma unroll
  for (int j = 0; j < 8; ++j) { p[j] = expf(sv[j] - sv[0]); sum += p[j]; }
  const float isum = 1.0f / sum;
  float H = 0.f;
#pragma unroll
  for (int j = 0; j < 8; ++j) { p[j] *= isum; H -= p[j] * logf(p[j] + 1e-9f); }

  if (lane == 0) {
    atomicAdd(out + OUT_MAIN + (long)c * B_ + b, H * (1.0f / (float)N_));
#pragma unroll
    for (int j = 0; j < 8; ++j) { fp[gr * 8 + j] = p[j]; fi[gr * 8 + j] = si[j]; }
  }
}

// ---- merge finals + PV + band add + out write (VERBATIM R7) -----------------
__global__ __launch_bounds__(256) void merge_pv(Ptrs8 bands,
                                                const float* __restrict__ fp,
                                                const int* __restrict__ fi,
                                                const float* __restrict__ V,
                                                float* __restrict__ out,
                                                MergeTab mt) {
  const int bb = blockIdx.y;
  const int w = threadIdx.x >> 6, lane = threadIdx.x & 63;
  const long R = (long)blockIdx.x * 4 + w;
  const int b = (int)(R >> 10);

  float4 o0 = {0, 0, 0, 0}, o1 = {0, 0, 0, 0};
  const int nc = mt.ncalls[bb];
  for (int s = 0; s < nc; ++s) {
    const int c = mt.calls[bb][s];
    const float wt = mt.wts[c];
    const int ki = mt.kis[c];
    const long fb = ((long)c * 8192 + R) * 8;
    float4 p0 = *(const float4*)(fp + fb);
    float4 p1 = *(const float4*)(fp + fb + 4);
    int4 i0 = *(const int4*)(fi + fb);
    int4 i1 = *(const int4*)(fi + fb + 4);
    float pj[8] = {p0.x, p0.y, p0.z, p0.w, p1.x, p1.y, p1.z, p1.w};
    int ij[8] = {i0.x, i0.y, i0.z, i0.w, i1.x, i1.y, i1.z, i1.w};
#pragma unroll
    for (int j = 0; j < 8; ++j) {
      const float pw = pj[j] * wt;
      const float4* vr = (const float4*)(V + (long)ki * BAND_ELEMS +
                                         ((long)(b << 10) + ij[j]) * D_);
      float4 x0 = vr[lane * 2], x1 = vr[lane * 2 + 1];
      o0.x += pw * x0.x; o0.y += pw * x0.y; o0.z += pw * x0.z; o0.w += pw * x0.w;
      o1.x += pw * x1.x; o1.y += pw * x1.y; o1.z += pw * x1.z; o1.w += pw * x1.w;
    }
  }

  const float4* src = (const float4*)(bands.p[bb] + R * D_);
  float4 s0 = src[lane * 2], s1 = src[lane * 2 + 1];
  s0.x += o0.x; s0.y += o0.y; s0.z += o0.z; s0.w += o0.w;
  s1.x += o1.x; s1.y += o1.y; s1.z += o1.z; s1.w += o1.w;
  float4* dst = (float4*)(out + (long)bb * BAND_ELEMS + R * D_);
  dst[lane * 2] = s0;
  dst[lane * 2 + 1] = s1;
}

// ---- zero the 152 entropy slots ---------------------------------------------
__global__ void init_eps(float* __restrict__ out) {
  if (threadIdx.x < NCALLS * B_) out[OUT_MAIN + threadIdx.x] = 0.f;
}

// --------------------------------------------------------------------------------
extern "C" void kernel_launch(void* const* d_in, const int* in_sizes, int n_in,
                              void* d_out, int out_size, void* d_ws, size_t ws_size,
                              hipStream_t stream) {
  Ptrs8 bands;
  for (int i = 0; i < 8; ++i) bands.p[i] = (const float*)d_in[i];
  const float* qW = (const float*)d_in[8];
  const float* qb = (const float*)d_in[9];
  const float* kW = (const float*)d_in[10];
  const float* kb = (const float*)d_in[11];
  const float* vW = (const float*)d_in[12];
  const float* vb = (const float*)d_in[13];
  float* out = (float*)d_out;
  float* ws = (float*)d_ws;

  float* Qn = ws;
  float* Kn = ws + (long)8 * BAND_ELEMS;
  float* V  = ws + (long)16 * BAND_ELEMS;
  float* candv = ws + (long)24 * BAND_ELEMS;
  ushort* candi = (ushort*)(candv + (long)NCALLS * 8192 * 64);
  float* fp = (float*)(candi + (long)NCALLS * 8192 * 64);
  int* fi = (int*)(fp + (long)NCALLS * 8192 * 8);

  static const int calls[NCALLS][2] = {
      {6, 0}, {0, 6}, {5, 1}, {1, 5}, {4, 2}, {2, 4},
      {0, 3}, {1, 3}, {2, 3}, {4, 3}, {5, 3}, {6, 3},
      {0, 7}, {1, 7}, {2, 7}, {3, 7}, {4, 7}, {5, 7}, {6, 7}};

  CallTab tab;
  MergeTab mt;
  for (int i = 0; i < 8; ++i) mt.ncalls[i] = 0;
  for (int c = 0; c < NCALLS; ++c) {
    tab.qi[c] = calls[c][0];
    tab.ki[c] = calls[c][1];
    mt.kis[c] = calls[c][1];
    mt.wts[c] = (c < 6) ? 1.0f : 0.5f;
    int q = calls[c][0];
    mt.calls[q][mt.ncalls[q]++] = c;
  }

  hipLaunchKernelGGL(init_eps, dim3(1), dim3(256), 0, stream, out);

  dim3 gp(D_ / BN, (B_ * N_) / BM, 24);
  hipLaunchKernelGGL(gemm_proj_all, gp, dim3(256), 0, stream,
                     bands, qW, kW, vW, qb, kb, vb, Qn, Kn, V);

  hipLaunchKernelGGL(l2norm_rows, dim3(2 * 8 * B_ * N_ / 4), dim3(256), 0, stream, Qn);

  dim3 gs(N_ / SBN, N_ / SBM, NCALLS * 8);
  hipLaunchKernelGGL(mfma_extract, gs, dim3(256), 0, stream, Qn, Kn, candv, candi, tab);

  hipLaunchKernelGGL(rerank_exact, dim3(NCALLS * 8192 / 4), dim3(256), 0, stream,
                     Qn, Kn, candv, candi, fp, fi, out, tab);

  hipLaunchKernelGGL(merge_pv, dim3(B_ * N_ / 4, 8), dim3(256), 0, stream,
                     bands, fp, fi, V, out, mt);
}

// Round 9
// 4785.857 us; speedup vs baseline: 1.1491x; 1.0446x over previous
//
#include <hip/hip_runtime.h>
#include <math.h>

#define B_ 8
#define N_ 1024
#define D_ 512
#define BAND_ELEMS (B_ * N_ * D_)          // 4194304 = 2^22
#define OUT_MAIN (8L * BAND_ELEMS)         // 33554432
#define NCALLS 19

struct Ptrs8 { const float* p[8]; };
struct CallTab { int qi[NCALLS]; int ki[NCALLS]; };
struct MergeTab { int ncalls[8]; int calls[8][3]; int kis[NCALLS]; float wts[NCALLS]; };

typedef __attribute__((ext_vector_type(8))) short bf16x8;
typedef __attribute__((ext_vector_type(8))) ushort ushort8;
typedef __attribute__((ext_vector_type(4))) float f32x4;

// ---------------------------------------------------------------------------
// fp32 GEMM core (VERBATIM R5/R6 — bit-exact contract: sequential-k fp32 fma
// chain per output). Used ONLY for the projections.
// ---------------------------------------------------------------------------
#define BM 128
#define BN 128
#define BK 16
#define LDP 132

__device__ __forceinline__ int bgran(int g) {
  return (g & ~7) | ((g + (g >> 3)) & 7);
}

__device__ __forceinline__ void gemm_core(const float* __restrict__ A,
                                          const float* __restrict__ Bm,
                                          int m0, int n0, int K,
                                          float (&acc)[8][8]) {
  __shared__ float As[BK * LDP];
  __shared__ float Bs[BK * LDP];

  const int t = threadIdx.x;
  const int tx = t & 15, ty = t >> 4;
  const int rs = t >> 2;
  const int cs = t & 3;

  float4 pa[2], pb[2];
#pragma unroll
  for (int it = 0; it < 2; ++it) {
    pa[it] = *(const float4*)(A + (long)(m0 + rs + 64 * it) * K + cs * 4);
    pb[it] = *(const float4*)(Bm + (long)(n0 + rs + 64 * it) * K + cs * 4);
  }

  for (int k0 = 0; k0 < K; k0 += BK) {
    __syncthreads();
    {
      const int sa = ((cs & 1) << 2);
      const int base = cs * 4 * LDP;
#pragma unroll
      for (int it = 0; it < 2; ++it) {
        const int r = rs + 64 * it;
        const int ra = r ^ sa;
        As[base + 0 * LDP + ra] = pa[it].x;
        As[base + 1 * LDP + ra] = pa[it].y;
        As[base + 2 * LDP + ra] = pa[it].z;
        As[base + 3 * LDP + ra] = pa[it].w;
        const int rb = bgran(r >> 2) * 4 + (r & 3);
        Bs[base + 0 * LDP + rb] = pb[it].x;
        Bs[base + 1 * LDP + rb] = pb[it].y;
        Bs[base + 2 * LDP + rb] = pb[it].z;
        Bs[base + 3 * LDP + rb] = pb[it].w;
      }
    }
    __syncthreads();

    if (k0 + BK < K) {
#pragma unroll
      for (int it = 0; it < 2; ++it) {
        pa[it] = *(const float4*)(A + (long)(m0 + rs + 64 * it) * K + k0 + BK + cs * 4);
        pb[it] = *(const float4*)(Bm + (long)(n0 + rs + 64 * it) * K + k0 + BK + cs * 4);
      }
    }

#pragma unroll
    for (int kk = 0; kk < BK; ++kk) {
      const int c1 = (kk >> 2) & 1;
      float a[8], b[8];
      {
        float4 u = *(const float4*)&As[kk * LDP + ty * 8 + c1 * 4];
        float4 v = *(const float4*)&As[kk * LDP + ty * 8 + 4 - c1 * 4];
        a[0] = u.x; a[1] = u.y; a[2] = u.z; a[3] = u.w;
        a[4] = v.x; a[5] = v.y; a[6] = v.z; a[7] = v.w;
        float4 p = *(const float4*)&Bs[kk * LDP + bgran(2 * tx) * 4];
        float4 q = *(const float4*)&Bs[kk * LDP + bgran(2 * tx + 1) * 4];
        b[0] = p.x; b[1] = p.y; b[2] = p.z; b[3] = p.w;
        b[4] = q.x; b[5] = q.y; b[6] = q.z; b[7] = q.w;
      }
#pragma unroll
      for (int i = 0; i < 8; ++i)
#pragma unroll
        for (int j = 0; j < 8; ++j) acc[i][j] = fmaf(a[i], b[j], acc[i][j]);
    }
  }
}

// ---- all 24 projections in one launch: z = mat*8 + band (VERBATIM R6) ------
__global__ __launch_bounds__(256) void gemm_proj_all(Ptrs8 bands,
                                                     const float* __restrict__ qW,
                                                     const float* __restrict__ kW,
                                                     const float* __restrict__ vW,
                                                     const float* __restrict__ qb,
                                                     const float* __restrict__ kb,
                                                     const float* __restrict__ vb,
                                                     float* __restrict__ Qn,
                                                     float* __restrict__ Kn,
                                                     float* __restrict__ V) {
  const int mat = blockIdx.z >> 3, band = blockIdx.z & 7;
  const float* W = (mat == 0) ? qW : (mat == 1) ? kW : vW;
  const float* bvec = (mat == 0) ? qb : (mat == 1) ? kb : vb;
  float* dst = (mat == 0) ? Qn : (mat == 1) ? Kn : V;
  W += (long)band * D_ * D_;
  bvec += band * D_;
  dst += (long)band * BAND_ELEMS;

  const int m0 = blockIdx.y * BM, n0 = blockIdx.x * BN;
  float acc[8][8] = {};
  gemm_core(bands.p[band], W, m0, n0, D_, acc);

  const int t = threadIdx.x;
  const int tx = t & 15, ty = t >> 4;
#pragma unroll
  for (int i = 0; i < 8; ++i) {
    float* crow = dst + (long)(m0 + ty * 8 + i) * D_ + n0 + tx * 8;
    const float* bp = bvec + n0 + tx * 8;
    float4 r0, r1;
    r0.x = acc[i][0] + bp[0]; r0.y = acc[i][1] + bp[1];
    r0.z = acc[i][2] + bp[2]; r0.w = acc[i][3] + bp[3];
    r1.x = acc[i][4] + bp[4]; r1.y = acc[i][5] + bp[5];
    r1.z = acc[i][6] + bp[6]; r1.w = acc[i][7] + bp[7];
    ((float4*)crow)[0] = r0;
    ((float4*)crow)[1] = r1;
  }
}

// ---- L2 normalization (VERBATIM R6) ----------------------------------------
__global__ __launch_bounds__(256) void l2norm_rows(float* __restrict__ X) {
  const long row = (long)blockIdx.x * 4 + (threadIdx.x >> 6);
  const int lane = threadIdx.x & 63;
  float* p = X + row * D_;
  float4 a = ((float4*)p)[lane];
  float4 b = ((float4*)p)[lane + 64];
  float s = a.x * a.x + a.y * a.y + a.z * a.z + a.w * a.w +
            b.x * b.x + b.y * b.y + b.z * b.z + b.w * b.w;
#pragma unroll
  for (int m = 1; m < 64; m <<= 1) s += __shfl_xor(s, m);
  const float inv = 1.0f / fmaxf(sqrtf(s), 1e-12f);
  a.x *= inv; a.y *= inv; a.z *= inv; a.w *= inv;
  b.x *= inv; b.y *= inv; b.z *= inv; b.w *= inv;
  ((float4*)p)[lane] = a;
  ((float4*)p)[lane + 64] = b;
}

// ---------------------------------------------------------------------------
// STAGE 1: bf16(hi) MFMA approx scores + per-tile top-8 extraction (VERBATIM R7)
// ---------------------------------------------------------------------------
#define SBM 128
#define SBN 128
#define SBK 32
#define HPAD 132

__device__ __forceinline__ ushort f2bf_rne(float x) {
  uint u = __float_as_uint(x);
  return (ushort)((u + 0x7fffu + ((u >> 16) & 1u)) >> 16);
}

__global__ __launch_bounds__(256) void mfma_extract(const float* __restrict__ Qn,
                                                    const float* __restrict__ Kn,
                                                    float* __restrict__ candv,
                                                    ushort* __restrict__ candi,
                                                    CallTab tab) {
  __shared__ ushort ldsA[4 * HPAD * 8];
  __shared__ ushort ldsB[4 * HPAD * 8];

  const int z = blockIdx.z;
  const int c = z >> 3, b = z & 7;
  const float* A = Qn + (long)tab.qi[c] * BAND_ELEMS + (long)b * N_ * D_;
  const float* Bm = Kn + (long)tab.ki[c] * BAND_ELEMS + (long)b * N_ * D_;
  const int m0 = blockIdx.y * SBM, n0 = blockIdx.x * SBN;

  const int t = threadIdx.x;
  const int lane = t & 63;
  const int wm = t >> 6;
  const int fr = lane & 15, fh = lane >> 4;

  f32x4 acc[2][8] = {};

  const int sg_r[2] = {t >> 2, (t + 256) >> 2};
  const int sg_h = t & 3;

  for (int k0 = 0; k0 < D_; k0 += SBK) {
    uint4 ga[2][2], gb[2][2];
#pragma unroll
    for (int it = 0; it < 2; ++it) {
      const float* pa = A + (long)(m0 + sg_r[it]) * D_ + k0 + sg_h * 8;
      ga[it][0] = *(const uint4*)pa;
      ga[it][1] = *(const uint4*)(pa + 4);
      const float* pb = Bm + (long)(n0 + sg_r[it]) * D_ + k0 + sg_h * 8;
      gb[it][0] = *(const uint4*)pb;
      gb[it][1] = *(const uint4*)(pb + 4);
    }
    __syncthreads();
#pragma unroll
    for (int it = 0; it < 2; ++it) {
      uint wa[8] = {ga[it][0].x, ga[it][0].y, ga[it][0].z, ga[it][0].w,
                    ga[it][1].x, ga[it][1].y, ga[it][1].z, ga[it][1].w};
      uint wb[8] = {gb[it][0].x, gb[it][0].y, gb[it][0].z, gb[it][0].w,
                    gb[it][1].x, gb[it][1].y, gb[it][1].z, gb[it][1].w};
      ushort8 va, vb;
#pragma unroll
      for (int e = 0; e < 8; ++e) {
        va[e] = f2bf_rne(__uint_as_float(wa[e]));
        vb[e] = f2bf_rne(__uint_as_float(wb[e]));
      }
      const int dst = (sg_h * HPAD + sg_r[it]) * 8;
      *(ushort8*)&ldsA[dst] = va;
      *(ushort8*)&ldsB[dst] = vb;
    }
    __syncthreads();

    bf16x8 af[2], bf[8];
#pragma unroll
    for (int i = 0; i < 2; ++i)
      af[i] = *(const bf16x8*)&ldsA[(fh * HPAD + wm * 32 + i * 16 + fr) * 8];
#pragma unroll
    for (int j = 0; j < 8; ++j)
      bf[j] = *(const bf16x8*)&ldsB[(fh * HPAD + j * 16 + fr) * 8];

#pragma unroll
    for (int i = 0; i < 2; ++i)
#pragma unroll
      for (int j = 0; j < 8; ++j)
        acc[i][j] = __builtin_amdgcn_mfma_f32_16x16x32_bf16(af[i], bf[j], acc[i][j], 0, 0, 0);
  }

#pragma unroll
  for (int i = 0; i < 2; ++i)
#pragma unroll
    for (int rr = 0; rr < 4; ++rr) {
      const int R = b * N_ + m0 + wm * 32 + i * 16 + fh * 4 + rr;
      const long base = (((long)c * 8192 + R) * 8 + blockIdx.x) * 8;
#pragma unroll
      for (int it = 0; it < 8; ++it) {
        float lv = acc[i][0][rr]; int lj = 0;
#pragma unroll
        for (int j = 1; j < 8; ++j)
          if (acc[i][j][rr] > lv) { lv = acc[i][j][rr]; lj = j; }
        int li = lj * 16 + fr;
#pragma unroll
        for (int m = 1; m < 16; m <<= 1) {
          float ov = __shfl_xor(lv, m);
          int oi = __shfl_xor(li, m);
          if (ov > lv || (ov == lv && oi < li)) { lv = ov; li = oi; }
        }
        if (fr == it) { candv[base + it] = lv; candi[base + it] = (ushort)(n0 + li); }
        if (fr == (li & 15)) {
#pragma unroll
          for (int j = 0; j < 8; ++j)
            if (j == (li >> 4)) acc[i][j][rr] = -INFINITY;
        }
      }
    }
}

// ---------------------------------------------------------------------------
// STAGE 2 v3: same exact arithmetic as R8, with (a) NO runtime-indexed array
// (two __shfl broadcasts instead — rule #20 scratch fix), (b) XCD-aware block
// swizzle so each XCD's K-gather working set stays L2-resident.
// ---------------------------------------------------------------------------
#define KROW 68
#define RRBLOCKS (NCALLS * 8192 / 4)       // 38912 = 8 * 4864

__global__ __launch_bounds__(256) void rerank_exact(const float* __restrict__ Qn,
                                                    const float* __restrict__ Kn,
                                                    const float* __restrict__ candv,
                                                    const ushort* __restrict__ candi,
                                                    float* __restrict__ fp,
                                                    int* __restrict__ fi,
                                                    float* __restrict__ out,
                                                    CallTab tab) {
  __shared__ float kbuf[4][16 * KROW];
  __shared__ float qbuf[4][64];

  // bijective XCD swizzle: consecutive hardware dispatch (bid%8 = XCD) gets
  // contiguous gr ranges per XCD -> per-XCD K working set ~2.4 calls (~5MB).
  const int bid = blockIdx.x;
  const int blk = (bid & 7) * (RRBLOCKS / 8) + (bid >> 3);

  const int w = threadIdx.x >> 6, lane = threadIdx.x & 63;
  const long gr = (long)blk * 4 + w;      // 0..19*8192-1
  const int c = (int)(gr >> 13);
  const int R = (int)(gr & 8191);
  const int b = R >> 10;

  const long cb = gr * 64;
  float cv = candv[cb + lane];
  int ci = (int)candi[cb + lane];

  // approx top-16 of the 64 candidates (comparator & retire verbatim R7/R8)
  int myi = 0;
#pragma unroll
  for (int it = 0; it < 16; ++it) {
    float lv = cv; int gi = ci;
#pragma unroll
    for (int m = 1; m < 64; m <<= 1) {
      float ov = __shfl_xor(lv, m);
      int oi = __shfl_xor(gi, m);
      if (ov > lv || (ov == lv && oi < gi)) { lv = ov; gi = oi; }
    }
    if ((lane & 15) == it) myi = gi;
    if (ci == gi) cv = -INFINITY;
  }
  // lane (s mod 16 == r) holds rank-r candidate index in myi.

  const int srow = lane >> 2;          // staged row slot 0..15
  const int sqt = lane & 3;            // quarter: 16 floats each
  const int mycand = lane & 15;        // candidate rank for this lane's chain

  const int kidx = __shfl(myi, srow);  // index of rank-srow candidate (registers!)
  const int eidx = __shfl(myi, mycand);

  const float* qrow = Qn + (long)tab.qi[c] * BAND_ELEMS + (long)R * D_;
  const float* ksrc = Kn + (long)tab.ki[c] * BAND_ELEMS +
                      ((long)(b << 10) + kidx) * D_ + sqt * 16;

  // prefetch chunk 0
  float4 pk[4];
  float pq;
#pragma unroll
  for (int j = 0; j < 4; ++j) pk[j] = *(const float4*)(ksrc + j * 4);
  pq = qrow[lane];

  float acc = 0.f;
  for (int ch = 0; ch < 8; ++ch) {
    __syncthreads();
#pragma unroll
    for (int j = 0; j < 4; ++j)
      *(float4*)&kbuf[w][srow * KROW + sqt * 16 + j * 4] = pk[j];
    qbuf[w][lane] = pq;
    __syncthreads();
    if (ch < 7) {
#pragma unroll
      for (int j = 0; j < 4; ++j) pk[j] = *(const float4*)(ksrc + (ch + 1) * 64 + j * 4);
      pq = qrow[(ch + 1) * 64 + lane];
    }
    // exact chain: 64 floats in order (same fmaf sequence as R7/R8)
    const float* kr = &kbuf[w][mycand * KROW];
    const float* qc = qbuf[w];
#pragma unroll
    for (int k = 0; k < 64; k += 4) {
      float4 qv = *(const float4*)(qc + k);
      float4 kv = *(const float4*)(kr + k);
      acc = fmaf(qv.x, kv.x, acc);
      acc = fmaf(qv.y, kv.y, acc);
      acc = fmaf(qv.z, kv.z, acc);
      acc = fmaf(qv.w, kv.w, acc);
    }
  }

  // top-8 by exact value (verbatim: dup lanes tie exactly, retire by idx)
  float ev = acc; int ei = eidx;
  float sv[8]; int si[8];
#pragma unroll
  for (int it = 0; it < 8; ++it) {
    float lv = ev; int gi = ei;
#pragma unroll
    for (int m = 1; m < 64; m <<= 1) {
      float ov = __shfl_xor(lv, m);
      int oi = __shfl_xor(gi, m);
      if (ov > lv || (ov == lv && oi < gi)) { lv = ov; gi = oi; }
    }
    sv[it] = lv; si[it] = gi;
    if (ei == gi) ev = -INFINITY;
  }

  // softmax + entropy (verbatim)
  float p[8], sum = 0.f;
#pragma unroll
  for (int j = 0; j < 8; ++j) { p[j] = expf(sv[j] - sv[0]); sum += p[j]; }
  const float isum = 1.0f / sum;
  float H = 0.f;
#pragma unroll
  for (int j = 0; j < 8; ++j) { p[j] *= isum; H -= p[j] * logf(p[j] + 1e-9f); }

  if (lane == 0) {
    atomicAdd(out + OUT_MAIN + (long)c * B_ + b, H * (1.0f / (float)N_));
#pragma unroll
    for (int j = 0; j < 8; ++j) { fp[gr * 8 + j] = p[j]; fi[gr * 8 + j] = si[j]; }
  }
}

// ---- merge finals + PV + band add + out write (VERBATIM R7) -----------------
__global__ __launch_bounds__(256) void merge_pv(Ptrs8 bands,
                                                const float* __restrict__ fp,
                                                const int* __restrict__ fi,
                                                const float* __restrict__ V,
                                                float* __restrict__ out,
                                                MergeTab mt) {
  const int bb = blockIdx.y;
  const int w = threadIdx.x >> 6, lane = threadIdx.x & 63;
  const long R = (long)blockIdx.x * 4 + w;
  const int b = (int)(R >> 10);

  float4 o0 = {0, 0, 0, 0}, o1 = {0, 0, 0, 0};
  const int nc = mt.ncalls[bb];
  for (int s = 0; s < nc; ++s) {
    const int c = mt.calls[bb][s];
    const float wt = mt.wts[c];
    const int ki = mt.kis[c];
    const long fb = ((long)c * 8192 + R) * 8;
    float4 p0 = *(const float4*)(fp + fb);
    float4 p1 = *(const float4*)(fp + fb + 4);
    int4 i0 = *(const int4*)(fi + fb);
    int4 i1 = *(const int4*)(fi + fb + 4);
    float pj[8] = {p0.x, p0.y, p0.z, p0.w, p1.x, p1.y, p1.z, p1.w};
    int ij[8] = {i0.x, i0.y, i0.z, i0.w, i1.x, i1.y, i1.z, i1.w};
#pragma unroll
    for (int j = 0; j < 8; ++j) {
      const float pw = pj[j] * wt;
      const float4* vr = (const float4*)(V + (long)ki * BAND_ELEMS +
                                         ((long)(b << 10) + ij[j]) * D_);
      float4 x0 = vr[lane * 2], x1 = vr[lane * 2 + 1];
      o0.x += pw * x0.x; o0.y += pw * x0.y; o0.z += pw * x0.z; o0.w += pw * x0.w;
      o1.x += pw * x1.x; o1.y += pw * x1.y; o1.z += pw * x1.z; o1.w += pw * x1.w;
    }
  }

  const float4* src = (const float4*)(bands.p[bb] + R * D_);
  float4 s0 = src[lane * 2], s1 = src[lane * 2 + 1];
  s0.x += o0.x; s0.y += o0.y; s0.z += o0.z; s0.w += o0.w;
  s1.x += o1.x; s1.y += o1.y; s1.z += o1.z; s1.w += o1.w;
  float4* dst = (float4*)(out + (long)bb * BAND_ELEMS + R * D_);
  dst[lane * 2] = s0;
  dst[lane * 2 + 1] = s1;
}

// ---- zero the 152 entropy slots ---------------------------------------------
__global__ void init_eps(float* __restrict__ out) {
  if (threadIdx.x < NCALLS * B_) out[OUT_MAIN + threadIdx.x] = 0.f;
}

// --------------------------------------------------------------------------------
extern "C" void kernel_launch(void* const* d_in, const int* in_sizes, int n_in,
                              void* d_out, int out_size, void* d_ws, size_t ws_size,
                              hipStream_t stream) {
  Ptrs8 bands;
  for (int i = 0; i < 8; ++i) bands.p[i] = (const float*)d_in[i];
  const float* qW = (const float*)d_in[8];
  const float* qb = (const float*)d_in[9];
  const float* kW = (const float*)d_in[10];
  const float* kb = (const float*)d_in[11];
  const float* vW = (const float*)d_in[12];
  const float* vb = (const float*)d_in[13];
  float* out = (float*)d_out;
  float* ws = (float*)d_ws;

  float* Qn = ws;
  float* Kn = ws + (long)8 * BAND_ELEMS;
  float* V  = ws + (long)16 * BAND_ELEMS;
  float* candv = ws + (long)24 * BAND_ELEMS;
  ushort* candi = (ushort*)(candv + (long)NCALLS * 8192 * 64);
  float* fp = (float*)(candi + (long)NCALLS * 8192 * 64);
  int* fi = (int*)(fp + (long)NCALLS * 8192 * 8);

  static const int calls[NCALLS][2] = {
      {6, 0}, {0, 6}, {5, 1}, {1, 5}, {4, 2}, {2, 4},
      {0, 3}, {1, 3}, {2, 3}, {4, 3}, {5, 3}, {6, 3},
      {0, 7}, {1, 7}, {2, 7}, {3, 7}, {4, 7}, {5, 7}, {6, 7}};

  CallTab tab;
  MergeTab mt;
  for (int i = 0; i < 8; ++i) mt.ncalls[i] = 0;
  for (int c = 0; c < NCALLS; ++c) {
    tab.qi[c] = calls[c][0];
    tab.ki[c] = calls[c][1];
    mt.kis[c] = calls[c][1];
    mt.wts[c] = (c < 6) ? 1.0f : 0.5f;
    int q = calls[c][0];
    mt.calls[q][mt.ncalls[q]++] = c;
  }

  hipLaunchKernelGGL(init_eps, dim3(1), dim3(256), 0, stream, out);

  dim3 gp(D_ / BN, (B_ * N_) / BM, 24);
  hipLaunchKernelGGL(gemm_proj_all, gp, dim3(256), 0, stream,
                     bands, qW, kW, vW, qb, kb, vb, Qn, Kn, V);

  hipLaunchKernelGGL(l2norm_rows, dim3(2 * 8 * B_ * N_ / 4), dim3(256), 0, stream, Qn);

  dim3 gs(N_ / SBN, N_ / SBM, NCALLS * 8);
  hipLaunchKernelGGL(mfma_extract, gs, dim3(256), 0, stream, Qn, Kn, candv, candi, tab);

  hipLaunchKernelGGL(rerank_exact, dim3(RRBLOCKS), dim3(256), 0, stream,
                     Qn, Kn, candv, candi, fp, fi, out, tab);

  hipLaunchKernelGGL(merge_pv, dim3(B_ * N_ / 4, 8), dim3(256), 0, stream,
                     bands, fp, fi, V, out, mt);
}

// Round 10
// 4752.076 us; speedup vs baseline: 1.1572x; 1.0071x over previous
//
#include <hip/hip_runtime.h>
#include <math.h>

#define B_ 8
#define N_ 1024
#define D_ 512
#define BAND_ELEMS (B_ * N_ * D_)          // 4194304 = 2^22
#define OUT_MAIN (8L * BAND_ELEMS)         // 33554432
#define NCALLS 19

struct Ptrs8 { const float* p[8]; };
struct CallTab { int qi[NCALLS]; int ki[NCALLS]; };
struct MergeTab { int ncalls[8]; int calls[8][3]; int kis[NCALLS]; float wts[NCALLS]; };

typedef __attribute__((ext_vector_type(8))) short bf16x8;
typedef __attribute__((ext_vector_type(8))) ushort ushort8;
typedef __attribute__((ext_vector_type(4))) float f32x4;

// ---------------------------------------------------------------------------
// fp32 GEMM core (VERBATIM R5/R6 — bit-exact contract: sequential-k fp32 fma
// chain per output). Used ONLY for the projections.
// ---------------------------------------------------------------------------
#define BM 128
#define BN 128
#define BK 16
#define LDP 132

__device__ __forceinline__ int bgran(int g) {
  return (g & ~7) | ((g + (g >> 3)) & 7);
}

__device__ __forceinline__ void gemm_core(const float* __restrict__ A,
                                          const float* __restrict__ Bm,
                                          int m0, int n0, int K,
                                          float (&acc)[8][8]) {
  __shared__ float As[BK * LDP];
  __shared__ float Bs[BK * LDP];

  const int t = threadIdx.x;
  const int tx = t & 15, ty = t >> 4;
  const int rs = t >> 2;
  const int cs = t & 3;

  float4 pa[2], pb[2];
#pragma unroll
  for (int it = 0; it < 2; ++it) {
    pa[it] = *(const float4*)(A + (long)(m0 + rs + 64 * it) * K + cs * 4);
    pb[it] = *(const float4*)(Bm + (long)(n0 + rs + 64 * it) * K + cs * 4);
  }

  for (int k0 = 0; k0 < K; k0 += BK) {
    __syncthreads();
    {
      const int sa = ((cs & 1) << 2);
      const int base = cs * 4 * LDP;
#pragma unroll
      for (int it = 0; it < 2; ++it) {
        const int r = rs + 64 * it;
        const int ra = r ^ sa;
        As[base + 0 * LDP + ra] = pa[it].x;
        As[base + 1 * LDP + ra] = pa[it].y;
        As[base + 2 * LDP + ra] = pa[it].z;
        As[base + 3 * LDP + ra] = pa[it].w;
        const int rb = bgran(r >> 2) * 4 + (r & 3);
        Bs[base + 0 * LDP + rb] = pb[it].x;
        Bs[base + 1 * LDP + rb] = pb[it].y;
        Bs[base + 2 * LDP + rb] = pb[it].z;
        Bs[base + 3 * LDP + rb] = pb[it].w;
      }
    }
    __syncthreads();

    if (k0 + BK < K) {
#pragma unroll
      for (int it = 0; it < 2; ++it) {
        pa[it] = *(const float4*)(A + (long)(m0 + rs + 64 * it) * K + k0 + BK + cs * 4);
        pb[it] = *(const float4*)(Bm + (long)(n0 + rs + 64 * it) * K + k0 + BK + cs * 4);
      }
    }

#pragma unroll
    for (int kk = 0; kk < BK; ++kk) {
      const int c1 = (kk >> 2) & 1;
      float a[8], b[8];
      {
        float4 u = *(const float4*)&As[kk * LDP + ty * 8 + c1 * 4];
        float4 v = *(const float4*)&As[kk * LDP + ty * 8 + 4 - c1 * 4];
        a[0] = u.x; a[1] = u.y; a[2] = u.z; a[3] = u.w;
        a[4] = v.x; a[5] = v.y; a[6] = v.z; a[7] = v.w;
        float4 p = *(const float4*)&Bs[kk * LDP + bgran(2 * tx) * 4];
        float4 q = *(const float4*)&Bs[kk * LDP + bgran(2 * tx + 1) * 4];
        b[0] = p.x; b[1] = p.y; b[2] = p.z; b[3] = p.w;
        b[4] = q.x; b[5] = q.y; b[6] = q.z; b[7] = q.w;
      }
#pragma unroll
      for (int i = 0; i < 8; ++i)
#pragma unroll
        for (int j = 0; j < 8; ++j) acc[i][j] = fmaf(a[i], b[j], acc[i][j]);
    }
  }
}

// ---- all 24 projections in one launch: z = mat*8 + band (VERBATIM R6) ------
__global__ __launch_bounds__(256) void gemm_proj_all(Ptrs8 bands,
                                                     const float* __restrict__ qW,
                                                     const float* __restrict__ kW,
                                                     const float* __restrict__ vW,
                                                     const float* __restrict__ qb,
                                                     const float* __restrict__ kb,
                                                     const float* __restrict__ vb,
                                                     float* __restrict__ Qn,
                                                     float* __restrict__ Kn,
                                                     float* __restrict__ V) {
  const int mat = blockIdx.z >> 3, band = blockIdx.z & 7;
  const float* W = (mat == 0) ? qW : (mat == 1) ? kW : vW;
  const float* bvec = (mat == 0) ? qb : (mat == 1) ? kb : vb;
  float* dst = (mat == 0) ? Qn : (mat == 1) ? Kn : V;
  W += (long)band * D_ * D_;
  bvec += band * D_;
  dst += (long)band * BAND_ELEMS;

  const int m0 = blockIdx.y * BM, n0 = blockIdx.x * BN;
  float acc[8][8] = {};
  gemm_core(bands.p[band], W, m0, n0, D_, acc);

  const int t = threadIdx.x;
  const int tx = t & 15, ty = t >> 4;
#pragma unroll
  for (int i = 0; i < 8; ++i) {
    float* crow = dst + (long)(m0 + ty * 8 + i) * D_ + n0 + tx * 8;
    const float* bp = bvec + n0 + tx * 8;
    float4 r0, r1;
    r0.x = acc[i][0] + bp[0]; r0.y = acc[i][1] + bp[1];
    r0.z = acc[i][2] + bp[2]; r0.w = acc[i][3] + bp[3];
    r1.x = acc[i][4] + bp[4]; r1.y = acc[i][5] + bp[5];
    r1.z = acc[i][6] + bp[6]; r1.w = acc[i][7] + bp[7];
    ((float4*)crow)[0] = r0;
    ((float4*)crow)[1] = r1;
  }
}

// ---- L2 normalization (VERBATIM R6) ----------------------------------------
__global__ __launch_bounds__(256) void l2norm_rows(float* __restrict__ X) {
  const long row = (long)blockIdx.x * 4 + (threadIdx.x >> 6);
  const int lane = threadIdx.x & 63;
  float* p = X + row * D_;
  float4 a = ((float4*)p)[lane];
  float4 b = ((float4*)p)[lane + 64];
  float s = a.x * a.x + a.y * a.y + a.z * a.z + a.w * a.w +
            b.x * b.x + b.y * b.y + b.z * b.z + b.w * b.w;
#pragma unroll
  for (int m = 1; m < 64; m <<= 1) s += __shfl_xor(s, m);
  const float inv = 1.0f / fmaxf(sqrtf(s), 1e-12f);
  a.x *= inv; a.y *= inv; a.z *= inv; a.w *= inv;
  b.x *= inv; b.y *= inv; b.z *= inv; b.w *= inv;
  ((float4*)p)[lane] = a;
  ((float4*)p)[lane + 64] = b;
}

// ---------------------------------------------------------------------------
// STAGE 1: bf16(hi) MFMA approx scores + per-tile top-8 extraction (VERBATIM R7)
// ---------------------------------------------------------------------------
#define SBM 128
#define SBN 128
#define SBK 32
#define HPAD 132

__device__ __forceinline__ ushort f2bf_rne(float x) {
  uint u = __float_as_uint(x);
  return (ushort)((u + 0x7fffu + ((u >> 16) & 1u)) >> 16);
}

__global__ __launch_bounds__(256) void mfma_extract(const float* __restrict__ Qn,
                                                    const float* __restrict__ Kn,
                                                    float* __restrict__ candv,
                                                    ushort* __restrict__ candi,
                                                    CallTab tab) {
  __shared__ ushort ldsA[4 * HPAD * 8];
  __shared__ ushort ldsB[4 * HPAD * 8];

  const int z = blockIdx.z;
  const int c = z >> 3, b = z & 7;
  const float* A = Qn + (long)tab.qi[c] * BAND_ELEMS + (long)b * N_ * D_;
  const float* Bm = Kn + (long)tab.ki[c] * BAND_ELEMS + (long)b * N_ * D_;
  const int m0 = blockIdx.y * SBM, n0 = blockIdx.x * SBN;

  const int t = threadIdx.x;
  const int lane = t & 63;
  const int wm = t >> 6;
  const int fr = lane & 15, fh = lane >> 4;

  f32x4 acc[2][8] = {};

  const int sg_r[2] = {t >> 2, (t + 256) >> 2};
  const int sg_h = t & 3;

  for (int k0 = 0; k0 < D_; k0 += SBK) {
    uint4 ga[2][2], gb[2][2];
#pragma unroll
    for (int it = 0; it < 2; ++it) {
      const float* pa = A + (long)(m0 + sg_r[it]) * D_ + k0 + sg_h * 8;
      ga[it][0] = *(const uint4*)pa;
      ga[it][1] = *(const uint4*)(pa + 4);
      const float* pb = Bm + (long)(n0 + sg_r[it]) * D_ + k0 + sg_h * 8;
      gb[it][0] = *(const uint4*)pb;
      gb[it][1] = *(const uint4*)(pb + 4);
    }
    __syncthreads();
#pragma unroll
    for (int it = 0; it < 2; ++it) {
      uint wa[8] = {ga[it][0].x, ga[it][0].y, ga[it][0].z, ga[it][0].w,
                    ga[it][1].x, ga[it][1].y, ga[it][1].z, ga[it][1].w};
      uint wb[8] = {gb[it][0].x, gb[it][0].y, gb[it][0].z, gb[it][0].w,
                    gb[it][1].x, gb[it][1].y, gb[it][1].z, gb[it][1].w};
      ushort8 va, vb;
#pragma unroll
      for (int e = 0; e < 8; ++e) {
        va[e] = f2bf_rne(__uint_as_float(wa[e]));
        vb[e] = f2bf_rne(__uint_as_float(wb[e]));
      }
      const int dst = (sg_h * HPAD + sg_r[it]) * 8;
      *(ushort8*)&ldsA[dst] = va;
      *(ushort8*)&ldsB[dst] = vb;
    }
    __syncthreads();

    bf16x8 af[2], bf[8];
#pragma unroll
    for (int i = 0; i < 2; ++i)
      af[i] = *(const bf16x8*)&ldsA[(fh * HPAD + wm * 32 + i * 16 + fr) * 8];
#pragma unroll
    for (int j = 0; j < 8; ++j)
      bf[j] = *(const bf16x8*)&ldsB[(fh * HPAD + j * 16 + fr) * 8];

#pragma unroll
    for (int i = 0; i < 2; ++i)
#pragma unroll
      for (int j = 0; j < 8; ++j)
        acc[i][j] = __builtin_amdgcn_mfma_f32_16x16x32_bf16(af[i], bf[j], acc[i][j], 0, 0, 0);
  }

#pragma unroll
  for (int i = 0; i < 2; ++i)
#pragma unroll
    for (int rr = 0; rr < 4; ++rr) {
      const int R = b * N_ + m0 + wm * 32 + i * 16 + fh * 4 + rr;
      const long base = (((long)c * 8192 + R) * 8 + blockIdx.x) * 8;
#pragma unroll
      for (int it = 0; it < 8; ++it) {
        float lv = acc[i][0][rr]; int lj = 0;
#pragma unroll
        for (int j = 1; j < 8; ++j)
          if (acc[i][j][rr] > lv) { lv = acc[i][j][rr]; lj = j; }
        int li = lj * 16 + fr;
#pragma unroll
        for (int m = 1; m < 16; m <<= 1) {
          float ov = __shfl_xor(lv, m);
          int oi = __shfl_xor(li, m);
          if (ov > lv || (ov == lv && oi < li)) { lv = ov; li = oi; }
        }
        if (fr == it) { candv[base + it] = lv; candi[base + it] = (ushort)(n0 + li); }
        if (fr == (li & 15)) {
#pragma unroll
          for (int j = 0; j < 8; ++j)
            if (j == (li >> 4)) acc[i][j][rr] = -INFINITY;
        }
      }
    }
}

// ---------------------------------------------------------------------------
// STAGE 2 v4: identical arithmetic to R9. ONE change: __launch_bounds__(256,2)
// raises the VGPR cap (min 2 waves/EU -> up to 256 VGPRs) so the cross-barrier
// prefetch registers (pk/pq) stay resident instead of spilling to scratch
// (R8/R9: 5 GB/dispatch scratch write traffic at VGPR_Count=32).
// ---------------------------------------------------------------------------
#define KROW 68
#define RRBLOCKS (NCALLS * 8192 / 4)       // 38912 = 8 * 4864

__global__ __launch_bounds__(256, 2) void rerank_exact(const float* __restrict__ Qn,
                                                       const float* __restrict__ Kn,
                                                       const float* __restrict__ candv,
                                                       const ushort* __restrict__ candi,
                                                       float* __restrict__ fp,
                                                       int* __restrict__ fi,
                                                       float* __restrict__ out,
                                                       CallTab tab) {
  __shared__ float kbuf[4][16 * KROW];
  __shared__ float qbuf[4][64];

  const int bid = blockIdx.x;
  const int blk = (bid & 7) * (RRBLOCKS / 8) + (bid >> 3);

  const int w = threadIdx.x >> 6, lane = threadIdx.x & 63;
  const long gr = (long)blk * 4 + w;      // 0..19*8192-1
  const int c = (int)(gr >> 13);
  const int R = (int)(gr & 8191);
  const int b = R >> 10;

  const long cb = gr * 64;
  float cv = candv[cb + lane];
  int ci = (int)candi[cb + lane];

  // approx top-16 of the 64 candidates (comparator & retire verbatim R7/R8)
  int myi = 0;
#pragma unroll
  for (int it = 0; it < 16; ++it) {
    float lv = cv; int gi = ci;
#pragma unroll
    for (int m = 1; m < 64; m <<= 1) {
      float ov = __shfl_xor(lv, m);
      int oi = __shfl_xor(gi, m);
      if (ov > lv || (ov == lv && oi < gi)) { lv = ov; gi = oi; }
    }
    if ((lane & 15) == it) myi = gi;
    if (ci == gi) cv = -INFINITY;
  }
  // lane (s mod 16 == r) holds rank-r candidate index in myi.

  const int srow = lane >> 2;          // staged row slot 0..15
  const int sqt = lane & 3;            // quarter: 16 floats each
  const int mycand = lane & 15;        // candidate rank for this lane's chain

  const int kidx = __shfl(myi, srow);  // index of rank-srow candidate (registers)
  const int eidx = __shfl(myi, mycand);

  const float* qrow = Qn + (long)tab.qi[c] * BAND_ELEMS + (long)R * D_;
  const float* ksrc = Kn + (long)tab.ki[c] * BAND_ELEMS +
                      ((long)(b << 10) + kidx) * D_ + sqt * 16;

  // prefetch chunk 0
  float4 pk[4];
  float pq;
#pragma unroll
  for (int j = 0; j < 4; ++j) pk[j] = *(const float4*)(ksrc + j * 4);
  pq = qrow[lane];

  float acc = 0.f;
  for (int ch = 0; ch < 8; ++ch) {
    __syncthreads();
#pragma unroll
    for (int j = 0; j < 4; ++j)
      *(float4*)&kbuf[w][srow * KROW + sqt * 16 + j * 4] = pk[j];
    qbuf[w][lane] = pq;
    __syncthreads();
    if (ch < 7) {
#pragma unroll
      for (int j = 0; j < 4; ++j) pk[j] = *(const float4*)(ksrc + (ch + 1) * 64 + j * 4);
      pq = qrow[(ch + 1) * 64 + lane];
    }
    // exact chain: 64 floats in order (same fmaf sequence as R7/R8/R9)
    const float* kr = &kbuf[w][mycand * KROW];
    const float* qc = qbuf[w];
#pragma unroll
    for (int k = 0; k < 64; k += 4) {
      float4 qv = *(const float4*)(qc + k);
      float4 kv = *(const float4*)(kr + k);
      acc = fmaf(qv.x, kv.x, acc);
      acc = fmaf(qv.y, kv.y, acc);
      acc = fmaf(qv.z, kv.z, acc);
      acc = fmaf(qv.w, kv.w, acc);
    }
  }

  // top-8 by exact value (verbatim: dup lanes tie exactly, retire by idx)
  float ev = acc; int ei = eidx;
  float sv[8]; int si[8];
#pragma unroll
  for (int it = 0; it < 8; ++it) {
    float lv = ev; int gi = ei;
#pragma unroll
    for (int m = 1; m < 64; m <<= 1) {
      float ov = __shfl_xor(lv, m);
      int oi = __shfl_xor(gi, m);
      if (ov > lv || (ov == lv && oi < gi)) { lv = ov; gi = oi; }
    }
    sv[it] = lv; si[it] = gi;
    if (ei == gi) ev = -INFINITY;
  }

  // softmax + entropy (verbatim)
  float p[8], sum = 0.f;
#pragma unroll
  for (int j = 0; j < 8; ++j) { p[j] = expf(sv[j] - sv[0]); sum += p[j]; }
  const float isum = 1.0f / sum;
  float H = 0.f;
#pragma unroll
  for (int j = 0; j < 8; ++j) { p[j] *= isum; H -= p[j] * logf(p[j] + 1e-9f); }

  if (lane == 0) {
    atomicAdd(out + OUT_MAIN + (long)c * B_ + b, H * (1.0f / (float)N_));
#pragma unroll
    for (int j = 0; j < 8; ++j) { fp[gr * 8 + j] = p[j]; fi[gr * 8 + j] = si[j]; }
  }
}

// ---- merge finals + PV + band add + out write (VERBATIM R7) -----------------
__global__ __launch_bounds__(256) void merge_pv(Ptrs8 bands,
                                                const float* __restrict__ fp,
                                                const int* __restrict__ fi,
                                                const float* __restrict__ V,
                                                float* __restrict__ out,
                                                MergeTab mt) {
  const int bb = blockIdx.y;
  const int w = threadIdx.x >> 6, lane = threadIdx.x & 63;
  const long R = (long)blockIdx.x * 4 + w;
  const int b = (int)(R >> 10);

  float4 o0 = {0, 0, 0, 0}, o1 = {0, 0, 0, 0};
  const int nc = mt.ncalls[bb];
  for (int s = 0; s < nc; ++s) {
    const int c = mt.calls[bb][s];
    const float wt = mt.wts[c];
    const int ki = mt.kis[c];
    const long fb = ((long)c * 8192 + R) * 8;
    float4 p0 = *(const float4*)(fp + fb);
    float4 p1 = *(const float4*)(fp + fb + 4);
    int4 i0 = *(const int4*)(fi + fb);
    int4 i1 = *(const int4*)(fi + fb + 4);
    float pj[8] = {p0.x, p0.y, p0.z, p0.w, p1.x, p1.y, p1.z, p1.w};
    int ij[8] = {i0.x, i0.y, i0.z, i0.w, i1.x, i1.y, i1.z, i1.w};
#pragma unroll
    for (int j = 0; j < 8; ++j) {
      const float pw = pj[j] * wt;
      const float4* vr = (const float4*)(V + (long)ki * BAND_ELEMS +
                                         ((long)(b << 10) + ij[j]) * D_);
      float4 x0 = vr[lane * 2], x1 = vr[lane * 2 + 1];
      o0.x += pw * x0.x; o0.y += pw * x0.y; o0.z += pw * x0.z; o0.w += pw * x0.w;
      o1.x += pw * x1.x; o1.y += pw * x1.y; o1.z += pw * x1.z; o1.w += pw * x1.w;
    }
  }

  const float4* src = (const float4*)(bands.p[bb] + R * D_);
  float4 s0 = src[lane * 2], s1 = src[lane * 2 + 1];
  s0.x += o0.x; s0.y += o0.y; s0.z += o0.z; s0.w += o0.w;
  s1.x += o1.x; s1.y += o1.y; s1.z += o1.z; s1.w += o1.w;
  float4* dst = (float4*)(out + (long)bb * BAND_ELEMS + R * D_);
  dst[lane * 2] = s0;
  dst[lane * 2 + 1] = s1;
}

// ---- zero the 152 entropy slots ---------------------------------------------
__global__ void init_eps(float* __restrict__ out) {
  if (threadIdx.x < NCALLS * B_) out[OUT_MAIN + threadIdx.x] = 0.f;
}

// --------------------------------------------------------------------------------
extern "C" void kernel_launch(void* const* d_in, const int* in_sizes, int n_in,
                              void* d_out, int out_size, void* d_ws, size_t ws_size,
                              hipStream_t stream) {
  Ptrs8 bands;
  for (int i = 0; i < 8; ++i) bands.p[i] = (const float*)d_in[i];
  const float* qW = (const float*)d_in[8];
  const float* qb = (const float*)d_in[9];
  const float* kW = (const float*)d_in[10];
  const float* kb = (const float*)d_in[11];
  const float* vW = (const float*)d_in[12];
  const float* vb = (const float*)d_in[13];
  float* out = (float*)d_out;
  float* ws = (float*)d_ws;

  float* Qn = ws;
  float* Kn = ws + (long)8 * BAND_ELEMS;
  float* V  = ws + (long)16 * BAND_ELEMS;
  float* candv = ws + (long)24 * BAND_ELEMS;
  ushort* candi = (ushort*)(candv + (long)NCALLS * 8192 * 64);
  float* fp = (float*)(candi + (long)NCALLS * 8192 * 64);
  int* fi = (int*)(fp + (long)NCALLS * 8192 * 8);

  static const int calls[NCALLS][2] = {
      {6, 0}, {0, 6}, {5, 1}, {1, 5}, {4, 2}, {2, 4},
      {0, 3}, {1, 3}, {2, 3}, {4, 3}, {5, 3}, {6, 3},
      {0, 7}, {1, 7}, {2, 7}, {3, 7}, {4, 7}, {5, 7}, {6, 7}};

  CallTab tab;
  MergeTab mt;
  for (int i = 0; i < 8; ++i) mt.ncalls[i] = 0;
  for (int c = 0; c < NCALLS; ++c) {
    tab.qi[c] = calls[c][0];
    tab.ki[c] = calls[c][1];
    mt.kis[c] = calls[c][1];
    mt.wts[c] = (c < 6) ? 1.0f : 0.5f;
    int q = calls[c][0];
    mt.calls[q][mt.ncalls[q]++] = c;
  }

  hipLaunchKernelGGL(init_eps, dim3(1), dim3(256), 0, stream, out);

  dim3 gp(D_ / BN, (B_ * N_) / BM, 24);
  hipLaunchKernelGGL(gemm_proj_all, gp, dim3(256), 0, stream,
                     bands, qW, kW, vW, qb, kb, vb, Qn, Kn, V);

  hipLaunchKernelGGL(l2norm_rows, dim3(2 * 8 * B_ * N_ / 4), dim3(256), 0, stream, Qn);

  dim3 gs(N_ / SBN, N_ / SBM, NCALLS * 8);
  hipLaunchKernelGGL(mfma_extract, gs, dim3(256), 0, stream, Qn, Kn, candv, candi, tab);

  hipLaunchKernelGGL(rerank_exact, dim3(RRBLOCKS), dim3(256), 0, stream,
                     Qn, Kn, candv, candi, fp, fi, out, tab);

  hipLaunchKernelGGL(merge_pv, dim3(B_ * N_ / 4, 8), dim3(256), 0, stream,
                     bands, fp, fi, V, out, mt);
}

// Round 11
// 3778.457 us; speedup vs baseline: 1.4554x; 1.2577x over previous
//
#include <hip/hip_runtime.h>
#include <math.h>

#define B_ 8
#define N_ 1024
#define D_ 512
#define BAND_ELEMS (B_ * N_ * D_)          // 4194304 = 2^22
#define OUT_MAIN (8L * BAND_ELEMS)         // 33554432
#define NCALLS 19

struct Ptrs8 { const float* p[8]; };
struct CallTab { int qi[NCALLS]; int ki[NCALLS]; };
struct MergeTab { int ncalls[8]; int calls[8][3]; int kis[NCALLS]; float wts[NCALLS]; };

typedef __attribute__((ext_vector_type(8))) short bf16x8;
typedef __attribute__((ext_vector_type(8))) ushort ushort8;
typedef __attribute__((ext_vector_type(4))) float f32x4;

// ---------------------------------------------------------------------------
// fp32 GEMM core (VERBATIM R5/R6 — bit-exact contract: sequential-k fp32 fma
// chain per output). Used ONLY for the projections.
// ---------------------------------------------------------------------------
#define BM 128
#define BN 128
#define BK 16
#define LDP 132

__device__ __forceinline__ int bgran(int g) {
  return (g & ~7) | ((g + (g >> 3)) & 7);
}

__device__ __forceinline__ void gemm_core(const float* __restrict__ A,
                                          const float* __restrict__ Bm,
                                          int m0, int n0, int K,
                                          float (&acc)[8][8]) {
  __shared__ float As[BK * LDP];
  __shared__ float Bs[BK * LDP];

  const int t = threadIdx.x;
  const int tx = t & 15, ty = t >> 4;
  const int rs = t >> 2;
  const int cs = t & 3;

  float4 pa[2], pb[2];
#pragma unroll
  for (int it = 0; it < 2; ++it) {
    pa[it] = *(const float4*)(A + (long)(m0 + rs + 64 * it) * K + cs * 4);
    pb[it] = *(const float4*)(Bm + (long)(n0 + rs + 64 * it) * K + cs * 4);
  }

  for (int k0 = 0; k0 < K; k0 += BK) {
    __syncthreads();
    {
      const int sa = ((cs & 1) << 2);
      const int base = cs * 4 * LDP;
#pragma unroll
      for (int it = 0; it < 2; ++it) {
        const int r = rs + 64 * it;
        const int ra = r ^ sa;
        As[base + 0 * LDP + ra] = pa[it].x;
        As[base + 1 * LDP + ra] = pa[it].y;
        As[base + 2 * LDP + ra] = pa[it].z;
        As[base + 3 * LDP + ra] = pa[it].w;
        const int rb = bgran(r >> 2) * 4 + (r & 3);
        Bs[base + 0 * LDP + rb] = pb[it].x;
        Bs[base + 1 * LDP + rb] = pb[it].y;
        Bs[base + 2 * LDP + rb] = pb[it].z;
        Bs[base + 3 * LDP + rb] = pb[it].w;
      }
    }
    __syncthreads();

    if (k0 + BK < K) {
#pragma unroll
      for (int it = 0; it < 2; ++it) {
        pa[it] = *(const float4*)(A + (long)(m0 + rs + 64 * it) * K + k0 + BK + cs * 4);
        pb[it] = *(const float4*)(Bm + (long)(n0 + rs + 64 * it) * K + k0 + BK + cs * 4);
      }
    }

#pragma unroll
    for (int kk = 0; kk < BK; ++kk) {
      const int c1 = (kk >> 2) & 1;
      float a[8], b[8];
      {
        float4 u = *(const float4*)&As[kk * LDP + ty * 8 + c1 * 4];
        float4 v = *(const float4*)&As[kk * LDP + ty * 8 + 4 - c1 * 4];
        a[0] = u.x; a[1] = u.y; a[2] = u.z; a[3] = u.w;
        a[4] = v.x; a[5] = v.y; a[6] = v.z; a[7] = v.w;
        float4 p = *(const float4*)&Bs[kk * LDP + bgran(2 * tx) * 4];
        float4 q = *(const float4*)&Bs[kk * LDP + bgran(2 * tx + 1) * 4];
        b[0] = p.x; b[1] = p.y; b[2] = p.z; b[3] = p.w;
        b[4] = q.x; b[5] = q.y; b[6] = q.z; b[7] = q.w;
      }
#pragma unroll
      for (int i = 0; i < 8; ++i)
#pragma unroll
        for (int j = 0; j < 8; ++j) acc[i][j] = fmaf(a[i], b[j], acc[i][j]);
    }
  }
}

// ---- all 24 projections in one launch: z = mat*8 + band (VERBATIM R6) ------
__global__ __launch_bounds__(256) void gemm_proj_all(Ptrs8 bands,
                                                     const float* __restrict__ qW,
                                                     const float* __restrict__ kW,
                                                     const float* __restrict__ vW,
                                                     const float* __restrict__ qb,
                                                     const float* __restrict__ kb,
                                                     const float* __restrict__ vb,
                                                     float* __restrict__ Qn,
                                                     float* __restrict__ Kn,
                                                     float* __restrict__ V) {
  const int mat = blockIdx.z >> 3, band = blockIdx.z & 7;
  const float* W = (mat == 0) ? qW : (mat == 1) ? kW : vW;
  const float* bvec = (mat == 0) ? qb : (mat == 1) ? kb : vb;
  float* dst = (mat == 0) ? Qn : (mat == 1) ? Kn : V;
  W += (long)band * D_ * D_;
  bvec += band * D_;
  dst += (long)band * BAND_ELEMS;

  const int m0 = blockIdx.y * BM, n0 = blockIdx.x * BN;
  float acc[8][8] = {};
  gemm_core(bands.p[band], W, m0, n0, D_, acc);

  const int t = threadIdx.x;
  const int tx = t & 15, ty = t >> 4;
#pragma unroll
  for (int i = 0; i < 8; ++i) {
    float* crow = dst + (long)(m0 + ty * 8 + i) * D_ + n0 + tx * 8;
    const float* bp = bvec + n0 + tx * 8;
    float4 r0, r1;
    r0.x = acc[i][0] + bp[0]; r0.y = acc[i][1] + bp[1];
    r0.z = acc[i][2] + bp[2]; r0.w = acc[i][3] + bp[3];
    r1.x = acc[i][4] + bp[4]; r1.y = acc[i][5] + bp[5];
    r1.z = acc[i][6] + bp[6]; r1.w = acc[i][7] + bp[7];
    ((float4*)crow)[0] = r0;
    ((float4*)crow)[1] = r1;
  }
}

// ---- L2 normalization (VERBATIM R6) ----------------------------------------
__global__ __launch_bounds__(256) void l2norm_rows(float* __restrict__ X) {
  const long row = (long)blockIdx.x * 4 + (threadIdx.x >> 6);
  const int lane = threadIdx.x & 63;
  float* p = X + row * D_;
  float4 a = ((float4*)p)[lane];
  float4 b = ((float4*)p)[lane + 64];
  float s = a.x * a.x + a.y * a.y + a.z * a.z + a.w * a.w +
            b.x * b.x + b.y * b.y + b.z * b.z + b.w * b.w;
#pragma unroll
  for (int m = 1; m < 64; m <<= 1) s += __shfl_xor(s, m);
  const float inv = 1.0f / fmaxf(sqrtf(s), 1e-12f);
  a.x *= inv; a.y *= inv; a.z *= inv; a.w *= inv;
  b.x *= inv; b.y *= inv; b.z *= inv; b.w *= inv;
  ((float4*)p)[lane] = a;
  ((float4*)p)[lane + 64] = b;
}

// ---------------------------------------------------------------------------
// STAGE 1: bf16(hi) MFMA approx scores + per-tile top-8 extraction (VERBATIM R7)
// ---------------------------------------------------------------------------
#define SBM 128
#define SBN 128
#define SBK 32
#define HPAD 132

__device__ __forceinline__ ushort f2bf_rne(float x) {
  uint u = __float_as_uint(x);
  return (ushort)((u + 0x7fffu + ((u >> 16) & 1u)) >> 16);
}

__global__ __launch_bounds__(256) void mfma_extract(const float* __restrict__ Qn,
                                                    const float* __restrict__ Kn,
                                                    float* __restrict__ candv,
                                                    ushort* __restrict__ candi,
                                                    CallTab tab) {
  __shared__ ushort ldsA[4 * HPAD * 8];
  __shared__ ushort ldsB[4 * HPAD * 8];

  const int z = blockIdx.z;
  const int c = z >> 3, b = z & 7;
  const float* A = Qn + (long)tab.qi[c] * BAND_ELEMS + (long)b * N_ * D_;
  const float* Bm = Kn + (long)tab.ki[c] * BAND_ELEMS + (long)b * N_ * D_;
  const int m0 = blockIdx.y * SBM, n0 = blockIdx.x * SBN;

  const int t = threadIdx.x;
  const int lane = t & 63;
  const int wm = t >> 6;
  const int fr = lane & 15, fh = lane >> 4;

  f32x4 acc[2][8] = {};

  const int sg_r[2] = {t >> 2, (t + 256) >> 2};
  const int sg_h = t & 3;

  for (int k0 = 0; k0 < D_; k0 += SBK) {
    uint4 ga[2][2], gb[2][2];
#pragma unroll
    for (int it = 0; it < 2; ++it) {
      const float* pa = A + (long)(m0 + sg_r[it]) * D_ + k0 + sg_h * 8;
      ga[it][0] = *(const uint4*)pa;
      ga[it][1] = *(const uint4*)(pa + 4);
      const float* pb = Bm + (long)(n0 + sg_r[it]) * D_ + k0 + sg_h * 8;
      gb[it][0] = *(const uint4*)pb;
      gb[it][1] = *(const uint4*)(pb + 4);
    }
    __syncthreads();
#pragma unroll
    for (int it = 0; it < 2; ++it) {
      uint wa[8] = {ga[it][0].x, ga[it][0].y, ga[it][0].z, ga[it][0].w,
                    ga[it][1].x, ga[it][1].y, ga[it][1].z, ga[it][1].w};
      uint wb[8] = {gb[it][0].x, gb[it][0].y, gb[it][0].z, gb[it][0].w,
                    gb[it][1].x, gb[it][1].y, gb[it][1].z, gb[it][1].w};
      ushort8 va, vb;
#pragma unroll
      for (int e = 0; e < 8; ++e) {
        va[e] = f2bf_rne(__uint_as_float(wa[e]));
        vb[e] = f2bf_rne(__uint_as_float(wb[e]));
      }
      const int dst = (sg_h * HPAD + sg_r[it]) * 8;
      *(ushort8*)&ldsA[dst] = va;
      *(ushort8*)&ldsB[dst] = vb;
    }
    __syncthreads();

    bf16x8 af[2], bf[8];
#pragma unroll
    for (int i = 0; i < 2; ++i)
      af[i] = *(const bf16x8*)&ldsA[(fh * HPAD + wm * 32 + i * 16 + fr) * 8];
#pragma unroll
    for (int j = 0; j < 8; ++j)
      bf[j] = *(const bf16x8*)&ldsB[(fh * HPAD + j * 16 + fr) * 8];

#pragma unroll
    for (int i = 0; i < 2; ++i)
#pragma unroll
      for (int j = 0; j < 8; ++j)
        acc[i][j] = __builtin_amdgcn_mfma_f32_16x16x32_bf16(af[i], bf[j], acc[i][j], 0, 0, 0);
  }

#pragma unroll
  for (int i = 0; i < 2; ++i)
#pragma unroll
    for (int rr = 0; rr < 4; ++rr) {
      const int R = b * N_ + m0 + wm * 32 + i * 16 + fh * 4 + rr;
      const long base = (((long)c * 8192 + R) * 8 + blockIdx.x) * 8;
#pragma unroll
      for (int it = 0; it < 8; ++it) {
        float lv = acc[i][0][rr]; int lj = 0;
#pragma unroll
        for (int j = 1; j < 8; ++j)
          if (acc[i][j][rr] > lv) { lv = acc[i][j][rr]; lj = j; }
        int li = lj * 16 + fr;
#pragma unroll
        for (int m = 1; m < 16; m <<= 1) {
          float ov = __shfl_xor(lv, m);
          int oi = __shfl_xor(li, m);
          if (ov > lv || (ov == lv && oi < li)) { lv = ov; li = oi; }
        }
        if (fr == it) { candv[base + it] = lv; candi[base + it] = (ushort)(n0 + li); }
        if (fr == (li & 15)) {
#pragma unroll
          for (int j = 0; j < 8; ++j)
            if (j == (li >> 4)) acc[i][j][rr] = -INFINITY;
        }
      }
    }
}

// ---------------------------------------------------------------------------
// STAGE 2 v5: identical fmaf chain to R7-R10. K/Q staged HBM->LDS directly via
// global_load_lds (no VGPR round-trip => nothing to spill; R8-R10 wrote 5 GB
// of scratch through the prefetch registers). Wave-private LDS regions, no
// barriers; double-buffered chunks with counted vmcnt(5).
// LDS granule layout: (row r, k-quad q) at base + (q*16 + r)*16B  => compute
// ds_read_b128 is 2-way bank (free); gload_lds dest stays linear (rule #21:
// mapping is applied on the per-lane SOURCE address).
// ---------------------------------------------------------------------------
#define RRBLOCKS (NCALLS * 8192 / 4)       // 38912 = 8 * 4864

#define GLOAD16(gsrc, ldst)                                                   \
  __builtin_amdgcn_global_load_lds(                                          \
      (const __attribute__((address_space(1))) void*)(gsrc),                 \
      (__attribute__((address_space(3))) void*)(ldst), 16, 0, 0)
#define GLOAD4(gsrc, ldst)                                                    \
  __builtin_amdgcn_global_load_lds(                                          \
      (const __attribute__((address_space(1))) void*)(gsrc),                 \
      (__attribute__((address_space(3))) void*)(ldst), 4, 0, 0)

__global__ __launch_bounds__(256) void rerank_exact(const float* __restrict__ Qn,
                                                    const float* __restrict__ Kn,
                                                    const float* __restrict__ candv,
                                                    const ushort* __restrict__ candi,
                                                    float* __restrict__ fp,
                                                    int* __restrict__ fi,
                                                    float* __restrict__ out,
                                                    CallTab tab) {
  __shared__ float sbuf[4][2][1088];   // per wave, per buf: 1024 K + 64 Q floats

  const int bid = blockIdx.x;
  const int blk = (bid & 7) * (RRBLOCKS / 8) + (bid >> 3);

  const int w = threadIdx.x >> 6, lane = threadIdx.x & 63;
  const long gr = (long)blk * 4 + w;      // 0..19*8192-1
  const int c = (int)(gr >> 13);
  const int R = (int)(gr & 8191);
  const int b = R >> 10;

  const long cb = gr * 64;
  float cv = candv[cb + lane];
  int ci = (int)candi[cb + lane];

  // approx top-16 of the 64 candidates (comparator & retire verbatim R7-R10)
  int myi = 0;
#pragma unroll
  for (int it = 0; it < 16; ++it) {
    float lv = cv; int gi = ci;
#pragma unroll
    for (int m = 1; m < 64; m <<= 1) {
      float ov = __shfl_xor(lv, m);
      int oi = __shfl_xor(gi, m);
      if (ov > lv || (ov == lv && oi < gi)) { lv = ov; gi = oi; }
    }
    if ((lane & 15) == it) myi = gi;
    if (ci == gi) cv = -INFINITY;
  }

  const int mycand = lane & 15;            // candidate rank for this lane
  const int eidx = __shfl(myi, mycand);    // its K-row index (registers only)

  const float* qrow = Qn + (long)tab.qi[c] * BAND_ELEMS + (long)R * D_;
  // lane's gload source: row = rank (lane&15), k-quad = i*4 + (lane>>4)
  const float* ksrc0 = Kn + (long)tab.ki[c] * BAND_ELEMS +
                       ((long)(b << 10) + eidx) * D_ + ((lane >> 4) << 2);

#define STAGE(bb, ch)                                                         \
  do {                                                                        \
    float* base_ = &sbuf[w][bb][0];                                           \
    GLOAD16(ksrc0 + (ch) * 64 + 0,  base_ + 0);                               \
    GLOAD16(ksrc0 + (ch) * 64 + 16, base_ + 256);                             \
    GLOAD16(ksrc0 + (ch) * 64 + 32, base_ + 512);                             \
    GLOAD16(ksrc0 + (ch) * 64 + 48, base_ + 768);                             \
    GLOAD4(qrow + (ch) * 64 + lane, base_ + 1024);                            \
  } while (0)

  float acc = 0.f;
  STAGE(0, 0);
#pragma unroll
  for (int ch = 0; ch < 8; ++ch) {
    if (ch < 7) {
      STAGE((ch + 1) & 1, ch + 1);
      asm volatile("s_waitcnt vmcnt(5)" ::: "memory");
    } else {
      asm volatile("s_waitcnt vmcnt(0)" ::: "memory");
    }
    const float* kb2 = &sbuf[w][ch & 1][0];
    const float* qb2 = &sbuf[w][ch & 1][1024];
    // exact chain: k ascending, x,y,z,w within quad (bit-identical to R7-R10)
#pragma unroll
    for (int kq = 0; kq < 16; ++kq) {
      float4 kv = *(const float4*)(kb2 + kq * 64 + mycand * 4);
      float4 qv = *(const float4*)(qb2 + kq * 4);
      acc = fmaf(qv.x, kv.x, acc);
      acc = fmaf(qv.y, kv.y, acc);
      acc = fmaf(qv.z, kv.z, acc);
      acc = fmaf(qv.w, kv.w, acc);
    }
  }
#undef STAGE

  // top-8 by exact value (verbatim: dup lanes tie exactly, retire by idx)
  float ev = acc; int ei = eidx;
  float sv[8]; int si[8];
#pragma unroll
  for (int it = 0; it < 8; ++it) {
    float lv = ev; int gi = ei;
#pragma unroll
    for (int m = 1; m < 64; m <<= 1) {
      float ov = __shfl_xor(lv, m);
      int oi = __shfl_xor(gi, m);
      if (ov > lv || (ov == lv && oi < gi)) { lv = ov; gi = oi; }
    }
    sv[it] = lv; si[it] = gi;
    if (ei == gi) ev = -INFINITY;
  }

  // softmax + entropy (verbatim)
  float p[8], sum = 0.f;
#pragma unroll
  for (int j = 0; j < 8; ++j) { p[j] = expf(sv[j] - sv[0]); sum += p[j]; }
  const float isum = 1.0f / sum;
  float H = 0.f;
#pragma unroll
  for (int j = 0; j < 8; ++j) { p[j] *= isum; H -= p[j] * logf(p[j] + 1e-9f); }

  if (lane == 0) {
    atomicAdd(out + OUT_MAIN + (long)c * B_ + b, H * (1.0f / (float)N_));
#pragma unroll
    for (int j = 0; j < 8; ++j) { fp[gr * 8 + j] = p[j]; fi[gr * 8 + j] = si[j]; }
  }
}

// ---- merge finals + PV + band add + out write (VERBATIM R7) -----------------
__global__ __launch_bounds__(256) void merge_pv(Ptrs8 bands,
                                                const float* __restrict__ fp,
                                                const int* __restrict__ fi,
                                                const float* __restrict__ V,
                                                float* __restrict__ out,
                                                MergeTab mt) {
  const int bb = blockIdx.y;
  const int w = threadIdx.x >> 6, lane = threadIdx.x & 63;
  const long R = (long)blockIdx.x * 4 + w;
  const int b = (int)(R >> 10);

  float4 o0 = {0, 0, 0, 0}, o1 = {0, 0, 0, 0};
  const int nc = mt.ncalls[bb];
  for (int s = 0; s < nc; ++s) {
    const int c = mt.calls[bb][s];
    const float wt = mt.wts[c];
    const int ki = mt.kis[c];
    const long fb = ((long)c * 8192 + R) * 8;
    float4 p0 = *(const float4*)(fp + fb);
    float4 p1 = *(const float4*)(fp + fb + 4);
    int4 i0 = *(const int4*)(fi + fb);
    int4 i1 = *(const int4*)(fi + fb + 4);
    float pj[8] = {p0.x, p0.y, p0.z, p0.w, p1.x, p1.y, p1.z, p1.w};
    int ij[8] = {i0.x, i0.y, i0.z, i0.w, i1.x, i1.y, i1.z, i1.w};
#pragma unroll
    for (int j = 0; j < 8; ++j) {
      const float pw = pj[j] * wt;
      const float4* vr = (const float4*)(V + (long)ki * BAND_ELEMS +
                                         ((long)(b << 10) + ij[j]) * D_);
      float4 x0 = vr[lane * 2], x1 = vr[lane * 2 + 1];
      o0.x += pw * x0.x; o0.y += pw * x0.y; o0.z += pw * x0.z; o0.w += pw * x0.w;
      o1.x += pw * x1.x; o1.y += pw * x1.y; o1.z += pw * x1.z; o1.w += pw * x1.w;
    }
  }

  const float4* src = (const float4*)(bands.p[bb] + R * D_);
  float4 s0 = src[lane * 2], s1 = src[lane * 2 + 1];
  s0.x += o0.x; s0.y += o0.y; s0.z += o0.z; s0.w += o0.w;
  s1.x += o1.x; s1.y += o1.y; s1.z += o1.z; s1.w += o1.w;
  float4* dst = (float4*)(out + (long)bb * BAND_ELEMS + R * D_);
  dst[lane * 2] = s0;
  dst[lane * 2 + 1] = s1;
}

// ---- zero the 152 entropy slots ---------------------------------------------
__global__ void init_eps(float* __restrict__ out) {
  if (threadIdx.x < NCALLS * B_) out[OUT_MAIN + threadIdx.x] = 0.f;
}

// --------------------------------------------------------------------------------
extern "C" void kernel_launch(void* const* d_in, const int* in_sizes, int n_in,
                              void* d_out, int out_size, void* d_ws, size_t ws_size,
                              hipStream_t stream) {
  Ptrs8 bands;
  for (int i = 0; i < 8; ++i) bands.p[i] = (const float*)d_in[i];
  const float* qW = (const float*)d_in[8];
  const float* qb = (const float*)d_in[9];
  const float* kW = (const float*)d_in[10];
  const float* kb = (const float*)d_in[11];
  const float* vW = (const float*)d_in[12];
  const float* vb = (const float*)d_in[13];
  float* out = (float*)d_out;
  float* ws = (float*)d_ws;

  float* Qn = ws;
  float* Kn = ws + (long)8 * BAND_ELEMS;
  float* V  = ws + (long)16 * BAND_ELEMS;
  float* candv = ws + (long)24 * BAND_ELEMS;
  ushort* candi = (ushort*)(candv + (long)NCALLS * 8192 * 64);
  float* fp = (float*)(candi + (long)NCALLS * 8192 * 64);
  int* fi = (int*)(fp + (long)NCALLS * 8192 * 8);

  static const int calls[NCALLS][2] = {
      {6, 0}, {0, 6}, {5, 1}, {1, 5}, {4, 2}, {2, 4},
      {0, 3}, {1, 3}, {2, 3}, {4, 3}, {5, 3}, {6, 3},
      {0, 7}, {1, 7}, {2, 7}, {3, 7}, {4, 7}, {5, 7}, {6, 7}};

  CallTab tab;
  MergeTab mt;
  for (int i = 0; i < 8; ++i) mt.ncalls[i] = 0;
  for (int c = 0; c < NCALLS; ++c) {
    tab.qi[c] = calls[c][0];
    tab.ki[c] = calls[c][1];
    mt.kis[c] = calls[c][1];
    mt.wts[c] = (c < 6) ? 1.0f : 0.5f;
    int q = calls[c][0];
    mt.calls[q][mt.ncalls[q]++] = c;
  }

  hipLaunchKernelGGL(init_eps, dim3(1), dim3(256), 0, stream, out);

  dim3 gp(D_ / BN, (B_ * N_) / BM, 24);
  hipLaunchKernelGGL(gemm_proj_all, gp, dim3(256), 0, stream,
                     bands, qW, kW, vW, qb, kb, vb, Qn, Kn, V);

  hipLaunchKernelGGL(l2norm_rows, dim3(2 * 8 * B_ * N_ / 4), dim3(256), 0, stream, Qn);

  dim3 gs(N_ / SBN, N_ / SBM, NCALLS * 8);
  hipLaunchKernelGGL(mfma_extract, gs, dim3(256), 0, stream, Qn, Kn, candv, candi, tab);

  hipLaunchKernelGGL(rerank_exact, dim3(RRBLOCKS), dim3(256), 0, stream,
                     Qn, Kn, candv, candi, fp, fi, out, tab);

  hipLaunchKernelGGL(merge_pv, dim3(B_ * N_ / 4, 8), dim3(256), 0, stream,
                     bands, fp, fi, V, out, mt);
}

// Round 12
// 3761.732 us; speedup vs baseline: 1.4619x; 1.0044x over previous
//
#include <hip/hip_runtime.h>
#include <math.h>

#define B_ 8
#define N_ 1024
#define D_ 512
#define BAND_ELEMS (B_ * N_ * D_)          // 4194304 = 2^22
#define OUT_MAIN (8L * BAND_ELEMS)         // 33554432
#define NCALLS 19

struct Ptrs8 { const float* p[8]; };
struct CallTab { int qi[NCALLS]; int ki[NCALLS]; };
struct MergeTab { int ncalls[8]; int calls[8][3]; int kis[NCALLS]; float wts[NCALLS]; };

typedef __attribute__((ext_vector_type(8))) short bf16x8;
typedef __attribute__((ext_vector_type(8))) ushort ushort8;
typedef __attribute__((ext_vector_type(4))) float f32x4;

__device__ __forceinline__ ushort f2bf_rne(float x) {
  uint u = __float_as_uint(x);
  return (ushort)((u + 0x7fffu + ((u >> 16) & 1u)) >> 16);
}

#define GLOAD16(gsrc, ldst)                                                   \
  __builtin_amdgcn_global_load_lds(                                          \
      (const __attribute__((address_space(1))) void*)(gsrc),                 \
      (__attribute__((address_space(3))) void*)(ldst), 16, 0, 0)
#define GLOAD4(gsrc, ldst)                                                    \
  __builtin_amdgcn_global_load_lds(                                          \
      (const __attribute__((address_space(1))) void*)(gsrc),                 \
      (__attribute__((address_space(3))) void*)(ldst), 4, 0, 0)

// ---------------------------------------------------------------------------
// fp32 GEMM core (VERBATIM R5/R6 — bit-exact contract: sequential-k fp32 fma
// chain per output). Used ONLY for the projections.
// ---------------------------------------------------------------------------
#define BM 128
#define BN 128
#define BK 16
#define LDP 132

__device__ __forceinline__ int bgran(int g) {
  return (g & ~7) | ((g + (g >> 3)) & 7);
}

__device__ __forceinline__ void gemm_core(const float* __restrict__ A,
                                          const float* __restrict__ Bm,
                                          int m0, int n0, int K,
                                          float (&acc)[8][8]) {
  __shared__ float As[BK * LDP];
  __shared__ float Bs[BK * LDP];

  const int t = threadIdx.x;
  const int tx = t & 15, ty = t >> 4;
  const int rs = t >> 2;
  const int cs = t & 3;

  float4 pa[2], pb[2];
#pragma unroll
  for (int it = 0; it < 2; ++it) {
    pa[it] = *(const float4*)(A + (long)(m0 + rs + 64 * it) * K + cs * 4);
    pb[it] = *(const float4*)(Bm + (long)(n0 + rs + 64 * it) * K + cs * 4);
  }

  for (int k0 = 0; k0 < K; k0 += BK) {
    __syncthreads();
    {
      const int sa = ((cs & 1) << 2);
      const int base = cs * 4 * LDP;
#pragma unroll
      for (int it = 0; it < 2; ++it) {
        const int r = rs + 64 * it;
        const int ra = r ^ sa;
        As[base + 0 * LDP + ra] = pa[it].x;
        As[base + 1 * LDP + ra] = pa[it].y;
        As[base + 2 * LDP + ra] = pa[it].z;
        As[base + 3 * LDP + ra] = pa[it].w;
        const int rb = bgran(r >> 2) * 4 + (r & 3);
        Bs[base + 0 * LDP + rb] = pb[it].x;
        Bs[base + 1 * LDP + rb] = pb[it].y;
        Bs[base + 2 * LDP + rb] = pb[it].z;
        Bs[base + 3 * LDP + rb] = pb[it].w;
      }
    }
    __syncthreads();

    if (k0 + BK < K) {
#pragma unroll
      for (int it = 0; it < 2; ++it) {
        pa[it] = *(const float4*)(A + (long)(m0 + rs + 64 * it) * K + k0 + BK + cs * 4);
        pb[it] = *(const float4*)(Bm + (long)(n0 + rs + 64 * it) * K + k0 + BK + cs * 4);
      }
    }

#pragma unroll
    for (int kk = 0; kk < BK; ++kk) {
      const int c1 = (kk >> 2) & 1;
      float a[8], b[8];
      {
        float4 u = *(const float4*)&As[kk * LDP + ty * 8 + c1 * 4];
        float4 v = *(const float4*)&As[kk * LDP + ty * 8 + 4 - c1 * 4];
        a[0] = u.x; a[1] = u.y; a[2] = u.z; a[3] = u.w;
        a[4] = v.x; a[5] = v.y; a[6] = v.z; a[7] = v.w;
        float4 p = *(const float4*)&Bs[kk * LDP + bgran(2 * tx) * 4];
        float4 q = *(const float4*)&Bs[kk * LDP + bgran(2 * tx + 1) * 4];
        b[0] = p.x; b[1] = p.y; b[2] = p.z; b[3] = p.w;
        b[4] = q.x; b[5] = q.y; b[6] = q.z; b[7] = q.w;
      }
#pragma unroll
      for (int i = 0; i < 8; ++i)
#pragma unroll
        for (int j = 0; j < 8; ++j) acc[i][j] = fmaf(a[i], b[j], acc[i][j]);
    }
  }
}

// ---- all 24 projections in one launch: z = mat*8 + band (VERBATIM R6) ------
__global__ __launch_bounds__(256) void gemm_proj_all(Ptrs8 bands,
                                                     const float* __restrict__ qW,
                                                     const float* __restrict__ kW,
                                                     const float* __restrict__ vW,
                                                     const float* __restrict__ qb,
                                                     const float* __restrict__ kb,
                                                     const float* __restrict__ vb,
                                                     float* __restrict__ Qn,
                                                     float* __restrict__ Kn,
                                                     float* __restrict__ V) {
  const int mat = blockIdx.z >> 3, band = blockIdx.z & 7;
  const float* W = (mat == 0) ? qW : (mat == 1) ? kW : vW;
  const float* bvec = (mat == 0) ? qb : (mat == 1) ? kb : vb;
  float* dst = (mat == 0) ? Qn : (mat == 1) ? Kn : V;
  W += (long)band * D_ * D_;
  bvec += band * D_;
  dst += (long)band * BAND_ELEMS;

  const int m0 = blockIdx.y * BM, n0 = blockIdx.x * BN;
  float acc[8][8] = {};
  gemm_core(bands.p[band], W, m0, n0, D_, acc);

  const int t = threadIdx.x;
  const int tx = t & 15, ty = t >> 4;
#pragma unroll
  for (int i = 0; i < 8; ++i) {
    float* crow = dst + (long)(m0 + ty * 8 + i) * D_ + n0 + tx * 8;
    const float* bp = bvec + n0 + tx * 8;
    float4 r0, r1;
    r0.x = acc[i][0] + bp[0]; r0.y = acc[i][1] + bp[1];
    r0.z = acc[i][2] + bp[2]; r0.w = acc[i][3] + bp[3];
    r1.x = acc[i][4] + bp[4]; r1.y = acc[i][5] + bp[5];
    r1.z = acc[i][6] + bp[6]; r1.w = acc[i][7] + bp[7];
    ((float4*)crow)[0] = r0;
    ((float4*)crow)[1] = r1;
  }
}

// ---- L2 normalization; also emits bf16 copy (same f2bf_rne bits the old
// ---- extract computed inline) when bf != nullptr --------------------------
__global__ __launch_bounds__(256) void l2norm_rows(float* __restrict__ X,
                                                   ushort* __restrict__ bf) {
  const long row = (long)blockIdx.x * 4 + (threadIdx.x >> 6);
  const int lane = threadIdx.x & 63;
  float* p = X + row * D_;
  float4 a = ((float4*)p)[lane];
  float4 b = ((float4*)p)[lane + 64];
  float s = a.x * a.x + a.y * a.y + a.z * a.z + a.w * a.w +
            b.x * b.x + b.y * b.y + b.z * b.z + b.w * b.w;
#pragma unroll
  for (int m = 1; m < 64; m <<= 1) s += __shfl_xor(s, m);
  const float inv = 1.0f / fmaxf(sqrtf(s), 1e-12f);
  a.x *= inv; a.y *= inv; a.z *= inv; a.w *= inv;
  b.x *= inv; b.y *= inv; b.z *= inv; b.w *= inv;
  ((float4*)p)[lane] = a;
  ((float4*)p)[lane + 64] = b;
  if (bf) {
    ushort4 w0, w1;
    w0.x = f2bf_rne(a.x); w0.y = f2bf_rne(a.y); w0.z = f2bf_rne(a.z); w0.w = f2bf_rne(a.w);
    w1.x = f2bf_rne(b.x); w1.y = f2bf_rne(b.y); w1.z = f2bf_rne(b.z); w1.w = f2bf_rne(b.w);
    *(ushort4*)(bf + row * D_ + lane * 4) = w0;
    *(ushort4*)(bf + row * D_ + 256 + lane * 4) = w1;
  }
}

// ---------------------------------------------------------------------------
// STAGE 1 (fast): bf16 MFMA approx scores from PRE-CONVERTED bf16 Q/K, staged
// HBM->LDS via global_load_lds (no conversion VALU, no VGPR round-trip).
// LDS granules: [oct*128 + row] of 16B (= 8 bf16); double-buffered.
// Per-lane source = row-major addr of granule g = it*256 + t; dest linear
// (rule #21: mapping applied on the SOURCE address). Frags/MFMA/extraction
// epilogue VERBATIM R7 -> bit-identical candidates.
// ---------------------------------------------------------------------------
#define SBM 128
#define SBN 128

__global__ __launch_bounds__(256) void mfma_extract_bf(const ushort* __restrict__ Qbf,
                                                       const ushort* __restrict__ Kbf,
                                                       float* __restrict__ candv,
                                                       ushort* __restrict__ candi,
                                                       CallTab tab) {
  __shared__ ushort ldsA[2][4096];
  __shared__ ushort ldsB[2][4096];

  const int z = blockIdx.z;
  const int c = z >> 3, b = z & 7;
  const ushort* A = Qbf + (long)tab.qi[c] * BAND_ELEMS + (long)b * N_ * D_;
  const ushort* Bm = Kbf + (long)tab.ki[c] * BAND_ELEMS + (long)b * N_ * D_;
  const int m0 = blockIdx.y * SBM, n0 = blockIdx.x * SBN;

  const int t = threadIdx.x;
  const int lane = t & 63;
  const int wm = t >> 6;
  const int fr = lane & 15, fh = lane >> 4;

  f32x4 acc[2][8] = {};

#define XSTAGE(bb, k0)                                                        \
  do {                                                                        \
    _Pragma("unroll")                                                         \
    for (int it_ = 0; it_ < 2; ++it_) {                                       \
      const int g_ = it_ * 256 + t;                                           \
      const int row_ = g_ & 127, oct_ = g_ >> 7;                              \
      GLOAD16(A + (long)(m0 + row_) * D_ + (k0) + oct_ * 8,                   \
              &ldsA[bb][(it_ * 256 + wm * 64) * 8]);                          \
      GLOAD16(Bm + (long)(n0 + row_) * D_ + (k0) + oct_ * 8,                  \
              &ldsB[bb][(it_ * 256 + wm * 64) * 8]);                          \
    }                                                                         \
  } while (0)

  int buf = 0;
  XSTAGE(0, 0);
  asm volatile("s_waitcnt vmcnt(0)" ::: "memory");
  __syncthreads();

  for (int kq = 0; kq < 16; ++kq) {
    if (kq < 15) XSTAGE(buf ^ 1, (kq + 1) * 32);

    bf16x8 af[2], bfr[8];
#pragma unroll
    for (int i = 0; i < 2; ++i)
      af[i] = *(const bf16x8*)&ldsA[buf][(fh * 128 + wm * 32 + i * 16 + fr) * 8];
#pragma unroll
    for (int j = 0; j < 8; ++j)
      bfr[j] = *(const bf16x8*)&ldsB[buf][(fh * 128 + j * 16 + fr) * 8];

#pragma unroll
    for (int i = 0; i < 2; ++i)
#pragma unroll
      for (int j = 0; j < 8; ++j)
        acc[i][j] = __builtin_amdgcn_mfma_f32_16x16x32_bf16(af[i], bfr[j], acc[i][j], 0, 0, 0);

    asm volatile("s_waitcnt vmcnt(0)" ::: "memory");
    __syncthreads();
    buf ^= 1;
  }
#undef XSTAGE

  // ---- per-tile top-8 extraction (VERBATIM R7) ----
#pragma unroll
  for (int i = 0; i < 2; ++i)
#pragma unroll
    for (int rr = 0; rr < 4; ++rr) {
      const int R = b * N_ + m0 + wm * 32 + i * 16 + fh * 4 + rr;
      const long base = (((long)c * 8192 + R) * 8 + blockIdx.x) * 8;
#pragma unroll
      for (int it = 0; it < 8; ++it) {
        float lv = acc[i][0][rr]; int lj = 0;
#pragma unroll
        for (int j = 1; j < 8; ++j)
          if (acc[i][j][rr] > lv) { lv = acc[i][j][rr]; lj = j; }
        int li = lj * 16 + fr;
#pragma unroll
        for (int m = 1; m < 16; m <<= 1) {
          float ov = __shfl_xor(lv, m);
          int oi = __shfl_xor(li, m);
          if (ov > lv || (ov == lv && oi < li)) { lv = ov; li = oi; }
        }
        if (fr == it) { candv[base + it] = lv; candi[base + it] = (ushort)(n0 + li); }
        if (fr == (li & 15)) {
#pragma unroll
          for (int j = 0; j < 8; ++j)
            if (j == (li >> 4)) acc[i][j][rr] = -INFINITY;
        }
      }
    }
}

// ---------------------------------------------------------------------------
// STAGE 1 (fallback, VERBATIM R11): used when ws_size can't fit bf16 buffers.
// ---------------------------------------------------------------------------
#define SBK 32
#define HPAD 132

__global__ __launch_bounds__(256) void mfma_extract(const float* __restrict__ Qn,
                                                    const float* __restrict__ Kn,
                                                    float* __restrict__ candv,
                                                    ushort* __restrict__ candi,
                                                    CallTab tab) {
  __shared__ ushort ldsA[4 * HPAD * 8];
  __shared__ ushort ldsB[4 * HPAD * 8];

  const int z = blockIdx.z;
  const int c = z >> 3, b = z & 7;
  const float* A = Qn + (long)tab.qi[c] * BAND_ELEMS + (long)b * N_ * D_;
  const float* Bm = Kn + (long)tab.ki[c] * BAND_ELEMS + (long)b * N_ * D_;
  const int m0 = blockIdx.y * SBM, n0 = blockIdx.x * SBN;

  const int t = threadIdx.x;
  const int lane = t & 63;
  const int wm = t >> 6;
  const int fr = lane & 15, fh = lane >> 4;

  f32x4 acc[2][8] = {};

  const int sg_r[2] = {t >> 2, (t + 256) >> 2};
  const int sg_h = t & 3;

  for (int k0 = 0; k0 < D_; k0 += SBK) {
    uint4 ga[2][2], gb[2][2];
#pragma unroll
    for (int it = 0; it < 2; ++it) {
      const float* pa = A + (long)(m0 + sg_r[it]) * D_ + k0 + sg_h * 8;
      ga[it][0] = *(const uint4*)pa;
      ga[it][1] = *(const uint4*)(pa + 4);
      const float* pb = Bm + (long)(n0 + sg_r[it]) * D_ + k0 + sg_h * 8;
      gb[it][0] = *(const uint4*)pb;
      gb[it][1] = *(const uint4*)(pb + 4);
    }
    __syncthreads();
#pragma unroll
    for (int it = 0; it < 2; ++it) {
      uint wa[8] = {ga[it][0].x, ga[it][0].y, ga[it][0].z, ga[it][0].w,
                    ga[it][1].x, ga[it][1].y, ga[it][1].z, ga[it][1].w};
      uint wb[8] = {gb[it][0].x, gb[it][0].y, gb[it][0].z, gb[it][0].w,
                    gb[it][1].x, gb[it][1].y, gb[it][1].z, gb[it][1].w};
      ushort8 va, vb;
#pragma unroll
      for (int e = 0; e < 8; ++e) {
        va[e] = f2bf_rne(__uint_as_float(wa[e]));
        vb[e] = f2bf_rne(__uint_as_float(wb[e]));
      }
      const int dst = (sg_h * HPAD + sg_r[it]) * 8;
      *(ushort8*)&ldsA[dst] = va;
      *(ushort8*)&ldsB[dst] = vb;
    }
    __syncthreads();

    bf16x8 af[2], bf[8];
#pragma unroll
    for (int i = 0; i < 2; ++i)
      af[i] = *(const bf16x8*)&ldsA[(fh * HPAD + wm * 32 + i * 16 + fr) * 8];
#pragma unroll
    for (int j = 0; j < 8; ++j)
      bf[j] = *(const bf16x8*)&ldsB[(fh * HPAD + j * 16 + fr) * 8];

#pragma unroll
    for (int i = 0; i < 2; ++i)
#pragma unroll
      for (int j = 0; j < 8; ++j)
        acc[i][j] = __builtin_amdgcn_mfma_f32_16x16x32_bf16(af[i], bf[j], acc[i][j], 0, 0, 0);
  }

#pragma unroll
  for (int i = 0; i < 2; ++i)
#pragma unroll
    for (int rr = 0; rr < 4; ++rr) {
      const int R = b * N_ + m0 + wm * 32 + i * 16 + fh * 4 + rr;
      const long base = (((long)c * 8192 + R) * 8 + blockIdx.x) * 8;
#pragma unroll
      for (int it = 0; it < 8; ++it) {
        float lv = acc[i][0][rr]; int lj = 0;
#pragma unroll
        for (int j = 1; j < 8; ++j)
          if (acc[i][j][rr] > lv) { lv = acc[i][j][rr]; lj = j; }
        int li = lj * 16 + fr;
#pragma unroll
        for (int m = 1; m < 16; m <<= 1) {
          float ov = __shfl_xor(lv, m);
          int oi = __shfl_xor(li, m);
          if (ov > lv || (ov == lv && oi < li)) { lv = ov; li = oi; }
        }
        if (fr == it) { candv[base + it] = lv; candi[base + it] = (ushort)(n0 + li); }
        if (fr == (li & 15)) {
#pragma unroll
          for (int j = 0; j < 8; ++j)
            if (j == (li >> 4)) acc[i][j][rr] = -INFINITY;
        }
      }
    }
}

// ---------------------------------------------------------------------------
// STAGE 2 (VERBATIM R11): exact fp32 chains, K/Q staged via global_load_lds.
// ---------------------------------------------------------------------------
#define RRBLOCKS (NCALLS * 8192 / 4)       // 38912 = 8 * 4864

__global__ __launch_bounds__(256) void rerank_exact(const float* __restrict__ Qn,
                                                    const float* __restrict__ Kn,
                                                    const float* __restrict__ candv,
                                                    const ushort* __restrict__ candi,
                                                    float* __restrict__ fp,
                                                    int* __restrict__ fi,
                                                    float* __restrict__ out,
                                                    CallTab tab) {
  __shared__ float sbuf[4][2][1088];

  const int bid = blockIdx.x;
  const int blk = (bid & 7) * (RRBLOCKS / 8) + (bid >> 3);

  const int w = threadIdx.x >> 6, lane = threadIdx.x & 63;
  const long gr = (long)blk * 4 + w;
  const int c = (int)(gr >> 13);
  const int R = (int)(gr & 8191);
  const int b = R >> 10;

  const long cb = gr * 64;
  float cv = candv[cb + lane];
  int ci = (int)candi[cb + lane];

  int myi = 0;
#pragma unroll
  for (int it = 0; it < 16; ++it) {
    float lv = cv; int gi = ci;
#pragma unroll
    for (int m = 1; m < 64; m <<= 1) {
      float ov = __shfl_xor(lv, m);
      int oi = __shfl_xor(gi, m);
      if (ov > lv || (ov == lv && oi < gi)) { lv = ov; gi = oi; }
    }
    if ((lane & 15) == it) myi = gi;
    if (ci == gi) cv = -INFINITY;
  }

  const int mycand = lane & 15;
  const int eidx = __shfl(myi, mycand);

  const float* qrow = Qn + (long)tab.qi[c] * BAND_ELEMS + (long)R * D_;
  const float* ksrc0 = Kn + (long)tab.ki[c] * BAND_ELEMS +
                       ((long)(b << 10) + eidx) * D_ + ((lane >> 4) << 2);

#define STAGE(bb, ch)                                                         \
  do {                                                                        \
    float* base_ = &sbuf[w][bb][0];                                           \
    GLOAD16(ksrc0 + (ch) * 64 + 0,  base_ + 0);                               \
    GLOAD16(ksrc0 + (ch) * 64 + 16, base_ + 256);                             \
    GLOAD16(ksrc0 + (ch) * 64 + 32, base_ + 512);                             \
    GLOAD16(ksrc0 + (ch) * 64 + 48, base_ + 768);                             \
    GLOAD4(qrow + (ch) * 64 + lane, base_ + 1024);                            \
  } while (0)

  float acc = 0.f;
  STAGE(0, 0);
#pragma unroll
  for (int ch = 0; ch < 8; ++ch) {
    if (ch < 7) {
      STAGE((ch + 1) & 1, ch + 1);
      asm volatile("s_waitcnt vmcnt(5)" ::: "memory");
    } else {
      asm volatile("s_waitcnt vmcnt(0)" ::: "memory");
    }
    const float* kb2 = &sbuf[w][ch & 1][0];
    const float* qb2 = &sbuf[w][ch & 1][1024];
#pragma unroll
    for (int kq = 0; kq < 16; ++kq) {
      float4 kv = *(const float4*)(kb2 + kq * 64 + mycand * 4);
      float4 qv = *(const float4*)(qb2 + kq * 4);
      acc = fmaf(qv.x, kv.x, acc);
      acc = fmaf(qv.y, kv.y, acc);
      acc = fmaf(qv.z, kv.z, acc);
      acc = fmaf(qv.w, kv.w, acc);
    }
  }
#undef STAGE

  float ev = acc; int ei = eidx;
  float sv[8]; int si[8];
#pragma unroll
  for (int it = 0; it < 8; ++it) {
    float lv = ev; int gi = ei;
#pragma unroll
    for (int m = 1; m < 64; m <<= 1) {
      float ov = __shfl_xor(lv, m);
      int oi = __shfl_xor(gi, m);
      if (ov > lv || (ov == lv && oi < gi)) { lv = ov; gi = oi; }
    }
    sv[it] = lv; si[it] = gi;
    if (ei == gi) ev = -INFINITY;
  }

  float p[8], sum = 0.f;
#pragma unroll
  for (int j = 0; j < 8; ++j) { p[j] = expf(sv[j] - sv[0]); sum += p[j]; }
  const float isum = 1.0f / sum;
  float H = 0.f;
#pragma unroll
  for (int j = 0; j < 8; ++j) { p[j] *= isum; H -= p[j] * logf(p[j] + 1e-9f); }

  if (lane == 0) {
    atomicAdd(out + OUT_MAIN + (long)c * B_ + b, H * (1.0f / (float)N_));
#pragma unroll
    for (int j = 0; j < 8; ++j) { fp[gr * 8 + j] = p[j]; fi[gr * 8 + j] = si[j]; }
  }
}

// ---- merge finals + PV + band add + out write (VERBATIM R7) -----------------
__global__ __launch_bounds__(256) void merge_pv(Ptrs8 bands,
                                                const float* __restrict__ fp,
                                                const int* __restrict__ fi,
                                                const float* __restrict__ V,
                                                float* __restrict__ out,
                                                MergeTab mt) {
  const int bb = blockIdx.y;
  const int w = threadIdx.x >> 6, lane = threadIdx.x & 63;
  const long R = (long)blockIdx.x * 4 + w;
  const int b = (int)(R >> 10);

  float4 o0 = {0, 0, 0, 0}, o1 = {0, 0, 0, 0};
  const int nc = mt.ncalls[bb];
  for (int s = 0; s < nc; ++s) {
    const int c = mt.calls[bb][s];
    const float wt = mt.wts[c];
    const int ki = mt.kis[c];
    const long fb = ((long)c * 8192 + R) * 8;
    float4 p0 = *(const float4*)(fp + fb);
    float4 p1 = *(const float4*)(fp + fb + 4);
    int4 i0 = *(const int4*)(fi + fb);
    int4 i1 = *(const int4*)(fi + fb + 4);
    float pj[8] = {p0.x, p0.y, p0.z, p0.w, p1.x, p1.y, p1.z, p1.w};
    int ij[8] = {i0.x, i0.y, i0.z, i0.w, i1.x, i1.y, i1.z, i1.w};
#pragma unroll
    for (int j = 0; j < 8; ++j) {
      const float pw = pj[j] * wt;
      const float4* vr = (const float4*)(V + (long)ki * BAND_ELEMS +
                                         ((long)(b << 10) + ij[j]) * D_);
      float4 x0 = vr[lane * 2], x1 = vr[lane * 2 + 1];
      o0.x += pw * x0.x; o0.y += pw * x0.y; o0.z += pw * x0.z; o0.w += pw * x0.w;
      o1.x += pw * x1.x; o1.y += pw * x1.y; o1.z += pw * x1.z; o1.w += pw * x1.w;
    }
  }

  const float4* src = (const float4*)(bands.p[bb] + R * D_);
  float4 s0 = src[lane * 2], s1 = src[lane * 2 + 1];
  s0.x += o0.x; s0.y += o0.y; s0.z += o0.z; s0.w += o0.w;
  s1.x += o1.x; s1.y += o1.y; s1.z += o1.z; s1.w += o1.w;
  float4* dst = (float4*)(out + (long)bb * BAND_ELEMS + R * D_);
  dst[lane * 2] = s0;
  dst[lane * 2 + 1] = s1;
}

// ---- zero the 152 entropy slots ---------------------------------------------
__global__ void init_eps(float* __restrict__ out) {
  if (threadIdx.x < NCALLS * B_) out[OUT_MAIN + threadIdx.x] = 0.f;
}

// --------------------------------------------------------------------------------
extern "C" void kernel_launch(void* const* d_in, const int* in_sizes, int n_in,
                              void* d_out, int out_size, void* d_ws, size_t ws_size,
                              hipStream_t stream) {
  Ptrs8 bands;
  for (int i = 0; i < 8; ++i) bands.p[i] = (const float*)d_in[i];
  const float* qW = (const float*)d_in[8];
  const float* qb = (const float*)d_in[9];
  const float* kW = (const float*)d_in[10];
  const float* kb = (const float*)d_in[11];
  const float* vW = (const float*)d_in[12];
  const float* vb = (const float*)d_in[13];
  float* out = (float*)d_out;
  float* ws = (float*)d_ws;

  float* Qn = ws;
  float* Kn = ws + (long)8 * BAND_ELEMS;
  float* V  = ws + (long)16 * BAND_ELEMS;
  float* candv = ws + (long)24 * BAND_ELEMS;
  ushort* candi = (ushort*)(candv + (long)NCALLS * 8192 * 64);
  float* fp = (float*)(candi + (long)NCALLS * 8192 * 64);
  int* fi = (int*)(fp + (long)NCALLS * 8192 * 8);
  ushort* bfbuf = (ushort*)(fi + (long)NCALLS * 8192 * 8);   // 16 bands bf16

  const size_t NEED_FAST =
      (size_t)(24L * BAND_ELEMS) * 4 +
      (size_t)NCALLS * 8192 * 64 * (4 + 2) +
      (size_t)NCALLS * 8192 * 8 * (4 + 4) +
      (size_t)16L * BAND_ELEMS * 2;
  const bool fast = ws_size >= NEED_FAST;

  static const int calls[NCALLS][2] = {
      {6, 0}, {0, 6}, {5, 1}, {1, 5}, {4, 2}, {2, 4},
      {0, 3}, {1, 3}, {2, 3}, {4, 3}, {5, 3}, {6, 3},
      {0, 7}, {1, 7}, {2, 7}, {3, 7}, {4, 7}, {5, 7}, {6, 7}};

  CallTab tab;
  MergeTab mt;
  for (int i = 0; i < 8; ++i) mt.ncalls[i] = 0;
  for (int c = 0; c < NCALLS; ++c) {
    tab.qi[c] = calls[c][0];
    tab.ki[c] = calls[c][1];
    mt.kis[c] = calls[c][1];
    mt.wts[c] = (c < 6) ? 1.0f : 0.5f;
    int q = calls[c][0];
    mt.calls[q][mt.ncalls[q]++] = c;
  }

  hipLaunchKernelGGL(init_eps, dim3(1), dim3(256), 0, stream, out);

  dim3 gp(D_ / BN, (B_ * N_) / BM, 24);
  hipLaunchKernelGGL(gemm_proj_all, gp, dim3(256), 0, stream,
                     bands, qW, kW, vW, qb, kb, vb, Qn, Kn, V);

  hipLaunchKernelGGL(l2norm_rows, dim3(2 * 8 * B_ * N_ / 4), dim3(256), 0, stream,
                     Qn, fast ? bfbuf : (ushort*)nullptr);

  dim3 gs(N_ / SBN, N_ / SBM, NCALLS * 8);
  if (fast) {
    hipLaunchKernelGGL(mfma_extract_bf, gs, dim3(256), 0, stream,
                       bfbuf, bfbuf + (long)8 * BAND_ELEMS, candv, candi, tab);
  } else {
    hipLaunchKernelGGL(mfma_extract, gs, dim3(256), 0, stream,
                       Qn, Kn, candv, candi, tab);
  }

  hipLaunchKernelGGL(rerank_exact, dim3(RRBLOCKS), dim3(256), 0, stream,
                     Qn, Kn, candv, candi, fp, fi, out, tab);

  hipLaunchKernelGGL(merge_pv, dim3(B_ * N_ / 4, 8), dim3(256), 0, stream,
                     bands, fp, fi, V, out, mt);
}

// Round 13
// 3586.694 us; speedup vs baseline: 1.5332x; 1.0488x over previous
//
#include <hip/hip_runtime.h>
#include <math.h>

#define B_ 8
#define N_ 1024
#define D_ 512
#define BAND_ELEMS (B_ * N_ * D_)          // 4194304 = 2^22
#define OUT_MAIN (8L * BAND_ELEMS)         // 33554432
#define NCALLS 19

struct Ptrs8 { const float* p[8]; };
struct CallTab { int qi[NCALLS]; int ki[NCALLS]; };
struct MergeTab { int ncalls[8]; int calls[8][3]; int kis[NCALLS]; float wts[NCALLS]; };

typedef __attribute__((ext_vector_type(8))) short bf16x8;
typedef __attribute__((ext_vector_type(4))) float f32x4;

__device__ __forceinline__ ushort f2bf_rne(float x) {
  uint u = __float_as_uint(x);
  return (ushort)((u + 0x7fffu + ((u >> 16) & 1u)) >> 16);
}

#define GLOAD16(gsrc, ldst)                                                   \
  __builtin_amdgcn_global_load_lds(                                          \
      (const __attribute__((address_space(1))) void*)(gsrc),                 \
      (__attribute__((address_space(3))) void*)(ldst), 16, 0, 0)
#define GLOAD4(gsrc, ldst)                                                    \
  __builtin_amdgcn_global_load_lds(                                          \
      (const __attribute__((address_space(1))) void*)(gsrc),                 \
      (__attribute__((address_space(3))) void*)(ldst), 4, 0, 0)

// ---------------------------------------------------------------------------
// fp32 GEMM core (VERBATIM R5/R6 — bit-exact contract: sequential-k fp32 fma
// chain per output). Used ONLY for the projections.
// ---------------------------------------------------------------------------
#define BM 128
#define BN 128
#define BK 16
#define LDP 132

__device__ __forceinline__ int bgran(int g) {
  return (g & ~7) | ((g + (g >> 3)) & 7);
}

__device__ __forceinline__ void gemm_core(const float* __restrict__ A,
                                          const float* __restrict__ Bm,
                                          int m0, int n0, int K,
                                          float (&acc)[8][8]) {
  __shared__ float As[BK * LDP];
  __shared__ float Bs[BK * LDP];

  const int t = threadIdx.x;
  const int tx = t & 15, ty = t >> 4;
  const int rs = t >> 2;
  const int cs = t & 3;

  float4 pa[2], pb[2];
#pragma unroll
  for (int it = 0; it < 2; ++it) {
    pa[it] = *(const float4*)(A + (long)(m0 + rs + 64 * it) * K + cs * 4);
    pb[it] = *(const float4*)(Bm + (long)(n0 + rs + 64 * it) * K + cs * 4);
  }

  for (int k0 = 0; k0 < K; k0 += BK) {
    __syncthreads();
    {
      const int sa = ((cs & 1) << 2);
      const int base = cs * 4 * LDP;
#pragma unroll
      for (int it = 0; it < 2; ++it) {
        const int r = rs + 64 * it;
        const int ra = r ^ sa;
        As[base + 0 * LDP + ra] = pa[it].x;
        As[base + 1 * LDP + ra] = pa[it].y;
        As[base + 2 * LDP + ra] = pa[it].z;
        As[base + 3 * LDP + ra] = pa[it].w;
        const int rb = bgran(r >> 2) * 4 + (r & 3);
        Bs[base + 0 * LDP + rb] = pb[it].x;
        Bs[base + 1 * LDP + rb] = pb[it].y;
        Bs[base + 2 * LDP + rb] = pb[it].z;
        Bs[base + 3 * LDP + rb] = pb[it].w;
      }
    }
    __syncthreads();

    if (k0 + BK < K) {
#pragma unroll
      for (int it = 0; it < 2; ++it) {
        pa[it] = *(const float4*)(A + (long)(m0 + rs + 64 * it) * K + k0 + BK + cs * 4);
        pb[it] = *(const float4*)(Bm + (long)(n0 + rs + 64 * it) * K + k0 + BK + cs * 4);
      }
    }

#pragma unroll
    for (int kk = 0; kk < BK; ++kk) {
      const int c1 = (kk >> 2) & 1;
      float a[8], b[8];
      {
        float4 u = *(const float4*)&As[kk * LDP + ty * 8 + c1 * 4];
        float4 v = *(const float4*)&As[kk * LDP + ty * 8 + 4 - c1 * 4];
        a[0] = u.x; a[1] = u.y; a[2] = u.z; a[3] = u.w;
        a[4] = v.x; a[5] = v.y; a[6] = v.z; a[7] = v.w;
        float4 p = *(const float4*)&Bs[kk * LDP + bgran(2 * tx) * 4];
        float4 q = *(const float4*)&Bs[kk * LDP + bgran(2 * tx + 1) * 4];
        b[0] = p.x; b[1] = p.y; b[2] = p.z; b[3] = p.w;
        b[4] = q.x; b[5] = q.y; b[6] = q.z; b[7] = q.w;
      }
#pragma unroll
      for (int i = 0; i < 8; ++i)
#pragma unroll
        for (int j = 0; j < 8; ++j) acc[i][j] = fmaf(a[i], b[j], acc[i][j]);
    }
  }
}

__device__ __forceinline__ void proj_epilogue(float* __restrict__ dst,
                                              const float* __restrict__ bvec,
                                              int m0, int n0, float (&acc)[8][8]) {
  const int t = threadIdx.x;
  const int tx = t & 15, ty = t >> 4;
#pragma unroll
  for (int i = 0; i < 8; ++i) {
    float* crow = dst + (long)(m0 + ty * 8 + i) * D_ + n0 + tx * 8;
    const float* bp = bvec + n0 + tx * 8;
    float4 r0, r1;
    r0.x = acc[i][0] + bp[0]; r0.y = acc[i][1] + bp[1];
    r0.z = acc[i][2] + bp[2]; r0.w = acc[i][3] + bp[3];
    r1.x = acc[i][4] + bp[4]; r1.y = acc[i][5] + bp[5];
    r1.z = acc[i][6] + bp[6]; r1.w = acc[i][7] + bp[7];
    ((float4*)crow)[0] = r0;
    ((float4*)crow)[1] = r1;
  }
}

// ---- Q,K projections: z = mat*8 + band, mat in {0,1} -----------------------
__global__ __launch_bounds__(256) void gemm_proj_qk(Ptrs8 bands,
                                                    const float* __restrict__ qW,
                                                    const float* __restrict__ kW,
                                                    const float* __restrict__ qb,
                                                    const float* __restrict__ kb,
                                                    float* __restrict__ Qn,
                                                    float* __restrict__ Kn) {
  const int mat = blockIdx.z >> 3, band = blockIdx.z & 7;
  const float* W = (mat == 0) ? qW : kW;
  const float* bvec = (mat == 0) ? qb : kb;
  float* dst = ((mat == 0) ? Qn : Kn) + (long)band * BAND_ELEMS;
  W += (long)band * D_ * D_;
  bvec += band * D_;

  const int m0 = blockIdx.y * BM, n0 = blockIdx.x * BN;
  float acc[8][8] = {};
  gemm_core(bands.p[band], W, m0, n0, D_, acc);
  proj_epilogue(dst, bvec, m0, n0, acc);
}

// ---- V projection (launched AFTER extract; overwrites the bf16 overlay) ----
__global__ __launch_bounds__(256) void gemm_proj_v(Ptrs8 bands,
                                                   const float* __restrict__ vW,
                                                   const float* __restrict__ vb,
                                                   float* __restrict__ V) {
  const int band = blockIdx.z;
  const float* W = vW + (long)band * D_ * D_;
  const float* bvec = vb + band * D_;
  float* dst = V + (long)band * BAND_ELEMS;

  const int m0 = blockIdx.y * BM, n0 = blockIdx.x * BN;
  float acc[8][8] = {};
  gemm_core(bands.p[band], W, m0, n0, D_, acc);
  proj_epilogue(dst, bvec, m0, n0, acc);
}

// ---- L2 normalization + bf16 emission (same f2bf_rne bits the old extract
// ---- computed inline) ------------------------------------------------------
__global__ __launch_bounds__(256) void l2norm_rows(float* __restrict__ X,
                                                   ushort* __restrict__ bf) {
  const long row = (long)blockIdx.x * 4 + (threadIdx.x >> 6);
  const int lane = threadIdx.x & 63;
  float* p = X + row * D_;
  float4 a = ((float4*)p)[lane];
  float4 b = ((float4*)p)[lane + 64];
  float s = a.x * a.x + a.y * a.y + a.z * a.z + a.w * a.w +
            b.x * b.x + b.y * b.y + b.z * b.z + b.w * b.w;
#pragma unroll
  for (int m = 1; m < 64; m <<= 1) s += __shfl_xor(s, m);
  const float inv = 1.0f / fmaxf(sqrtf(s), 1e-12f);
  a.x *= inv; a.y *= inv; a.z *= inv; a.w *= inv;
  b.x *= inv; b.y *= inv; b.z *= inv; b.w *= inv;
  ((float4*)p)[lane] = a;
  ((float4*)p)[lane + 64] = b;
  ushort4 w0, w1;
  w0.x = f2bf_rne(a.x); w0.y = f2bf_rne(a.y); w0.z = f2bf_rne(a.z); w0.w = f2bf_rne(a.w);
  w1.x = f2bf_rne(b.x); w1.y = f2bf_rne(b.y); w1.z = f2bf_rne(b.z); w1.w = f2bf_rne(b.w);
  *(ushort4*)(bf + row * D_ + lane * 4) = w0;
  *(ushort4*)(bf + row * D_ + 256 + lane * 4) = w1;
}

// ---------------------------------------------------------------------------
// STAGE 1: bf16 MFMA approx scores from PRE-CONVERTED bf16 Q/K, staged
// HBM->LDS via global_load_lds. LDS granule (oct, row) at oct*132 + row
// (16B granules; 132-stride = proven fallback bank layout). gload dest is
// wave-uniform: oct & wave-half are uniform per wave, lane adds lane*16B.
// Fragment reads + MFMA + extraction epilogue VERBATIM -> identical bits.
// ---------------------------------------------------------------------------
#define SBM 128
#define SBN 128
#define XP 132

__global__ __launch_bounds__(256) void mfma_extract_bf(const ushort* __restrict__ Qbf,
                                                       const ushort* __restrict__ Kbf,
                                                       float* __restrict__ candv,
                                                       ushort* __restrict__ candi,
                                                       CallTab tab) {
  __shared__ ushort ldsA[2][4 * XP * 8];
  __shared__ ushort ldsB[2][4 * XP * 8];

  const int z = blockIdx.z;
  const int c = z >> 3, b = z & 7;
  const ushort* A = Qbf + (long)tab.qi[c] * BAND_ELEMS + (long)b * N_ * D_;
  const ushort* Bm = Kbf + (long)tab.ki[c] * BAND_ELEMS + (long)b * N_ * D_;
  const int m0 = blockIdx.y * SBM, n0 = blockIdx.x * SBN;

  const int t = threadIdx.x;
  const int lane = t & 63;
  const int wm = t >> 6;
  const int fr = lane & 15, fh = lane >> 4;

  f32x4 acc[2][8] = {};

  // wave-uniform pieces of the staging address:
  const int half = wm & 1;                  // which 64-row half of the plane

#define XSTAGE(bb, k0)                                                        \
  do {                                                                        \
    _Pragma("unroll")                                                         \
    for (int it_ = 0; it_ < 2; ++it_) {                                       \
      const int oct_ = it_ * 2 + (wm >> 1);                                   \
      const int row_ = half * 64 + lane;                                      \
      GLOAD16(A + (long)(m0 + row_) * D_ + (k0) + oct_ * 8,                   \
              &ldsA[bb][(oct_ * XP + half * 64) * 8]);                        \
      GLOAD16(Bm + (long)(n0 + row_) * D_ + (k0) + oct_ * 8,                  \
              &ldsB[bb][(oct_ * XP + half * 64) * 8]);                        \
    }                                                                         \
  } while (0)

  int buf = 0;
  XSTAGE(0, 0);
  asm volatile("s_waitcnt vmcnt(0)" ::: "memory");
  __syncthreads();

  for (int kq = 0; kq < 16; ++kq) {
    if (kq < 15) XSTAGE(buf ^ 1, (kq + 1) * 32);

    bf16x8 af[2], bfr[8];
#pragma unroll
    for (int i = 0; i < 2; ++i)
      af[i] = *(const bf16x8*)&ldsA[buf][(fh * XP + wm * 32 + i * 16 + fr) * 8];
#pragma unroll
    for (int j = 0; j < 8; ++j)
      bfr[j] = *(const bf16x8*)&ldsB[buf][(fh * XP + j * 16 + fr) * 8];

#pragma unroll
    for (int i = 0; i < 2; ++i)
#pragma unroll
      for (int j = 0; j < 8; ++j)
        acc[i][j] = __builtin_amdgcn_mfma_f32_16x16x32_bf16(af[i], bfr[j], acc[i][j], 0, 0, 0);

    asm volatile("s_waitcnt vmcnt(0)" ::: "memory");
    __syncthreads();
    buf ^= 1;
  }
#undef XSTAGE

  // ---- per-tile top-8 extraction (VERBATIM R7) ----
#pragma unroll
  for (int i = 0; i < 2; ++i)
#pragma unroll
    for (int rr = 0; rr < 4; ++rr) {
      const int R = b * N_ + m0 + wm * 32 + i * 16 + fh * 4 + rr;
      const long base = (((long)c * 8192 + R) * 8 + blockIdx.x) * 8;
#pragma unroll
      for (int it = 0; it < 8; ++it) {
        float lv = acc[i][0][rr]; int lj = 0;
#pragma unroll
        for (int j = 1; j < 8; ++j)
          if (acc[i][j][rr] > lv) { lv = acc[i][j][rr]; lj = j; }
        int li = lj * 16 + fr;
#pragma unroll
        for (int m = 1; m < 16; m <<= 1) {
          float ov = __shfl_xor(lv, m);
          int oi = __shfl_xor(li, m);
          if (ov > lv || (ov == lv && oi < li)) { lv = ov; li = oi; }
        }
        if (fr == it) { candv[base + it] = lv; candi[base + it] = (ushort)(n0 + li); }
        if (fr == (li & 15)) {
#pragma unroll
          for (int j = 0; j < 8; ++j)
            if (j == (li >> 4)) acc[i][j][rr] = -INFINITY;
        }
      }
    }
}

// ---------------------------------------------------------------------------
// STAGE 2 (VERBATIM R11): exact fp32 chains, K/Q staged via global_load_lds.
// ---------------------------------------------------------------------------
#define RRBLOCKS (NCALLS * 8192 / 4)       // 38912 = 8 * 4864

__global__ __launch_bounds__(256) void rerank_exact(const float* __restrict__ Qn,
                                                    const float* __restrict__ Kn,
                                                    const float* __restrict__ candv,
                                                    const ushort* __restrict__ candi,
                                                    float* __restrict__ fp,
                                                    int* __restrict__ fi,
                                                    float* __restrict__ out,
                                                    CallTab tab) {
  __shared__ float sbuf[4][2][1088];

  const int bid = blockIdx.x;
  const int blk = (bid & 7) * (RRBLOCKS / 8) + (bid >> 3);

  const int w = threadIdx.x >> 6, lane = threadIdx.x & 63;
  const long gr = (long)blk * 4 + w;
  const int c = (int)(gr >> 13);
  const int R = (int)(gr & 8191);
  const int b = R >> 10;

  const long cb = gr * 64;
  float cv = candv[cb + lane];
  int ci = (int)candi[cb + lane];

  int myi = 0;
#pragma unroll
  for (int it = 0; it < 16; ++it) {
    float lv = cv; int gi = ci;
#pragma unroll
    for (int m = 1; m < 64; m <<= 1) {
      float ov = __shfl_xor(lv, m);
      int oi = __shfl_xor(gi, m);
      if (ov > lv || (ov == lv && oi < gi)) { lv = ov; gi = oi; }
    }
    if ((lane & 15) == it) myi = gi;
    if (ci == gi) cv = -INFINITY;
  }

  const int mycand = lane & 15;
  const int eidx = __shfl(myi, mycand);

  const float* qrow = Qn + (long)tab.qi[c] * BAND_ELEMS + (long)R * D_;
  const float* ksrc0 = Kn + (long)tab.ki[c] * BAND_ELEMS +
                       ((long)(b << 10) + eidx) * D_ + ((lane >> 4) << 2);

#define STAGE(bb, ch)                                                         \
  do {                                                                        \
    float* base_ = &sbuf[w][bb][0];                                           \
    GLOAD16(ksrc0 + (ch) * 64 + 0,  base_ + 0);                               \
    GLOAD16(ksrc0 + (ch) * 64 + 16, base_ + 256);                             \
    GLOAD16(ksrc0 + (ch) * 64 + 32, base_ + 512);                             \
    GLOAD16(ksrc0 + (ch) * 64 + 48, base_ + 768);                             \
    GLOAD4(qrow + (ch) * 64 + lane, base_ + 1024);                            \
  } while (0)

  float acc = 0.f;
  STAGE(0, 0);
#pragma unroll
  for (int ch = 0; ch < 8; ++ch) {
    if (ch < 7) {
      STAGE((ch + 1) & 1, ch + 1);
      asm volatile("s_waitcnt vmcnt(5)" ::: "memory");
    } else {
      asm volatile("s_waitcnt vmcnt(0)" ::: "memory");
    }
    const float* kb2 = &sbuf[w][ch & 1][0];
    const float* qb2 = &sbuf[w][ch & 1][1024];
#pragma unroll
    for (int kq = 0; kq < 16; ++kq) {
      float4 kv = *(const float4*)(kb2 + kq * 64 + mycand * 4);
      float4 qv = *(const float4*)(qb2 + kq * 4);
      acc = fmaf(qv.x, kv.x, acc);
      acc = fmaf(qv.y, kv.y, acc);
      acc = fmaf(qv.z, kv.z, acc);
      acc = fmaf(qv.w, kv.w, acc);
    }
  }
#undef STAGE

  float ev = acc; int ei = eidx;
  float sv[8]; int si[8];
#pragma unroll
  for (int it = 0; it < 8; ++it) {
    float lv = ev; int gi = ei;
#pragma unroll
    for (int m = 1; m < 64; m <<= 1) {
      float ov = __shfl_xor(lv, m);
      int oi = __shfl_xor(gi, m);
      if (ov > lv || (ov == lv && oi < gi)) { lv = ov; gi = oi; }
    }
    sv[it] = lv; si[it] = gi;
    if (ei == gi) ev = -INFINITY;
  }

  float p[8], sum = 0.f;
#pragma unroll
  for (int j = 0; j < 8; ++j) { p[j] = expf(sv[j] - sv[0]); sum += p[j]; }
  const float isum = 1.0f / sum;
  float H = 0.f;
#pragma unroll
  for (int j = 0; j < 8; ++j) { p[j] *= isum; H -= p[j] * logf(p[j] + 1e-9f); }

  if (lane == 0) {
    atomicAdd(out + OUT_MAIN + (long)c * B_ + b, H * (1.0f / (float)N_));
#pragma unroll
    for (int j = 0; j < 8; ++j) { fp[gr * 8 + j] = p[j]; fi[gr * 8 + j] = si[j]; }
  }
}

// ---- merge finals + PV + band add + out write (VERBATIM R7) -----------------
__global__ __launch_bounds__(256) void merge_pv(Ptrs8 bands,
                                                const float* __restrict__ fp,
                                                const int* __restrict__ fi,
                                                const float* __restrict__ V,
                                                float* __restrict__ out,
                                                MergeTab mt) {
  const int bb = blockIdx.y;
  const int w = threadIdx.x >> 6, lane = threadIdx.x & 63;
  const long R = (long)blockIdx.x * 4 + w;
  const int b = (int)(R >> 10);

  float4 o0 = {0, 0, 0, 0}, o1 = {0, 0, 0, 0};
  const int nc = mt.ncalls[bb];
  for (int s = 0; s < nc; ++s) {
    const int c = mt.calls[bb][s];
    const float wt = mt.wts[c];
    const int ki = mt.kis[c];
    const long fb = ((long)c * 8192 + R) * 8;
    float4 p0 = *(const float4*)(fp + fb);
    float4 p1 = *(const float4*)(fp + fb + 4);
    int4 i0 = *(const int4*)(fi + fb);
    int4 i1 = *(const int4*)(fi + fb + 4);
    float pj[8] = {p0.x, p0.y, p0.z, p0.w, p1.x, p1.y, p1.z, p1.w};
    int ij[8] = {i0.x, i0.y, i0.z, i0.w, i1.x, i1.y, i1.z, i1.w};
#pragma unroll
    for (int j = 0; j < 8; ++j) {
      const float pw = pj[j] * wt;
      const float4* vr = (const float4*)(V + (long)ki * BAND_ELEMS +
                                         ((long)(b << 10) + ij[j]) * D_);
      float4 x0 = vr[lane * 2], x1 = vr[lane * 2 + 1];
      o0.x += pw * x0.x; o0.y += pw * x0.y; o0.z += pw * x0.z; o0.w += pw * x0.w;
      o1.x += pw * x1.x; o1.y += pw * x1.y; o1.z += pw * x1.z; o1.w += pw * x1.w;
    }
  }

  const float4* src = (const float4*)(bands.p[bb] + R * D_);
  float4 s0 = src[lane * 2], s1 = src[lane * 2 + 1];
  s0.x += o0.x; s0.y += o0.y; s0.z += o0.z; s0.w += o0.w;
  s1.x += o1.x; s1.y += o1.y; s1.z += o1.z; s1.w += o1.w;
  float4* dst = (float4*)(out + (long)bb * BAND_ELEMS + R * D_);
  dst[lane * 2] = s0;
  dst[lane * 2 + 1] = s1;
}

// ---- zero the 152 entropy slots ---------------------------------------------
__global__ void init_eps(float* __restrict__ out) {
  if (threadIdx.x < NCALLS * B_) out[OUT_MAIN + threadIdx.x] = 0.f;
}

// --------------------------------------------------------------------------------
extern "C" void kernel_launch(void* const* d_in, const int* in_sizes, int n_in,
                              void* d_out, int out_size, void* d_ws, size_t ws_size,
                              hipStream_t stream) {
  Ptrs8 bands;
  for (int i = 0; i < 8; ++i) bands.p[i] = (const float*)d_in[i];
  const float* qW = (const float*)d_in[8];
  const float* qb = (const float*)d_in[9];
  const float* kW = (const float*)d_in[10];
  const float* kb = (const float*)d_in[11];
  const float* vW = (const float*)d_in[12];
  const float* vb = (const float*)d_in[13];
  float* out = (float*)d_out;
  float* ws = (float*)d_ws;

  float* Qn = ws;                                        // fp32, 134.2 MB
  float* Kn = ws + (long)8 * BAND_ELEMS;                 // fp32, 134.2 MB
  // OVERLAY region (134.2 MB): bf16 Q+K during l2norm->extract, then V fp32
  float* V = ws + (long)16 * BAND_ELEMS;
  ushort* bfbuf = (ushort*)V;                            // 16*BAND_ELEMS ushorts
  float* candv = ws + (long)24 * BAND_ELEMS;             // 39.9 MB
  ushort* candi = (ushort*)(candv + (long)NCALLS * 8192 * 64);  // 19.9 MB
  float* fp = (float*)(candi + (long)NCALLS * 8192 * 64);       // 5 MB
  int* fi = (int*)(fp + (long)NCALLS * 8192 * 8);               // 5 MB
  // total 472.4 MB — same footprint as R6 (proven to fit)

  static const int calls[NCALLS][2] = {
      {6, 0}, {0, 6}, {5, 1}, {1, 5}, {4, 2}, {2, 4},
      {0, 3}, {1, 3}, {2, 3}, {4, 3}, {5, 3}, {6, 3},
      {0, 7}, {1, 7}, {2, 7}, {3, 7}, {4, 7}, {5, 7}, {6, 7}};

  CallTab tab;
  MergeTab mt;
  for (int i = 0; i < 8; ++i) mt.ncalls[i] = 0;
  for (int c = 0; c < NCALLS; ++c) {
    tab.qi[c] = calls[c][0];
    tab.ki[c] = calls[c][1];
    mt.kis[c] = calls[c][1];
    mt.wts[c] = (c < 6) ? 1.0f : 0.5f;
    int q = calls[c][0];
    mt.calls[q][mt.ncalls[q]++] = c;
  }

  hipLaunchKernelGGL(init_eps, dim3(1), dim3(256), 0, stream, out);

  // 1) Q,K projections (V deferred — its slot holds bf16 for now)
  dim3 gqk(D_ / BN, (B_ * N_) / BM, 16);
  hipLaunchKernelGGL(gemm_proj_qk, gqk, dim3(256), 0, stream,
                     bands, qW, kW, qb, kb, Qn, Kn);

  // 2) l2norm Qn+Kn (contiguous rows) + bf16 emission into overlay
  hipLaunchKernelGGL(l2norm_rows, dim3(2 * 8 * B_ * N_ / 4), dim3(256), 0, stream,
                     Qn, bfbuf);

  // 3) approx scores + per-tile top-8 from bf16
  dim3 gs(N_ / SBN, N_ / SBM, NCALLS * 8);
  hipLaunchKernelGGL(mfma_extract_bf, gs, dim3(256), 0, stream,
                     bfbuf, bfbuf + (long)8 * BAND_ELEMS, candv, candi, tab);

  // 4) V projection — overwrites the bf16 overlay (extract is done with it)
  dim3 gv(D_ / BN, (B_ * N_) / BM, 8);
  hipLaunchKernelGGL(gemm_proj_v, gv, dim3(256), 0, stream, bands, vW, vb, V);

  // 5) exact rerank + 6) merge/PV
  hipLaunchKernelGGL(rerank_exact, dim3(RRBLOCKS), dim3(256), 0, stream,
                     Qn, Kn, candv, candi, fp, fi, out, tab);

  hipLaunchKernelGGL(merge_pv, dim3(B_ * N_ / 4, 8), dim3(256), 0, stream,
                     bands, fp, fi, V, out, mt);
}

// Round 14
// 3530.214 us; speedup vs baseline: 1.5578x; 1.0160x over previous
//
#include <hip/hip_runtime.h>
#include <math.h>

#define B_ 8
#define N_ 1024
#define D_ 512
#define BAND_ELEMS (B_ * N_ * D_)          // 4194304 = 2^22
#define OUT_MAIN (8L * BAND_ELEMS)         // 33554432
#define NCALLS 19

struct Ptrs8 { const float* p[8]; };
struct CallTab { int qi[NCALLS]; int ki[NCALLS]; };
struct MergeTab { int ncalls[8]; int calls[8][3]; int kis[NCALLS]; float wts[NCALLS]; };

typedef __attribute__((ext_vector_type(8))) short bf16x8;
typedef __attribute__((ext_vector_type(4))) float f32x4;

__device__ __forceinline__ ushort f2bf_rne(float x) {
  uint u = __float_as_uint(x);
  return (ushort)((u + 0x7fffu + ((u >> 16) & 1u)) >> 16);
}

#define GLOAD16(gsrc, ldst)                                                   \
  __builtin_amdgcn_global_load_lds(                                          \
      (const __attribute__((address_space(1))) void*)(gsrc),                 \
      (__attribute__((address_space(3))) void*)(ldst), 16, 0, 0)
#define GLOAD4(gsrc, ldst)                                                    \
  __builtin_amdgcn_global_load_lds(                                          \
      (const __attribute__((address_space(1))) void*)(gsrc),                 \
      (__attribute__((address_space(3))) void*)(ldst), 4, 0, 0)

// ---------------------------------------------------------------------------
// fp32 GEMM core (VERBATIM R5/R6 — bit-exact contract: sequential-k fp32 fma
// chain per output). Used ONLY for the projections.
// ---------------------------------------------------------------------------
#define BM 128
#define BN 128
#define BK 16
#define LDP 132

__device__ __forceinline__ int bgran(int g) {
  return (g & ~7) | ((g + (g >> 3)) & 7);
}

__device__ __forceinline__ void gemm_core(const float* __restrict__ A,
                                          const float* __restrict__ Bm,
                                          int m0, int n0, int K,
                                          float (&acc)[8][8]) {
  __shared__ float As[BK * LDP];
  __shared__ float Bs[BK * LDP];

  const int t = threadIdx.x;
  const int tx = t & 15, ty = t >> 4;
  const int rs = t >> 2;
  const int cs = t & 3;

  float4 pa[2], pb[2];
#pragma unroll
  for (int it = 0; it < 2; ++it) {
    pa[it] = *(const float4*)(A + (long)(m0 + rs + 64 * it) * K + cs * 4);
    pb[it] = *(const float4*)(Bm + (long)(n0 + rs + 64 * it) * K + cs * 4);
  }

  for (int k0 = 0; k0 < K; k0 += BK) {
    __syncthreads();
    {
      const int sa = ((cs & 1) << 2);
      const int base = cs * 4 * LDP;
#pragma unroll
      for (int it = 0; it < 2; ++it) {
        const int r = rs + 64 * it;
        const int ra = r ^ sa;
        As[base + 0 * LDP + ra] = pa[it].x;
        As[base + 1 * LDP + ra] = pa[it].y;
        As[base + 2 * LDP + ra] = pa[it].z;
        As[base + 3 * LDP + ra] = pa[it].w;
        const int rb = bgran(r >> 2) * 4 + (r & 3);
        Bs[base + 0 * LDP + rb] = pb[it].x;
        Bs[base + 1 * LDP + rb] = pb[it].y;
        Bs[base + 2 * LDP + rb] = pb[it].z;
        Bs[base + 3 * LDP + rb] = pb[it].w;
      }
    }
    __syncthreads();

    if (k0 + BK < K) {
#pragma unroll
      for (int it = 0; it < 2; ++it) {
        pa[it] = *(const float4*)(A + (long)(m0 + rs + 64 * it) * K + k0 + BK + cs * 4);
        pb[it] = *(const float4*)(Bm + (long)(n0 + rs + 64 * it) * K + k0 + BK + cs * 4);
      }
    }

#pragma unroll
    for (int kk = 0; kk < BK; ++kk) {
      const int c1 = (kk >> 2) & 1;
      float a[8], b[8];
      {
        float4 u = *(const float4*)&As[kk * LDP + ty * 8 + c1 * 4];
        float4 v = *(const float4*)&As[kk * LDP + ty * 8 + 4 - c1 * 4];
        a[0] = u.x; a[1] = u.y; a[2] = u.z; a[3] = u.w;
        a[4] = v.x; a[5] = v.y; a[6] = v.z; a[7] = v.w;
        float4 p = *(const float4*)&Bs[kk * LDP + bgran(2 * tx) * 4];
        float4 q = *(const float4*)&Bs[kk * LDP + bgran(2 * tx + 1) * 4];
        b[0] = p.x; b[1] = p.y; b[2] = p.z; b[3] = p.w;
        b[4] = q.x; b[5] = q.y; b[6] = q.z; b[7] = q.w;
      }
#pragma unroll
      for (int i = 0; i < 8; ++i)
#pragma unroll
        for (int j = 0; j < 8; ++j) acc[i][j] = fmaf(a[i], b[j], acc[i][j]);
    }
  }
}

__device__ __forceinline__ void proj_epilogue(float* __restrict__ dst,
                                              const float* __restrict__ bvec,
                                              int m0, int n0, float (&acc)[8][8]) {
  const int t = threadIdx.x;
  const int tx = t & 15, ty = t >> 4;
#pragma unroll
  for (int i = 0; i < 8; ++i) {
    float* crow = dst + (long)(m0 + ty * 8 + i) * D_ + n0 + tx * 8;
    const float* bp = bvec + n0 + tx * 8;
    float4 r0, r1;
    r0.x = acc[i][0] + bp[0]; r0.y = acc[i][1] + bp[1];
    r0.z = acc[i][2] + bp[2]; r0.w = acc[i][3] + bp[3];
    r1.x = acc[i][4] + bp[4]; r1.y = acc[i][5] + bp[5];
    r1.z = acc[i][6] + bp[6]; r1.w = acc[i][7] + bp[7];
    ((float4*)crow)[0] = r0;
    ((float4*)crow)[1] = r1;
  }
}

// ---- Q,K projections: z = mat*8 + band, mat in {0,1} -----------------------
__global__ __launch_bounds__(256) void gemm_proj_qk(Ptrs8 bands,
                                                    const float* __restrict__ qW,
                                                    const float* __restrict__ kW,
                                                    const float* __restrict__ qb,
                                                    const float* __restrict__ kb,
                                                    float* __restrict__ Qn,
                                                    float* __restrict__ Kn) {
  const int mat = blockIdx.z >> 3, band = blockIdx.z & 7;
  const float* W = (mat == 0) ? qW : kW;
  const float* bvec = (mat == 0) ? qb : kb;
  float* dst = ((mat == 0) ? Qn : Kn) + (long)band * BAND_ELEMS;
  W += (long)band * D_ * D_;
  bvec += band * D_;

  const int m0 = blockIdx.y * BM, n0 = blockIdx.x * BN;
  float acc[8][8] = {};
  gemm_core(bands.p[band], W, m0, n0, D_, acc);
  proj_epilogue(dst, bvec, m0, n0, acc);
}

// ---- V projection (launched AFTER extract; overwrites the bf16 overlay) ----
__global__ __launch_bounds__(256) void gemm_proj_v(Ptrs8 bands,
                                                   const float* __restrict__ vW,
                                                   const float* __restrict__ vb,
                                                   float* __restrict__ V) {
  const int band = blockIdx.z;
  const float* W = vW + (long)band * D_ * D_;
  const float* bvec = vb + band * D_;
  float* dst = V + (long)band * BAND_ELEMS;

  const int m0 = blockIdx.y * BM, n0 = blockIdx.x * BN;
  float acc[8][8] = {};
  gemm_core(bands.p[band], W, m0, n0, D_, acc);
  proj_epilogue(dst, bvec, m0, n0, acc);
}

// ---- L2 normalization + bf16 emission (same f2bf_rne bits) ------------------
__global__ __launch_bounds__(256) void l2norm_rows(float* __restrict__ X,
                                                   ushort* __restrict__ bf) {
  const long row = (long)blockIdx.x * 4 + (threadIdx.x >> 6);
  const int lane = threadIdx.x & 63;
  float* p = X + row * D_;
  float4 a = ((float4*)p)[lane];
  float4 b = ((float4*)p)[lane + 64];
  float s = a.x * a.x + a.y * a.y + a.z * a.z + a.w * a.w +
            b.x * b.x + b.y * b.y + b.z * b.z + b.w * b.w;
#pragma unroll
  for (int m = 1; m < 64; m <<= 1) s += __shfl_xor(s, m);
  const float inv = 1.0f / fmaxf(sqrtf(s), 1e-12f);
  a.x *= inv; a.y *= inv; a.z *= inv; a.w *= inv;
  b.x *= inv; b.y *= inv; b.z *= inv; b.w *= inv;
  ((float4*)p)[lane] = a;
  ((float4*)p)[lane + 64] = b;
  ushort4 w0, w1;
  w0.x = f2bf_rne(a.x); w0.y = f2bf_rne(a.y); w0.z = f2bf_rne(a.z); w0.w = f2bf_rne(a.w);
  w1.x = f2bf_rne(b.x); w1.y = f2bf_rne(b.y); w1.z = f2bf_rne(b.z); w1.w = f2bf_rne(b.w);
  *(ushort4*)(bf + row * D_ + lane * 4) = w0;
  *(ushort4*)(bf + row * D_ + 256 + lane * 4) = w1;
}

// ---------------------------------------------------------------------------
// STAGE 1: bf16 MFMA approx scores + per-tile top-8. R14 change: 3-buffer
// pipeline with COUNTED vmcnt (never 0 mid-loop) + raw s_barrier (no drain).
// Loads get ~2 iterations to land instead of being drained immediately.
// Frags/MFMA/extraction epilogue VERBATIM -> bit-identical candidates.
// ---------------------------------------------------------------------------
#define SBM 128
#define SBN 128
#define XP 132

__global__ __launch_bounds__(256) void mfma_extract_bf(const ushort* __restrict__ Qbf,
                                                       const ushort* __restrict__ Kbf,
                                                       float* __restrict__ candv,
                                                       ushort* __restrict__ candi,
                                                       CallTab tab) {
  __shared__ ushort ldsA[3][4 * XP * 8];
  __shared__ ushort ldsB[3][4 * XP * 8];

  const int z = blockIdx.z;
  const int c = z >> 3, b = z & 7;
  const ushort* A = Qbf + (long)tab.qi[c] * BAND_ELEMS + (long)b * N_ * D_;
  const ushort* Bm = Kbf + (long)tab.ki[c] * BAND_ELEMS + (long)b * N_ * D_;
  const int m0 = blockIdx.y * SBM, n0 = blockIdx.x * SBN;

  const int t = threadIdx.x;
  const int lane = t & 63;
  const int wm = t >> 6;
  const int fr = lane & 15, fh = lane >> 4;

  f32x4 acc[2][8] = {};

  const int half = wm & 1;

#define XSTAGE(pA, pB, k0)                                                    \
  do {                                                                        \
    _Pragma("unroll")                                                         \
    for (int it_ = 0; it_ < 2; ++it_) {                                       \
      const int oct_ = it_ * 2 + (wm >> 1);                                   \
      const int row_ = half * 64 + lane;                                      \
      GLOAD16(A + (long)(m0 + row_) * D_ + (k0) + oct_ * 8,                   \
              (pA) + (oct_ * XP + half * 64) * 8);                            \
      GLOAD16(Bm + (long)(n0 + row_) * D_ + (k0) + oct_ * 8,                  \
              (pB) + (oct_ * XP + half * 64) * 8);                            \
    }                                                                         \
  } while (0)

  ushort* pA0 = &ldsA[0][0]; ushort* pB0 = &ldsB[0][0];
  ushort* pA1 = &ldsA[1][0]; ushort* pB1 = &ldsB[1][0];
  ushort* pA2 = &ldsA[2][0]; ushort* pB2 = &ldsB[2][0];

  // prologue: stage k-chunks 0 and 1 (4 wave-loads each -> vmcnt 8)
  XSTAGE(pA0, pB0, 0);
  XSTAGE(pA1, pB1, 32);

  for (int kq = 0; kq < 16; ++kq) {
    if (kq + 2 < 16) {
      XSTAGE(pA2, pB2, (kq + 2) * 32);          // overwrites buf read at kq-1
      asm volatile("s_waitcnt vmcnt(8)" ::: "memory");   // buf kq landed
    } else if (kq + 1 < 16) {
      asm volatile("s_waitcnt vmcnt(4)" ::: "memory");
    } else {
      asm volatile("s_waitcnt vmcnt(0)" ::: "memory");
    }
    __builtin_amdgcn_sched_barrier(0);
    __builtin_amdgcn_s_barrier();                // all waves: buf kq ready
    __builtin_amdgcn_sched_barrier(0);

    bf16x8 af[2], bfr[8];
#pragma unroll
    for (int i = 0; i < 2; ++i)
      af[i] = *(const bf16x8*)&pA0[(fh * XP + wm * 32 + i * 16 + fr) * 8];
#pragma unroll
    for (int j = 0; j < 8; ++j)
      bfr[j] = *(const bf16x8*)&pB0[(fh * XP + j * 16 + fr) * 8];

#pragma unroll
    for (int i = 0; i < 2; ++i)
#pragma unroll
      for (int j = 0; j < 8; ++j)
        acc[i][j] = __builtin_amdgcn_mfma_f32_16x16x32_bf16(af[i], bfr[j], acc[i][j], 0, 0, 0);

    __builtin_amdgcn_sched_barrier(0);
    __builtin_amdgcn_s_barrier();                // all waves done reading buf kq
    __builtin_amdgcn_sched_barrier(0);

    ushort* ta = pA0; pA0 = pA1; pA1 = pA2; pA2 = ta;
    ushort* tb = pB0; pB0 = pB1; pB1 = pB2; pB2 = tb;
  }
#undef XSTAGE

  // ---- per-tile top-8 extraction (VERBATIM R7) ----
#pragma unroll
  for (int i = 0; i < 2; ++i)
#pragma unroll
    for (int rr = 0; rr < 4; ++rr) {
      const int R = b * N_ + m0 + wm * 32 + i * 16 + fh * 4 + rr;
      const long base = (((long)c * 8192 + R) * 8 + blockIdx.x) * 8;
#pragma unroll
      for (int it = 0; it < 8; ++it) {
        float lv = acc[i][0][rr]; int lj = 0;
#pragma unroll
        for (int j = 1; j < 8; ++j)
          if (acc[i][j][rr] > lv) { lv = acc[i][j][rr]; lj = j; }
        int li = lj * 16 + fr;
#pragma unroll
        for (int m = 1; m < 16; m <<= 1) {
          float ov = __shfl_xor(lv, m);
          int oi = __shfl_xor(li, m);
          if (ov > lv || (ov == lv && oi < li)) { lv = ov; li = oi; }
        }
        if (fr == it) { candv[base + it] = lv; candi[base + it] = (ushort)(n0 + li); }
        if (fr == (li & 15)) {
#pragma unroll
          for (int j = 0; j < 8; ++j)
            if (j == (li >> 4)) acc[i][j][rr] = -INFINITY;
        }
      }
    }
}

// ---------------------------------------------------------------------------
// STAGE 2 (VERBATIM R11): exact fp32 chains, K/Q staged via global_load_lds.
// ---------------------------------------------------------------------------
#define RRBLOCKS (NCALLS * 8192 / 4)       // 38912 = 8 * 4864

__global__ __launch_bounds__(256) void rerank_exact(const float* __restrict__ Qn,
                                                    const float* __restrict__ Kn,
                                                    const float* __restrict__ candv,
                                                    const ushort* __restrict__ candi,
                                                    float* __restrict__ fp,
                                                    int* __restrict__ fi,
                                                    float* __restrict__ out,
                                                    CallTab tab) {
  __shared__ float sbuf[4][2][1088];

  const int bid = blockIdx.x;
  const int blk = (bid & 7) * (RRBLOCKS / 8) + (bid >> 3);

  const int w = threadIdx.x >> 6, lane = threadIdx.x & 63;
  const long gr = (long)blk * 4 + w;
  const int c = (int)(gr >> 13);
  const int R = (int)(gr & 8191);
  const int b = R >> 10;

  const long cb = gr * 64;
  float cv = candv[cb + lane];
  int ci = (int)candi[cb + lane];

  int myi = 0;
#pragma unroll
  for (int it = 0; it < 16; ++it) {
    float lv = cv; int gi = ci;
#pragma unroll
    for (int m = 1; m < 64; m <<= 1) {
      float ov = __shfl_xor(lv, m);
      int oi = __shfl_xor(gi, m);
      if (ov > lv || (ov == lv && oi < gi)) { lv = ov; gi = oi; }
    }
    if ((lane & 15) == it) myi = gi;
    if (ci == gi) cv = -INFINITY;
  }

  const int mycand = lane & 15;
  const int eidx = __shfl(myi, mycand);

  const float* qrow = Qn + (long)tab.qi[c] * BAND_ELEMS + (long)R * D_;
  const float* ksrc0 = Kn + (long)tab.ki[c] * BAND_ELEMS +
                       ((long)(b << 10) + eidx) * D_ + ((lane >> 4) << 2);

#define STAGE(bb, ch)                                                         \
  do {                                                                        \
    float* base_ = &sbuf[w][bb][0];                                           \
    GLOAD16(ksrc0 + (ch) * 64 + 0,  base_ + 0);                               \
    GLOAD16(ksrc0 + (ch) * 64 + 16, base_ + 256);                             \
    GLOAD16(ksrc0 + (ch) * 64 + 32, base_ + 512);                             \
    GLOAD16(ksrc0 + (ch) * 64 + 48, base_ + 768);                             \
    GLOAD4(qrow + (ch) * 64 + lane, base_ + 1024);                            \
  } while (0)

  float acc = 0.f;
  STAGE(0, 0);
#pragma unroll
  for (int ch = 0; ch < 8; ++ch) {
    if (ch < 7) {
      STAGE((ch + 1) & 1, ch + 1);
      asm volatile("s_waitcnt vmcnt(5)" ::: "memory");
    } else {
      asm volatile("s_waitcnt vmcnt(0)" ::: "memory");
    }
    const float* kb2 = &sbuf[w][ch & 1][0];
    const float* qb2 = &sbuf[w][ch & 1][1024];
#pragma unroll
    for (int kq = 0; kq < 16; ++kq) {
      float4 kv = *(const float4*)(kb2 + kq * 64 + mycand * 4);
      float4 qv = *(const float4*)(qb2 + kq * 4);
      acc = fmaf(qv.x, kv.x, acc);
      acc = fmaf(qv.y, kv.y, acc);
      acc = fmaf(qv.z, kv.z, acc);
      acc = fmaf(qv.w, kv.w, acc);
    }
  }
#undef STAGE

  float ev = acc; int ei = eidx;
  float sv[8]; int si[8];
#pragma unroll
  for (int it = 0; it < 8; ++it) {
    float lv = ev; int gi = ei;
#pragma unroll
    for (int m = 1; m < 64; m <<= 1) {
      float ov = __shfl_xor(lv, m);
      int oi = __shfl_xor(gi, m);
      if (ov > lv || (ov == lv && oi < gi)) { lv = ov; gi = oi; }
    }
    sv[it] = lv; si[it] = gi;
    if (ei == gi) ev = -INFINITY;
  }

  float p[8], sum = 0.f;
#pragma unroll
  for (int j = 0; j < 8; ++j) { p[j] = expf(sv[j] - sv[0]); sum += p[j]; }
  const float isum = 1.0f / sum;
  float H = 0.f;
#pragma unroll
  for (int j = 0; j < 8; ++j) { p[j] *= isum; H -= p[j] * logf(p[j] + 1e-9f); }

  if (lane == 0) {
    atomicAdd(out + OUT_MAIN + (long)c * B_ + b, H * (1.0f / (float)N_));
#pragma unroll
    for (int j = 0; j < 8; ++j) { fp[gr * 8 + j] = p[j]; fi[gr * 8 + j] = si[j]; }
  }
}

// ---- merge finals + PV + band add + out write (VERBATIM R7) -----------------
__global__ __launch_bounds__(256) void merge_pv(Ptrs8 bands,
                                                const float* __restrict__ fp,
                                                const int* __restrict__ fi,
                                                const float* __restrict__ V,
                                                float* __restrict__ out,
                                                MergeTab mt) {
  const int bb = blockIdx.y;
  const int w = threadIdx.x >> 6, lane = threadIdx.x & 63;
  const long R = (long)blockIdx.x * 4 + w;
  const int b = (int)(R >> 10);

  float4 o0 = {0, 0, 0, 0}, o1 = {0, 0, 0, 0};
  const int nc = mt.ncalls[bb];
  for (int s = 0; s < nc; ++s) {
    const int c = mt.calls[bb][s];
    const float wt = mt.wts[c];
    const int ki = mt.kis[c];
    const long fb = ((long)c * 8192 + R) * 8;
    float4 p0 = *(const float4*)(fp + fb);
    float4 p1 = *(const float4*)(fp + fb + 4);
    int4 i0 = *(const int4*)(fi + fb);
    int4 i1 = *(const int4*)(fi + fb + 4);
    float pj[8] = {p0.x, p0.y, p0.z, p0.w, p1.x, p1.y, p1.z, p1.w};
    int ij[8] = {i0.x, i0.y, i0.z, i0.w, i1.x, i1.y, i1.z, i1.w};
#pragma unroll
    for (int j = 0; j < 8; ++j) {
      const float pw = pj[j] * wt;
      const float4* vr = (const float4*)(V + (long)ki * BAND_ELEMS +
                                         ((long)(b << 10) + ij[j]) * D_);
      float4 x0 = vr[lane * 2], x1 = vr[lane * 2 + 1];
      o0.x += pw * x0.x; o0.y += pw * x0.y; o0.z += pw * x0.z; o0.w += pw * x0.w;
      o1.x += pw * x1.x; o1.y += pw * x1.y; o1.z += pw * x1.z; o1.w += pw * x1.w;
    }
  }

  const float4* src = (const float4*)(bands.p[bb] + R * D_);
  float4 s0 = src[lane * 2], s1 = src[lane * 2 + 1];
  s0.x += o0.x; s0.y += o0.y; s0.z += o0.z; s0.w += o0.w;
  s1.x += o1.x; s1.y += o1.y; s1.z += o1.z; s1.w += o1.w;
  float4* dst = (float4*)(out + (long)bb * BAND_ELEMS + R * D_);
  dst[lane * 2] = s0;
  dst[lane * 2 + 1] = s1;
}

// ---- zero the 152 entropy slots ---------------------------------------------
__global__ void init_eps(float* __restrict__ out) {
  if (threadIdx.x < NCALLS * B_) out[OUT_MAIN + threadIdx.x] = 0.f;
}

// --------------------------------------------------------------------------------
extern "C" void kernel_launch(void* const* d_in, const int* in_sizes, int n_in,
                              void* d_out, int out_size, void* d_ws, size_t ws_size,
                              hipStream_t stream) {
  Ptrs8 bands;
  for (int i = 0; i < 8; ++i) bands.p[i] = (const float*)d_in[i];
  const float* qW = (const float*)d_in[8];
  const float* qb = (const float*)d_in[9];
  const float* kW = (const float*)d_in[10];
  const float* kb = (const float*)d_in[11];
  const float* vW = (const float*)d_in[12];
  const float* vb = (const float*)d_in[13];
  float* out = (float*)d_out;
  float* ws = (float*)d_ws;

  float* Qn = ws;                                        // fp32, 134.2 MB
  float* Kn = ws + (long)8 * BAND_ELEMS;                 // fp32, 134.2 MB
  // OVERLAY region (134.2 MB): bf16 Q+K during l2norm->extract, then V fp32
  float* V = ws + (long)16 * BAND_ELEMS;
  ushort* bfbuf = (ushort*)V;
  float* candv = ws + (long)24 * BAND_ELEMS;             // 39.9 MB
  ushort* candi = (ushort*)(candv + (long)NCALLS * 8192 * 64);  // 19.9 MB
  float* fp = (float*)(candi + (long)NCALLS * 8192 * 64);       // 5 MB
  int* fi = (int*)(fp + (long)NCALLS * 8192 * 8);               // 5 MB

  static const int calls[NCALLS][2] = {
      {6, 0}, {0, 6}, {5, 1}, {1, 5}, {4, 2}, {2, 4},
      {0, 3}, {1, 3}, {2, 3}, {4, 3}, {5, 3}, {6, 3},
      {0, 7}, {1, 7}, {2, 7}, {3, 7}, {4, 7}, {5, 7}, {6, 7}};

  CallTab tab;
  MergeTab mt;
  for (int i = 0; i < 8; ++i) mt.ncalls[i] = 0;
  for (int c = 0; c < NCALLS; ++c) {
    tab.qi[c] = calls[c][0];
    tab.ki[c] = calls[c][1];
    mt.kis[c] = calls[c][1];
    mt.wts[c] = (c < 6) ? 1.0f : 0.5f;
    int q = calls[c][0];
    mt.calls[q][mt.ncalls[q]++] = c;
  }

  hipLaunchKernelGGL(init_eps, dim3(1), dim3(256), 0, stream, out);

  // 1) Q,K projections (V deferred — its slot holds bf16 for now)
  dim3 gqk(D_ / BN, (B_ * N_) / BM, 16);
  hipLaunchKernelGGL(gemm_proj_qk, gqk, dim3(256), 0, stream,
                     bands, qW, kW, qb, kb, Qn, Kn);

  // 2) l2norm Qn+Kn + bf16 emission into overlay
  hipLaunchKernelGGL(l2norm_rows, dim3(2 * 8 * B_ * N_ / 4), dim3(256), 0, stream,
                     Qn, bfbuf);

  // 3) approx scores + per-tile top-8 from bf16 (pipelined)
  dim3 gs(N_ / SBN, N_ / SBM, NCALLS * 8);
  hipLaunchKernelGGL(mfma_extract_bf, gs, dim3(256), 0, stream,
                     bfbuf, bfbuf + (long)8 * BAND_ELEMS, candv, candi, tab);

  // 4) V projection — overwrites the bf16 overlay
  dim3 gv(D_ / BN, (B_ * N_) / BM, 8);
  hipLaunchKernelGGL(gemm_proj_v, gv, dim3(256), 0, stream, bands, vW, vb, V);

  // 5) exact rerank + 6) merge/PV
  hipLaunchKernelGGL(rerank_exact, dim3(RRBLOCKS), dim3(256), 0, stream,
                     Qn, Kn, candv, candi, fp, fi, out, tab);

  hipLaunchKernelGGL(merge_pv, dim3(B_ * N_ / 4, 8), dim3(256), 0, stream,
                     bands, fp, fi, V, out, mt);
}

// Round 15
// 3449.581 us; speedup vs baseline: 1.5942x; 1.0234x over previous
//
#include <hip/hip_runtime.h>
#include <math.h>

#define B_ 8
#define N_ 1024
#define D_ 512
#define BAND_ELEMS (B_ * N_ * D_)          // 4194304 = 2^22
#define OUT_MAIN (8L * BAND_ELEMS)         // 33554432
#define NCALLS 19

struct Ptrs8 { const float* p[8]; };
struct CallTab { int qi[NCALLS]; int ki[NCALLS]; };
struct MergeTab { int ncalls[8]; int calls[8][3]; int kis[NCALLS]; float wts[NCALLS]; };

typedef __attribute__((ext_vector_type(8))) short bf16x8;
typedef __attribute__((ext_vector_type(4))) float f32x4;

__device__ __forceinline__ ushort f2bf_rne(float x) {
  uint u = __float_as_uint(x);
  return (ushort)((u + 0x7fffu + ((u >> 16) & 1u)) >> 16);
}

#define GLOAD16(gsrc, ldst)                                                   \
  __builtin_amdgcn_global_load_lds(                                          \
      (const __attribute__((address_space(1))) void*)(gsrc),                 \
      (__attribute__((address_space(3))) void*)(ldst), 16, 0, 0)
#define GLOAD4(gsrc, ldst)                                                    \
  __builtin_amdgcn_global_load_lds(                                          \
      (const __attribute__((address_space(1))) void*)(gsrc),                 \
      (__attribute__((address_space(3))) void*)(ldst), 4, 0, 0)

// ---------------------------------------------------------------------------
// fp32 GEMM core (VERBATIM R5/R6 — bit-exact contract: sequential-k fp32 fma
// chain per output). Used ONLY for the projections.
// ---------------------------------------------------------------------------
#define BM 128
#define BN 128
#define BK 16
#define LDP 132

__device__ __forceinline__ int bgran(int g) {
  return (g & ~7) | ((g + (g >> 3)) & 7);
}

__device__ __forceinline__ void gemm_core(const float* __restrict__ A,
                                          const float* __restrict__ Bm,
                                          int m0, int n0, int K,
                                          float (&acc)[8][8]) {
  __shared__ float As[BK * LDP];
  __shared__ float Bs[BK * LDP];

  const int t = threadIdx.x;
  const int tx = t & 15, ty = t >> 4;
  const int rs = t >> 2;
  const int cs = t & 3;

  float4 pa[2], pb[2];
#pragma unroll
  for (int it = 0; it < 2; ++it) {
    pa[it] = *(const float4*)(A + (long)(m0 + rs + 64 * it) * K + cs * 4);
    pb[it] = *(const float4*)(Bm + (long)(n0 + rs + 64 * it) * K + cs * 4);
  }

  for (int k0 = 0; k0 < K; k0 += BK) {
    __syncthreads();
    {
      const int sa = ((cs & 1) << 2);
      const int base = cs * 4 * LDP;
#pragma unroll
      for (int it = 0; it < 2; ++it) {
        const int r = rs + 64 * it;
        const int ra = r ^ sa;
        As[base + 0 * LDP + ra] = pa[it].x;
        As[base + 1 * LDP + ra] = pa[it].y;
        As[base + 2 * LDP + ra] = pa[it].z;
        As[base + 3 * LDP + ra] = pa[it].w;
        const int rb = bgran(r >> 2) * 4 + (r & 3);
        Bs[base + 0 * LDP + rb] = pb[it].x;
        Bs[base + 1 * LDP + rb] = pb[it].y;
        Bs[base + 2 * LDP + rb] = pb[it].z;
        Bs[base + 3 * LDP + rb] = pb[it].w;
      }
    }
    __syncthreads();

    if (k0 + BK < K) {
#pragma unroll
      for (int it = 0; it < 2; ++it) {
        pa[it] = *(const float4*)(A + (long)(m0 + rs + 64 * it) * K + k0 + BK + cs * 4);
        pb[it] = *(const float4*)(Bm + (long)(n0 + rs + 64 * it) * K + k0 + BK + cs * 4);
      }
    }

#pragma unroll
    for (int kk = 0; kk < BK; ++kk) {
      const int c1 = (kk >> 2) & 1;
      float a[8], b[8];
      {
        float4 u = *(const float4*)&As[kk * LDP + ty * 8 + c1 * 4];
        float4 v = *(const float4*)&As[kk * LDP + ty * 8 + 4 - c1 * 4];
        a[0] = u.x; a[1] = u.y; a[2] = u.z; a[3] = u.w;
        a[4] = v.x; a[5] = v.y; a[6] = v.z; a[7] = v.w;
        float4 p = *(const float4*)&Bs[kk * LDP + bgran(2 * tx) * 4];
        float4 q = *(const float4*)&Bs[kk * LDP + bgran(2 * tx + 1) * 4];
        b[0] = p.x; b[1] = p.y; b[2] = p.z; b[3] = p.w;
        b[4] = q.x; b[5] = q.y; b[6] = q.z; b[7] = q.w;
      }
#pragma unroll
      for (int i = 0; i < 8; ++i)
#pragma unroll
        for (int j = 0; j < 8; ++j) acc[i][j] = fmaf(a[i], b[j], acc[i][j]);
    }
  }
}

__device__ __forceinline__ void proj_epilogue(float* __restrict__ dst,
                                              const float* __restrict__ bvec,
                                              int m0, int n0, float (&acc)[8][8]) {
  const int t = threadIdx.x;
  const int tx = t & 15, ty = t >> 4;
#pragma unroll
  for (int i = 0; i < 8; ++i) {
    float* crow = dst + (long)(m0 + ty * 8 + i) * D_ + n0 + tx * 8;
    const float* bp = bvec + n0 + tx * 8;
    float4 r0, r1;
    r0.x = acc[i][0] + bp[0]; r0.y = acc[i][1] + bp[1];
    r0.z = acc[i][2] + bp[2]; r0.w = acc[i][3] + bp[3];
    r1.x = acc[i][4] + bp[4]; r1.y = acc[i][5] + bp[5];
    r1.z = acc[i][6] + bp[6]; r1.w = acc[i][7] + bp[7];
    ((float4*)crow)[0] = r0;
    ((float4*)crow)[1] = r1;
  }
}

// ---- Q,K projections: z = mat*8 + band, mat in {0,1} -----------------------
__global__ __launch_bounds__(256) void gemm_proj_qk(Ptrs8 bands,
                                                    const float* __restrict__ qW,
                                                    const float* __restrict__ kW,
                                                    const float* __restrict__ qb,
                                                    const float* __restrict__ kb,
                                                    float* __restrict__ Qn,
                                                    float* __restrict__ Kn) {
  const int mat = blockIdx.z >> 3, band = blockIdx.z & 7;
  const float* W = (mat == 0) ? qW : kW;
  const float* bvec = (mat == 0) ? qb : kb;
  float* dst = ((mat == 0) ? Qn : Kn) + (long)band * BAND_ELEMS;
  W += (long)band * D_ * D_;
  bvec += band * D_;

  const int m0 = blockIdx.y * BM, n0 = blockIdx.x * BN;
  float acc[8][8] = {};
  gemm_core(bands.p[band], W, m0, n0, D_, acc);
  proj_epilogue(dst, bvec, m0, n0, acc);
}

// ---- V projection (launched AFTER extract; overwrites the bf16 overlay) ----
__global__ __launch_bounds__(256) void gemm_proj_v(Ptrs8 bands,
                                                   const float* __restrict__ vW,
                                                   const float* __restrict__ vb,
                                                   float* __restrict__ V) {
  const int band = blockIdx.z;
  const float* W = vW + (long)band * D_ * D_;
  const float* bvec = vb + band * D_;
  float* dst = V + (long)band * BAND_ELEMS;

  const int m0 = blockIdx.y * BM, n0 = blockIdx.x * BN;
  float acc[8][8] = {};
  gemm_core(bands.p[band], W, m0, n0, D_, acc);
  proj_epilogue(dst, bvec, m0, n0, acc);
}

// ---- L2 normalization + bf16 emission (same f2bf_rne bits) ------------------
__global__ __launch_bounds__(256) void l2norm_rows(float* __restrict__ X,
                                                   ushort* __restrict__ bf) {
  const long row = (long)blockIdx.x * 4 + (threadIdx.x >> 6);
  const int lane = threadIdx.x & 63;
  float* p = X + row * D_;
  float4 a = ((float4*)p)[lane];
  float4 b = ((float4*)p)[lane + 64];
  float s = a.x * a.x + a.y * a.y + a.z * a.z + a.w * a.w +
            b.x * b.x + b.y * b.y + b.z * b.z + b.w * b.w;
#pragma unroll
  for (int m = 1; m < 64; m <<= 1) s += __shfl_xor(s, m);
  const float inv = 1.0f / fmaxf(sqrtf(s), 1e-12f);
  a.x *= inv; a.y *= inv; a.z *= inv; a.w *= inv;
  b.x *= inv; b.y *= inv; b.z *= inv; b.w *= inv;
  ((float4*)p)[lane] = a;
  ((float4*)p)[lane + 64] = b;
  ushort4 w0, w1;
  w0.x = f2bf_rne(a.x); w0.y = f2bf_rne(a.y); w0.z = f2bf_rne(a.z); w0.w = f2bf_rne(a.w);
  w1.x = f2bf_rne(b.x); w1.y = f2bf_rne(b.y); w1.z = f2bf_rne(b.z); w1.w = f2bf_rne(b.w);
  *(ushort4*)(bf + row * D_ + lane * 4) = w0;
  *(ushort4*)(bf + row * D_ + 256 + lane * 4) = w1;
}

// ---------------------------------------------------------------------------
// STAGE 1: bf16 MFMA approx scores + per-tile top-8. R15 change: COALESCED
// staging. LDS granule (row, oct) at g = row*4 + (oct ^ ((row>>1)&3)):
//  - GLOAD16 lanes = 16 rows x 4 consecutive granules -> each 4-lane group
//    reads one contiguous 64B line of a row (16 lines/instr, was 64).
//  - fragment ds_read_b128 banks: quad = (4*row + oct') mod 8 -> 2-way (free).
// Same bf16 values -> same MFMAs -> bit-identical candidates.
// 3-buffer counted-vmcnt pipeline + raw barriers kept from R14.
// ---------------------------------------------------------------------------
#define SBM 128
#define SBN 128

__device__ __forceinline__ int gidx(int row, int oct) {
  return row * 4 + (oct ^ ((row >> 1) & 3));
}

__global__ __launch_bounds__(256) void mfma_extract_bf(const ushort* __restrict__ Qbf,
                                                       const ushort* __restrict__ Kbf,
                                                       float* __restrict__ candv,
                                                       ushort* __restrict__ candi,
                                                       CallTab tab) {
  __shared__ ushort ldsA[3][4096];   // 512 granules x 8 ushorts = 8KB per buf
  __shared__ ushort ldsB[3][4096];

  const int z = blockIdx.z;
  const int c = z >> 3, b = z & 7;
  const ushort* A = Qbf + (long)tab.qi[c] * BAND_ELEMS + (long)b * N_ * D_;
  const ushort* Bm = Kbf + (long)tab.ki[c] * BAND_ELEMS + (long)b * N_ * D_;
  const int m0 = blockIdx.y * SBM, n0 = blockIdx.x * SBN;

  const int t = threadIdx.x;
  const int lane = t & 63;
  const int wm = t >> 6;
  const int fr = lane & 15, fh = lane >> 4;

  f32x4 acc[2][8] = {};

  // staging geometry: wave wm, it_ covers rows row0..row0+15 (one GLOAD16
  // per operand = 64 granules = 16 rows); per-lane source is coalesced 64B.
  const int srow_off = lane >> 2;               // row within 16-row group
  const int soct = lane & 3;                    // granule slot within row

#define XSTAGE(pA, pB, k0)                                                    \
  do {                                                                        \
    _Pragma("unroll")                                                         \
    for (int it_ = 0; it_ < 2; ++it_) {                                       \
      const int row0_ = wm * 32 + it_ * 16;                                   \
      const int row_ = row0_ + srow_off;                                      \
      const int oct_ = soct ^ ((row_ >> 1) & 3);                              \
      GLOAD16(A + (long)(m0 + row_) * D_ + (k0) + oct_ * 8,                   \
              (pA) + row0_ * 32);                                             \
      GLOAD16(Bm + (long)(n0 + row_) * D_ + (k0) + oct_ * 8,                  \
              (pB) + row0_ * 32);                                             \
    }                                                                         \
  } while (0)

  ushort* pA0 = &ldsA[0][0]; ushort* pB0 = &ldsB[0][0];
  ushort* pA1 = &ldsA[1][0]; ushort* pB1 = &ldsB[1][0];
  ushort* pA2 = &ldsA[2][0]; ushort* pB2 = &ldsB[2][0];

  // prologue: stage k-chunks 0 and 1 (4 wave-loads each -> 8 outstanding)
  XSTAGE(pA0, pB0, 0);
  XSTAGE(pA1, pB1, 32);

  for (int kq = 0; kq < 16; ++kq) {
    if (kq + 2 < 16) {
      XSTAGE(pA2, pB2, (kq + 2) * 32);
      asm volatile("s_waitcnt vmcnt(8)" ::: "memory");   // buf kq landed
    } else if (kq + 1 < 16) {
      asm volatile("s_waitcnt vmcnt(4)" ::: "memory");
    } else {
      asm volatile("s_waitcnt vmcnt(0)" ::: "memory");
    }
    __builtin_amdgcn_sched_barrier(0);
    __builtin_amdgcn_s_barrier();                // all waves: buf kq ready
    __builtin_amdgcn_sched_barrier(0);

    bf16x8 af[2], bfr[8];
#pragma unroll
    for (int i = 0; i < 2; ++i) {
      const int row = wm * 32 + i * 16 + fr;
      af[i] = *(const bf16x8*)&pA0[gidx(row, fh) * 8];
    }
#pragma unroll
    for (int j = 0; j < 8; ++j) {
      const int row = j * 16 + fr;
      bfr[j] = *(const bf16x8*)&pB0[gidx(row, fh) * 8];
    }

#pragma unroll
    for (int i = 0; i < 2; ++i)
#pragma unroll
      for (int j = 0; j < 8; ++j)
        acc[i][j] = __builtin_amdgcn_mfma_f32_16x16x32_bf16(af[i], bfr[j], acc[i][j], 0, 0, 0);

    __builtin_amdgcn_sched_barrier(0);
    __builtin_amdgcn_s_barrier();                // all waves done reading buf kq
    __builtin_amdgcn_sched_barrier(0);

    ushort* ta = pA0; pA0 = pA1; pA1 = pA2; pA2 = ta;
    ushort* tb = pB0; pB0 = pB1; pB1 = pB2; pB2 = tb;
  }
#undef XSTAGE

  // ---- per-tile top-8 extraction (VERBATIM R7) ----
#pragma unroll
  for (int i = 0; i < 2; ++i)
#pragma unroll
    for (int rr = 0; rr < 4; ++rr) {
      const int R = b * N_ + m0 + wm * 32 + i * 16 + fh * 4 + rr;
      const long base = (((long)c * 8192 + R) * 8 + blockIdx.x) * 8;
#pragma unroll
      for (int it = 0; it < 8; ++it) {
        float lv = acc[i][0][rr]; int lj = 0;
#pragma unroll
        for (int j = 1; j < 8; ++j)
          if (acc[i][j][rr] > lv) { lv = acc[i][j][rr]; lj = j; }
        int li = lj * 16 + fr;
#pragma unroll
        for (int m = 1; m < 16; m <<= 1) {
          float ov = __shfl_xor(lv, m);
          int oi = __shfl_xor(li, m);
          if (ov > lv || (ov == lv && oi < li)) { lv = ov; li = oi; }
        }
        if (fr == it) { candv[base + it] = lv; candi[base + it] = (ushort)(n0 + li); }
        if (fr == (li & 15)) {
#pragma unroll
          for (int j = 0; j < 8; ++j)
            if (j == (li >> 4)) acc[i][j][rr] = -INFINITY;
        }
      }
    }
}

// ---------------------------------------------------------------------------
// STAGE 2 (VERBATIM R11): exact fp32 chains, K/Q staged via global_load_lds.
// ---------------------------------------------------------------------------
#define RRBLOCKS (NCALLS * 8192 / 4)       // 38912 = 8 * 4864

__global__ __launch_bounds__(256) void rerank_exact(const float* __restrict__ Qn,
                                                    const float* __restrict__ Kn,
                                                    const float* __restrict__ candv,
                                                    const ushort* __restrict__ candi,
                                                    float* __restrict__ fp,
                                                    int* __restrict__ fi,
                                                    float* __restrict__ out,
                                                    CallTab tab) {
  __shared__ float sbuf[4][2][1088];

  const int bid = blockIdx.x;
  const int blk = (bid & 7) * (RRBLOCKS / 8) + (bid >> 3);

  const int w = threadIdx.x >> 6, lane = threadIdx.x & 63;
  const long gr = (long)blk * 4 + w;
  const int c = (int)(gr >> 13);
  const int R = (int)(gr & 8191);
  const int b = R >> 10;

  const long cb = gr * 64;
  float cv = candv[cb + lane];
  int ci = (int)candi[cb + lane];

  int myi = 0;
#pragma unroll
  for (int it = 0; it < 16; ++it) {
    float lv = cv; int gi = ci;
#pragma unroll
    for (int m = 1; m < 64; m <<= 1) {
      float ov = __shfl_xor(lv, m);
      int oi = __shfl_xor(gi, m);
      if (ov > lv || (ov == lv && oi < gi)) { lv = ov; gi = oi; }
    }
    if ((lane & 15) == it) myi = gi;
    if (ci == gi) cv = -INFINITY;
  }

  const int mycand = lane & 15;
  const int eidx = __shfl(myi, mycand);

  const float* qrow = Qn + (long)tab.qi[c] * BAND_ELEMS + (long)R * D_;
  const float* ksrc0 = Kn + (long)tab.ki[c] * BAND_ELEMS +
                       ((long)(b << 10) + eidx) * D_ + ((lane >> 4) << 2);

#define STAGE(bb, ch)                                                         \
  do {                                                                        \
    float* base_ = &sbuf[w][bb][0];                                           \
    GLOAD16(ksrc0 + (ch) * 64 + 0,  base_ + 0);                               \
    GLOAD16(ksrc0 + (ch) * 64 + 16, base_ + 256);                             \
    GLOAD16(ksrc0 + (ch) * 64 + 32, base_ + 512);                             \
    GLOAD16(ksrc0 + (ch) * 64 + 48, base_ + 768);                             \
    GLOAD4(qrow + (ch) * 64 + lane, base_ + 1024);                            \
  } while (0)

  float acc = 0.f;
  STAGE(0, 0);
#pragma unroll
  for (int ch = 0; ch < 8; ++ch) {
    if (ch < 7) {
      STAGE((ch + 1) & 1, ch + 1);
      asm volatile("s_waitcnt vmcnt(5)" ::: "memory");
    } else {
      asm volatile("s_waitcnt vmcnt(0)" ::: "memory");
    }
    const float* kb2 = &sbuf[w][ch & 1][0];
    const float* qb2 = &sbuf[w][ch & 1][1024];
#pragma unroll
    for (int kq = 0; kq < 16; ++kq) {
      float4 kv = *(const float4*)(kb2 + kq * 64 + mycand * 4);
      float4 qv = *(const float4*)(qb2 + kq * 4);
      acc = fmaf(qv.x, kv.x, acc);
      acc = fmaf(qv.y, kv.y, acc);
      acc = fmaf(qv.z, kv.z, acc);
      acc = fmaf(qv.w, kv.w, acc);
    }
  }
#undef STAGE

  float ev = acc; int ei = eidx;
  float sv[8]; int si[8];
#pragma unroll
  for (int it = 0; it < 8; ++it) {
    float lv = ev; int gi = ei;
#pragma unroll
    for (int m = 1; m < 64; m <<= 1) {
      float ov = __shfl_xor(lv, m);
      int oi = __shfl_xor(gi, m);
      if (ov > lv || (ov == lv && oi < gi)) { lv = ov; gi = oi; }
    }
    sv[it] = lv; si[it] = gi;
    if (ei == gi) ev = -INFINITY;
  }

  float p[8], sum = 0.f;
#pragma unroll
  for (int j = 0; j < 8; ++j) { p[j] = expf(sv[j] - sv[0]); sum += p[j]; }
  const float isum = 1.0f / sum;
  float H = 0.f;
#pragma unroll
  for (int j = 0; j < 8; ++j) { p[j] *= isum; H -= p[j] * logf(p[j] + 1e-9f); }

  if (lane == 0) {
    atomicAdd(out + OUT_MAIN + (long)c * B_ + b, H * (1.0f / (float)N_));
#pragma unroll
    for (int j = 0; j < 8; ++j) { fp[gr * 8 + j] = p[j]; fi[gr * 8 + j] = si[j]; }
  }
}

// ---- merge finals + PV + band add + out write (VERBATIM R7) -----------------
__global__ __launch_bounds__(256) void merge_pv(Ptrs8 bands,
                                                const float* __restrict__ fp,
                                                const int* __restrict__ fi,
                                                const float* __restrict__ V,
                                                float* __restrict__ out,
                                                MergeTab mt) {
  const int bb = blockIdx.y;
  const int w = threadIdx.x >> 6, lane = threadIdx.x & 63;
  const long R = (long)blockIdx.x * 4 + w;
  const int b = (int)(R >> 10);

  float4 o0 = {0, 0, 0, 0}, o1 = {0, 0, 0, 0};
  const int nc = mt.ncalls[bb];
  for (int s = 0; s < nc; ++s) {
    const int c = mt.calls[bb][s];
    const float wt = mt.wts[c];
    const int ki = mt.kis[c];
    const long fb = ((long)c * 8192 + R) * 8;
    float4 p0 = *(const float4*)(fp + fb);
    float4 p1 = *(const float4*)(fp + fb + 4);
    int4 i0 = *(const int4*)(fi + fb);
    int4 i1 = *(const int4*)(fi + fb + 4);
    float pj[8] = {p0.x, p0.y, p0.z, p0.w, p1.x, p1.y, p1.z, p1.w};
    int ij[8] = {i0.x, i0.y, i0.z, i0.w, i1.x, i1.y, i1.z, i1.w};
#pragma unroll
    for (int j = 0; j < 8; ++j) {
      const float pw = pj[j] * wt;
      const float4* vr = (const float4*)(V + (long)ki * BAND_ELEMS +
                                         ((long)(b << 10) + ij[j]) * D_);
      float4 x0 = vr[lane * 2], x1 = vr[lane * 2 + 1];
      o0.x += pw * x0.x; o0.y += pw * x0.y; o0.z += pw * x0.z; o0.w += pw * x0.w;
      o1.x += pw * x1.x; o1.y += pw * x1.y; o1.z += pw * x1.z; o1.w += pw * x1.w;
    }
  }

  const float4* src = (const float4*)(bands.p[bb] + R * D_);
  float4 s0 = src[lane * 2], s1 = src[lane * 2 + 1];
  s0.x += o0.x; s0.y += o0.y; s0.z += o0.z; s0.w += o0.w;
  s1.x += o1.x; s1.y += o1.y; s1.z += o1.z; s1.w += o1.w;
  float4* dst = (float4*)(out + (long)bb * BAND_ELEMS + R * D_);
  dst[lane * 2] = s0;
  dst[lane * 2 + 1] = s1;
}

// ---- zero the 152 entropy slots ---------------------------------------------
__global__ void init_eps(float* __restrict__ out) {
  if (threadIdx.x < NCALLS * B_) out[OUT_MAIN + threadIdx.x] = 0.f;
}

// --------------------------------------------------------------------------------
extern "C" void kernel_launch(void* const* d_in, const int* in_sizes, int n_in,
                              void* d_out, int out_size, void* d_ws, size_t ws_size,
                              hipStream_t stream) {
  Ptrs8 bands;
  for (int i = 0; i < 8; ++i) bands.p[i] = (const float*)d_in[i];
  const float* qW = (const float*)d_in[8];
  const float* qb = (const float*)d_in[9];
  const float* kW = (const float*)d_in[10];
  const float* kb = (const float*)d_in[11];
  const float* vW = (const float*)d_in[12];
  const float* vb = (const float*)d_in[13];
  float* out = (float*)d_out;
  float* ws = (float*)d_ws;

  float* Qn = ws;                                        // fp32, 134.2 MB
  float* Kn = ws + (long)8 * BAND_ELEMS;                 // fp32, 134.2 MB
  // OVERLAY region (134.2 MB): bf16 Q+K during l2norm->extract, then V fp32
  float* V = ws + (long)16 * BAND_ELEMS;
  ushort* bfbuf = (ushort*)V;
  float* candv = ws + (long)24 * BAND_ELEMS;             // 39.9 MB
  ushort* candi = (ushort*)(candv + (long)NCALLS * 8192 * 64);  // 19.9 MB
  float* fp = (float*)(candi + (long)NCALLS * 8192 * 64);       // 5 MB
  int* fi = (int*)(fp + (long)NCALLS * 8192 * 8);               // 5 MB

  static const int calls[NCALLS][2] = {
      {6, 0}, {0, 6}, {5, 1}, {1, 5}, {4, 2}, {2, 4},
      {0, 3}, {1, 3}, {2, 3}, {4, 3}, {5, 3}, {6, 3},
      {0, 7}, {1, 7}, {2, 7}, {3, 7}, {4, 7}, {5, 7}, {6, 7}};

  CallTab tab;
  MergeTab mt;
  for (int i = 0; i < 8; ++i) mt.ncalls[i] = 0;
  for (int c = 0; c < NCALLS; ++c) {
    tab.qi[c] = calls[c][0];
    tab.ki[c] = calls[c][1];
    mt.kis[c] = calls[c][1];
    mt.wts[c] = (c < 6) ? 1.0f : 0.5f;
    int q = calls[c][0];
    mt.calls[q][mt.ncalls[q]++] = c;
  }

  hipLaunchKernelGGL(init_eps, dim3(1), dim3(256), 0, stream, out);

  // 1) Q,K projections (V deferred — its slot holds bf16 for now)
  dim3 gqk(D_ / BN, (B_ * N_) / BM, 16);
  hipLaunchKernelGGL(gemm_proj_qk, gqk, dim3(256), 0, stream,
                     bands, qW, kW, qb, kb, Qn, Kn);

  // 2) l2norm Qn+Kn + bf16 emission into overlay
  hipLaunchKernelGGL(l2norm_rows, dim3(2 * 8 * B_ * N_ / 4), dim3(256), 0, stream,
                     Qn, bfbuf);

  // 3) approx scores + per-tile top-8 from bf16 (pipelined, coalesced)
  dim3 gs(N_ / SBN, N_ / SBM, NCALLS * 8);
  hipLaunchKernelGGL(mfma_extract_bf, gs, dim3(256), 0, stream,
                     bfbuf, bfbuf + (long)8 * BAND_ELEMS, candv, candi, tab);

  // 4) V projection — overwrites the bf16 overlay
  dim3 gv(D_ / BN, (B_ * N_) / BM, 8);
  hipLaunchKernelGGL(gemm_proj_v, gv, dim3(256), 0, stream, bands, vW, vb, V);

  // 5) exact rerank + 6) merge/PV
  hipLaunchKernelGGL(rerank_exact, dim3(RRBLOCKS), dim3(256), 0, stream,
                     Qn, Kn, candv, candi, fp, fi, out, tab);

  hipLaunchKernelGGL(merge_pv, dim3(B_ * N_ / 4, 8), dim3(256), 0, stream,
                     bands, fp, fi, V, out, mt);
}

// Round 16
// 3099.970 us; speedup vs baseline: 1.7740x; 1.1128x over previous
//
#include <hip/hip_runtime.h>
#include <math.h>

#define B_ 8
#define N_ 1024
#define D_ 512
#define BAND_ELEMS (B_ * N_ * D_)          // 4194304 = 2^22
#define OUT_MAIN (8L * BAND_ELEMS)         // 33554432
#define NCALLS 19

struct Ptrs8 { const float* p[8]; };
struct CallTab { int qi[NCALLS]; int ki[NCALLS]; };
struct MergeTab { int ncalls[8]; int calls[8][3]; int kis[NCALLS]; float wts[NCALLS]; };

typedef __attribute__((ext_vector_type(8))) short bf16x8;
typedef __attribute__((ext_vector_type(8))) ushort ushort8;
typedef __attribute__((ext_vector_type(4))) float f32x4;

__device__ __forceinline__ ushort f2bf_rne(float x) {
  uint u = __float_as_uint(x);
  return (ushort)((u + 0x7fffu + ((u >> 16) & 1u)) >> 16);
}
__device__ __forceinline__ float bf2f(ushort h) {
  return __uint_as_float(((uint)h) << 16);
}

#define GLOAD16(gsrc, ldst)                                                   \
  __builtin_amdgcn_global_load_lds(                                          \
      (const __attribute__((address_space(1))) void*)(gsrc),                 \
      (__attribute__((address_space(3))) void*)(ldst), 16, 0, 0)
#define GLOAD4(gsrc, ldst)                                                    \
  __builtin_amdgcn_global_load_lds(                                          \
      (const __attribute__((address_space(1))) void*)(gsrc),                 \
      (__attribute__((address_space(3))) void*)(ldst), 4, 0, 0)

// ---------------------------------------------------------------------------
// fp32 GEMM core (VERBATIM R5/R6 — bit-exact contract). Q/K projections only.
// ---------------------------------------------------------------------------
#define BM 128
#define BN 128
#define BK 16
#define LDP 132

__device__ __forceinline__ int bgran(int g) {
  return (g & ~7) | ((g + (g >> 3)) & 7);
}

__device__ __forceinline__ void gemm_core(const float* __restrict__ A,
                                          const float* __restrict__ Bm,
                                          int m0, int n0, int K,
                                          float (&acc)[8][8]) {
  __shared__ float As[BK * LDP];
  __shared__ float Bs[BK * LDP];

  const int t = threadIdx.x;
  const int tx = t & 15, ty = t >> 4;
  const int rs = t >> 2;
  const int cs = t & 3;

  float4 pa[2], pb[2];
#pragma unroll
  for (int it = 0; it < 2; ++it) {
    pa[it] = *(const float4*)(A + (long)(m0 + rs + 64 * it) * K + cs * 4);
    pb[it] = *(const float4*)(Bm + (long)(n0 + rs + 64 * it) * K + cs * 4);
  }

  for (int k0 = 0; k0 < K; k0 += BK) {
    __syncthreads();
    {
      const int sa = ((cs & 1) << 2);
      const int base = cs * 4 * LDP;
#pragma unroll
      for (int it = 0; it < 2; ++it) {
        const int r = rs + 64 * it;
        const int ra = r ^ sa;
        As[base + 0 * LDP + ra] = pa[it].x;
        As[base + 1 * LDP + ra] = pa[it].y;
        As[base + 2 * LDP + ra] = pa[it].z;
        As[base + 3 * LDP + ra] = pa[it].w;
        const int rb = bgran(r >> 2) * 4 + (r & 3);
        Bs[base + 0 * LDP + rb] = pb[it].x;
        Bs[base + 1 * LDP + rb] = pb[it].y;
        Bs[base + 2 * LDP + rb] = pb[it].z;
        Bs[base + 3 * LDP + rb] = pb[it].w;
      }
    }
    __syncthreads();

    if (k0 + BK < K) {
#pragma unroll
      for (int it = 0; it < 2; ++it) {
        pa[it] = *(const float4*)(A + (long)(m0 + rs + 64 * it) * K + k0 + BK + cs * 4);
        pb[it] = *(const float4*)(Bm + (long)(n0 + rs + 64 * it) * K + k0 + BK + cs * 4);
      }
    }

#pragma unroll
    for (int kk = 0; kk < BK; ++kk) {
      const int c1 = (kk >> 2) & 1;
      float a[8], b[8];
      {
        float4 u = *(const float4*)&As[kk * LDP + ty * 8 + c1 * 4];
        float4 v = *(const float4*)&As[kk * LDP + ty * 8 + 4 - c1 * 4];
        a[0] = u.x; a[1] = u.y; a[2] = u.z; a[3] = u.w;
        a[4] = v.x; a[5] = v.y; a[6] = v.z; a[7] = v.w;
        float4 p = *(const float4*)&Bs[kk * LDP + bgran(2 * tx) * 4];
        float4 q = *(const float4*)&Bs[kk * LDP + bgran(2 * tx + 1) * 4];
        b[0] = p.x; b[1] = p.y; b[2] = p.z; b[3] = p.w;
        b[4] = q.x; b[5] = q.y; b[6] = q.z; b[7] = q.w;
      }
#pragma unroll
      for (int i = 0; i < 8; ++i)
#pragma unroll
        for (int j = 0; j < 8; ++j) acc[i][j] = fmaf(a[i], b[j], acc[i][j]);
    }
  }
}

__device__ __forceinline__ void proj_epilogue(float* __restrict__ dst,
                                              const float* __restrict__ bvec,
                                              int m0, int n0, float (&acc)[8][8]) {
  const int t = threadIdx.x;
  const int tx = t & 15, ty = t >> 4;
#pragma unroll
  for (int i = 0; i < 8; ++i) {
    float* crow = dst + (long)(m0 + ty * 8 + i) * D_ + n0 + tx * 8;
    const float* bp = bvec + n0 + tx * 8;
    float4 r0, r1;
    r0.x = acc[i][0] + bp[0]; r0.y = acc[i][1] + bp[1];
    r0.z = acc[i][2] + bp[2]; r0.w = acc[i][3] + bp[3];
    r1.x = acc[i][4] + bp[4]; r1.y = acc[i][5] + bp[5];
    r1.z = acc[i][6] + bp[6]; r1.w = acc[i][7] + bp[7];
    ((float4*)crow)[0] = r0;
    ((float4*)crow)[1] = r1;
  }
}

// ---- Q,K projections: z = mat*8 + band, mat in {0,1} (VERBATIM R13) --------
__global__ __launch_bounds__(256) void gemm_proj_qk(Ptrs8 bands,
                                                    const float* __restrict__ qW,
                                                    const float* __restrict__ kW,
                                                    const float* __restrict__ qb,
                                                    const float* __restrict__ kb,
                                                    float* __restrict__ Qn,
                                                    float* __restrict__ Kn) {
  const int mat = blockIdx.z >> 3, band = blockIdx.z & 7;
  const float* W = (mat == 0) ? qW : kW;
  const float* bvec = (mat == 0) ? qb : kb;
  float* dst = ((mat == 0) ? Qn : Kn) + (long)band * BAND_ELEMS;
  W += (long)band * D_ * D_;
  bvec += band * D_;

  const int m0 = blockIdx.y * BM, n0 = blockIdx.x * BN;
  float acc[8][8] = {};
  gemm_core(bands.p[band], W, m0, n0, D_, acc);
  proj_epilogue(dst, bvec, m0, n0, acc);
}

// ---------------------------------------------------------------------------
// V projection via bf16 split-2 MFMA (R2-validated body): x = hi + lo,
// acc += Ah*Bh + Ah*Bl + Al*Bh. Error ~1e-5 relative — V is value-only
// (never affects selection), tolerance 0.119. ~3x faster than fp32 VALU.
// ---------------------------------------------------------------------------
__global__ __launch_bounds__(256) void gemm_proj_v_mfma(Ptrs8 bands,
                                                        const float* __restrict__ vW,
                                                        const float* __restrict__ vb,
                                                        float* __restrict__ V) {
  __shared__ ushort plds[4 * 4096];   // planes: Ah, Bh, Al, Bl

  const int band = blockIdx.z;
  const uint* Au = (const uint*)bands.p[band];
  const uint* Bu = (const uint*)(vW + (long)band * D_ * D_);
  const float* bvec = vb + band * D_;
  float* dst = V + (long)band * BAND_ELEMS;

  const int t = threadIdx.x;
  const int lane = t & 63;
  const int wave = t >> 6;
  const int wm = wave >> 1, wn = wave & 1;
  const int fr = lane & 15, fh = lane >> 4;
  const int m0 = blockIdx.y * BM, n0 = blockIdx.x * BN;

  f32x4 acc[4][4] = {};

  const int sg_r[2] = {t >> 2, (t + 256) >> 2};
  const int sg_h = t & 3;

  for (int k0 = 0; k0 < D_; k0 += 32) {
    uint4 ga[2][2], gb[2][2];
#pragma unroll
    for (int it = 0; it < 2; ++it) {
      long offA = (long)(m0 + sg_r[it]) * D_ + k0 + sg_h * 8;
      ga[it][0] = *(const uint4*)(Au + offA);
      ga[it][1] = *(const uint4*)(Au + offA + 4);
      long offB = (long)(n0 + sg_r[it]) * D_ + k0 + sg_h * 8;
      gb[it][0] = *(const uint4*)(Bu + offB);
      gb[it][1] = *(const uint4*)(Bu + offB + 4);
    }
    __syncthreads();
#pragma unroll
    for (int op = 0; op < 2; ++op) {
#pragma unroll
      for (int it = 0; it < 2; ++it) {
        uint w[8];
        {
          uint4 w0 = op ? gb[it][0] : ga[it][0];
          uint4 w1 = op ? gb[it][1] : ga[it][1];
          w[0] = w0.x; w[1] = w0.y; w[2] = w0.z; w[3] = w0.w;
          w[4] = w1.x; w[5] = w1.y; w[6] = w1.z; w[7] = w1.w;
        }
        ushort8 vhi, vlo;
#pragma unroll
        for (int e = 0; e < 8; ++e) {
          float x = __uint_as_float(w[e]);
          ushort hb = f2bf_rne(x);
          ushort lb = f2bf_rne(x - bf2f(hb));
          vhi[e] = hb;
          vlo[e] = lb;
        }
        const int ds2 = (sg_h * 128 + sg_r[it]) * 8;
        *(ushort8*)&plds[op * 4096 + ds2] = vhi;
        *(ushort8*)&plds[(2 + op) * 4096 + ds2] = vlo;
      }
    }
    __syncthreads();

    bf16x8 ah[4], bh[4], al[4], bl[4];
#pragma unroll
    for (int i = 0; i < 4; ++i) {
      const int ra = wm * 64 + i * 16 + fr;
      const int rb = wn * 64 + i * 16 + fr;
      ah[i] = *(const bf16x8*)&plds[0 * 4096 + (fh * 128 + ra) * 8];
      bh[i] = *(const bf16x8*)&plds[1 * 4096 + (fh * 128 + rb) * 8];
      al[i] = *(const bf16x8*)&plds[2 * 4096 + (fh * 128 + ra) * 8];
      bl[i] = *(const bf16x8*)&plds[3 * 4096 + (fh * 128 + rb) * 8];
    }

#pragma unroll
    for (int i = 0; i < 4; ++i)
#pragma unroll
      for (int j = 0; j < 4; ++j) {
        acc[i][j] = __builtin_amdgcn_mfma_f32_16x16x32_bf16(ah[i], bh[j], acc[i][j], 0, 0, 0);
        acc[i][j] = __builtin_amdgcn_mfma_f32_16x16x32_bf16(ah[i], bl[j], acc[i][j], 0, 0, 0);
        acc[i][j] = __builtin_amdgcn_mfma_f32_16x16x32_bf16(al[i], bh[j], acc[i][j], 0, 0, 0);
      }
  }

  // epilogue: col = lane&15, row = (lane>>4)*4 + reg (R2-validated)
#pragma unroll
  for (int i = 0; i < 4; ++i)
#pragma unroll
    for (int j = 0; j < 4; ++j) {
      const int col = n0 + wn * 64 + j * 16 + fr;
      const float bv = bvec[col];
#pragma unroll
      for (int r = 0; r < 4; ++r) {
        const int row = m0 + wm * 64 + i * 16 + fh * 4 + r;
        dst[(long)row * D_ + col] = acc[i][j][r] + bv;
      }
    }
}

// ---- L2 normalization + bf16 emission (VERBATIM R13) ------------------------
__global__ __launch_bounds__(256) void l2norm_rows(float* __restrict__ X,
                                                   ushort* __restrict__ bf) {
  const long row = (long)blockIdx.x * 4 + (threadIdx.x >> 6);
  const int lane = threadIdx.x & 63;
  float* p = X + row * D_;
  float4 a = ((float4*)p)[lane];
  float4 b = ((float4*)p)[lane + 64];
  float s = a.x * a.x + a.y * a.y + a.z * a.z + a.w * a.w +
            b.x * b.x + b.y * b.y + b.z * b.z + b.w * b.w;
#pragma unroll
  for (int m = 1; m < 64; m <<= 1) s += __shfl_xor(s, m);
  const float inv = 1.0f / fmaxf(sqrtf(s), 1e-12f);
  a.x *= inv; a.y *= inv; a.z *= inv; a.w *= inv;
  b.x *= inv; b.y *= inv; b.z *= inv; b.w *= inv;
  ((float4*)p)[lane] = a;
  ((float4*)p)[lane + 64] = b;
  ushort4 w0, w1;
  w0.x = f2bf_rne(a.x); w0.y = f2bf_rne(a.y); w0.z = f2bf_rne(a.z); w0.w = f2bf_rne(a.w);
  w1.x = f2bf_rne(b.x); w1.y = f2bf_rne(b.y); w1.z = f2bf_rne(b.z); w1.w = f2bf_rne(b.w);
  *(ushort4*)(bf + row * D_ + lane * 4) = w0;
  *(ushort4*)(bf + row * D_ + 256 + lane * 4) = w1;
}

// ---------------------------------------------------------------------------
// STAGE 1: bf16 MFMA approx scores + per-tile top-8. R16: 4-buffer fully
// unrolled pipeline — buffer index & k-offset are compile-time literals, all
// LDS/global addresses hoisted to loop-invariant bases. Same loads, same
// granule map (R15), same MFMAs, VERBATIM extraction -> bit-identical output.
// vmcnt: stage kq+3; 3 stages (12 loads) in flight -> vmcnt(12); tail 8/4/0.
// ---------------------------------------------------------------------------
#define SBM 128
#define SBN 128

__device__ __forceinline__ int gidx(int row, int oct) {
  return row * 4 + (oct ^ ((row >> 1) & 3));
}

__global__ __launch_bounds__(256) void mfma_extract_bf(const ushort* __restrict__ Qbf,
                                                       const ushort* __restrict__ Kbf,
                                                       float* __restrict__ candv,
                                                       ushort* __restrict__ candi,
                                                       CallTab tab) {
  __shared__ ushort lds[4][2][4096];   // [buf][A/B][granule*8]  = 64 KB

  const int z = blockIdx.z;
  const int c = z >> 3, b = z & 7;
  const ushort* A = Qbf + (long)tab.qi[c] * BAND_ELEMS + (long)b * N_ * D_;
  const ushort* Bm = Kbf + (long)tab.ki[c] * BAND_ELEMS + (long)b * N_ * D_;
  const int m0 = blockIdx.y * SBM, n0 = blockIdx.x * SBN;

  const int t = threadIdx.x;
  const int lane = t & 63;
  const int wm = t >> 6;
  const int fr = lane & 15, fh = lane >> 4;

  f32x4 acc[2][8] = {};

  // hoisted staging bases (per-lane coalesced source, wave-uniform dest)
  const int srow = lane >> 2;
  const int soct = lane & 3;
  const ushort* sA[2];
  const ushort* sB[2];
  int dof[2];
#pragma unroll
  for (int it = 0; it < 2; ++it) {
    const int row0 = wm * 32 + it * 16;
    const int row = row0 + srow;
    const int oct = soct ^ ((row >> 1) & 3);
    sA[it] = A + (long)(m0 + row) * D_ + oct * 8;
    sB[it] = Bm + (long)(n0 + row) * D_ + oct * 8;
    dof[it] = row0 * 32;                 // ushort offset within a plane
  }

  // hoisted fragment granule offsets (loop-invariant)
  int gofA[2], gofB[8];
#pragma unroll
  for (int i = 0; i < 2; ++i) gofA[i] = gidx(wm * 32 + i * 16 + fr, fh) * 8;
#pragma unroll
  for (int j = 0; j < 8; ++j) gofB[j] = gidx(j * 16 + fr, fh) * 8;

  ushort* lb = &lds[0][0][0];

#define XSTAGE(buf, m)                                                        \
  do {                                                                        \
    GLOAD16(sA[0] + (m) * 32, lb + ((buf) * 2 + 0) * 4096 + dof[0]);          \
    GLOAD16(sB[0] + (m) * 32, lb + ((buf) * 2 + 1) * 4096 + dof[0]);          \
    GLOAD16(sA[1] + (m) * 32, lb + ((buf) * 2 + 0) * 4096 + dof[1]);          \
    GLOAD16(sB[1] + (m) * 32, lb + ((buf) * 2 + 1) * 4096 + dof[1]);          \
  } while (0)

  XSTAGE(0, 0);
  XSTAGE(1, 1);
  XSTAGE(2, 2);

#pragma unroll
  for (int ot = 0; ot < 4; ++ot) {
#pragma unroll
    for (int ph = 0; ph < 4; ++ph) {
      const int kq = ot * 4 + ph;        // compile-time after unroll
      if (kq < 13) {
        XSTAGE((ph + 3) & 3, kq + 3);
        asm volatile("s_waitcnt vmcnt(12)" ::: "memory");
      } else if (kq == 13) {
        asm volatile("s_waitcnt vmcnt(8)" ::: "memory");
      } else if (kq == 14) {
        asm volatile("s_waitcnt vmcnt(4)" ::: "memory");
      } else {
        asm volatile("s_waitcnt vmcnt(0)" ::: "memory");
      }
      __builtin_amdgcn_sched_barrier(0);
      __builtin_amdgcn_s_barrier();                // buf kq ready (all waves)
      __builtin_amdgcn_sched_barrier(0);

      bf16x8 af[2], bfr[8];
#pragma unroll
      for (int i = 0; i < 2; ++i)
        af[i] = *(const bf16x8*)(lb + (ph * 2 + 0) * 4096 + gofA[i]);
#pragma unroll
      for (int j = 0; j < 8; ++j)
        bfr[j] = *(const bf16x8*)(lb + (ph * 2 + 1) * 4096 + gofB[j]);

#pragma unroll
      for (int i = 0; i < 2; ++i)
#pragma unroll
        for (int j = 0; j < 8; ++j)
          acc[i][j] = __builtin_amdgcn_mfma_f32_16x16x32_bf16(af[i], bfr[j], acc[i][j], 0, 0, 0);

      __builtin_amdgcn_sched_barrier(0);
      __builtin_amdgcn_s_barrier();                // all waves done with buf kq
      __builtin_amdgcn_sched_barrier(0);
    }
  }
#undef XSTAGE

  // ---- per-tile top-8 extraction (VERBATIM R7) ----
#pragma unroll
  for (int i = 0; i < 2; ++i)
#pragma unroll
    for (int rr = 0; rr < 4; ++rr) {
      const int R = b * N_ + m0 + wm * 32 + i * 16 + fh * 4 + rr;
      const long base = (((long)c * 8192 + R) * 8 + blockIdx.x) * 8;
#pragma unroll
      for (int it = 0; it < 8; ++it) {
        float lv = acc[i][0][rr]; int lj = 0;
#pragma unroll
        for (int j = 1; j < 8; ++j)
          if (acc[i][j][rr] > lv) { lv = acc[i][j][rr]; lj = j; }
        int li = lj * 16 + fr;
#pragma unroll
        for (int m = 1; m < 16; m <<= 1) {
          float ov = __shfl_xor(lv, m);
          int oi = __shfl_xor(li, m);
          if (ov > lv || (ov == lv && oi < li)) { lv = ov; li = oi; }
        }
        if (fr == it) { candv[base + it] = lv; candi[base + it] = (ushort)(n0 + li); }
        if (fr == (li & 15)) {
#pragma unroll
          for (int j = 0; j < 8; ++j)
            if (j == (li >> 4)) acc[i][j][rr] = -INFINITY;
        }
      }
    }
}

// ---------------------------------------------------------------------------
// STAGE 2 (VERBATIM R11): exact fp32 chains, K/Q staged via global_load_lds.
// ---------------------------------------------------------------------------
#define RRBLOCKS (NCALLS * 8192 / 4)       // 38912 = 8 * 4864

__global__ __launch_bounds__(256) void rerank_exact(const float* __restrict__ Qn,
                                                    const float* __restrict__ Kn,
                                                    const float* __restrict__ candv,
                                                    const ushort* __restrict__ candi,
                                                    float* __restrict__ fp,
                                                    int* __restrict__ fi,
                                                    float* __restrict__ out,
                                                    CallTab tab) {
  __shared__ float sbuf[4][2][1088];

  const int bid = blockIdx.x;
  const int blk = (bid & 7) * (RRBLOCKS / 8) + (bid >> 3);

  const int w = threadIdx.x >> 6, lane = threadIdx.x & 63;
  const long gr = (long)blk * 4 + w;
  const int c = (int)(gr >> 13);
  const int R = (int)(gr & 8191);
  const int b = R >> 10;

  const long cb = gr * 64;
  float cv = candv[cb + lane];
  int ci = (int)candi[cb + lane];

  int myi = 0;
#pragma unroll
  for (int it = 0; it < 16; ++it) {
    float lv = cv; int gi = ci;
#pragma unroll
    for (int m = 1; m < 64; m <<= 1) {
      float ov = __shfl_xor(lv, m);
      int oi = __shfl_xor(gi, m);
      if (ov > lv || (ov == lv && oi < gi)) { lv = ov; gi = oi; }
    }
    if ((lane & 15) == it) myi = gi;
    if (ci == gi) cv = -INFINITY;
  }

  const int mycand = lane & 15;
  const int eidx = __shfl(myi, mycand);

  const float* qrow = Qn + (long)tab.qi[c] * BAND_ELEMS + (long)R * D_;
  const float* ksrc0 = Kn + (long)tab.ki[c] * BAND_ELEMS +
                       ((long)(b << 10) + eidx) * D_ + ((lane >> 4) << 2);

#define STAGE(bb, ch)                                                         \
  do {                                                                        \
    float* base_ = &sbuf[w][bb][0];                                           \
    GLOAD16(ksrc0 + (ch) * 64 + 0,  base_ + 0);                               \
    GLOAD16(ksrc0 + (ch) * 64 + 16, base_ + 256);                             \
    GLOAD16(ksrc0 + (ch) * 64 + 32, base_ + 512);                             \
    GLOAD16(ksrc0 + (ch) * 64 + 48, base_ + 768);                             \
    GLOAD4(qrow + (ch) * 64 + lane, base_ + 1024);                            \
  } while (0)

  float acc = 0.f;
  STAGE(0, 0);
#pragma unroll
  for (int ch = 0; ch < 8; ++ch) {
    if (ch < 7) {
      STAGE((ch + 1) & 1, ch + 1);
      asm volatile("s_waitcnt vmcnt(5)" ::: "memory");
    } else {
      asm volatile("s_waitcnt vmcnt(0)" ::: "memory");
    }
    const float* kb2 = &sbuf[w][ch & 1][0];
    const float* qb2 = &sbuf[w][ch & 1][1024];
#pragma unroll
    for (int kq = 0; kq < 16; ++kq) {
      float4 kv = *(const float4*)(kb2 + kq * 64 + mycand * 4);
      float4 qv = *(const float4*)(qb2 + kq * 4);
      acc = fmaf(qv.x, kv.x, acc);
      acc = fmaf(qv.y, kv.y, acc);
      acc = fmaf(qv.z, kv.z, acc);
      acc = fmaf(qv.w, kv.w, acc);
    }
  }
#undef STAGE

  float ev = acc; int ei = eidx;
  float sv[8]; int si[8];
#pragma unroll
  for (int it = 0; it < 8; ++it) {
    float lv = ev; int gi = ei;
#pragma unroll
    for (int m = 1; m < 64; m <<= 1) {
      float ov = __shfl_xor(lv, m);
      int oi = __shfl_xor(gi, m);
      if (ov > lv || (ov == lv && oi < gi)) { lv = ov; gi = oi; }
    }
    sv[it] = lv; si[it] = gi;
    if (ei == gi) ev = -INFINITY;
  }

  float p[8], sum = 0.f;
#pragma unroll
  for (int j = 0; j < 8; ++j) { p[j] = expf(sv[j] - sv[0]); sum += p[j]; }
  const float isum = 1.0f / sum;
  float H = 0.f;
#pragma unroll
  for (int j = 0; j < 8; ++j) { p[j] *= isum; H -= p[j] * logf(p[j] + 1e-9f); }

  if (lane == 0) {
    atomicAdd(out + OUT_MAIN + (long)c * B_ + b, H * (1.0f / (float)N_));
#pragma unroll
    for (int j = 0; j < 8; ++j) { fp[gr * 8 + j] = p[j]; fi[gr * 8 + j] = si[j]; }
  }
}

// ---- merge finals + PV + band add + out write (VERBATIM R7) -----------------
__global__ __launch_bounds__(256) void merge_pv(Ptrs8 bands,
                                                const float* __restrict__ fp,
                                                const int* __restrict__ fi,
                                                const float* __restrict__ V,
                                                float* __restrict__ out,
                                                MergeTab mt) {
  const int bb = blockIdx.y;
  const int w = threadIdx.x >> 6, lane = threadIdx.x & 63;
  const long R = (long)blockIdx.x * 4 + w;
  const int b = (int)(R >> 10);

  float4 o0 = {0, 0, 0, 0}, o1 = {0, 0, 0, 0};
  const int nc = mt.ncalls[bb];
  for (int s = 0; s < nc; ++s) {
    const int c = mt.calls[bb][s];
    const float wt = mt.wts[c];
    const int ki = mt.kis[c];
    const long fb = ((long)c * 8192 + R) * 8;
    float4 p0 = *(const float4*)(fp + fb);
    float4 p1 = *(const float4*)(fp + fb + 4);
    int4 i0 = *(const int4*)(fi + fb);
    int4 i1 = *(const int4*)(fi + fb + 4);
    float pj[8] = {p0.x, p0.y, p0.z, p0.w, p1.x, p1.y, p1.z, p1.w};
    int ij[8] = {i0.x, i0.y, i0.z, i0.w, i1.x, i1.y, i1.z, i1.w};
#pragma unroll
    for (int j = 0; j < 8; ++j) {
      const float pw = pj[j] * wt;
      const float4* vr = (const float4*)(V + (long)ki * BAND_ELEMS +
                                         ((long)(b << 10) + ij[j]) * D_);
      float4 x0 = vr[lane * 2], x1 = vr[lane * 2 + 1];
      o0.x += pw * x0.x; o0.y += pw * x0.y; o0.z += pw * x0.z; o0.w += pw * x0.w;
      o1.x += pw * x1.x; o1.y += pw * x1.y; o1.z += pw * x1.z; o1.w += pw * x1.w;
    }
  }

  const float4* src = (const float4*)(bands.p[bb] + R * D_);
  float4 s0 = src[lane * 2], s1 = src[lane * 2 + 1];
  s0.x += o0.x; s0.y += o0.y; s0.z += o0.z; s0.w += o0.w;
  s1.x += o1.x; s1.y += o1.y; s1.z += o1.z; s1.w += o1.w;
  float4* dst = (float4*)(out + (long)bb * BAND_ELEMS + R * D_);
  dst[lane * 2] = s0;
  dst[lane * 2 + 1] = s1;
}

// ---- zero the 152 entropy slots ---------------------------------------------
__global__ void init_eps(float* __restrict__ out) {
  if (threadIdx.x < NCALLS * B_) out[OUT_MAIN + threadIdx.x] = 0.f;
}

// --------------------------------------------------------------------------------
extern "C" void kernel_launch(void* const* d_in, const int* in_sizes, int n_in,
                              void* d_out, int out_size, void* d_ws, size_t ws_size,
                              hipStream_t stream) {
  Ptrs8 bands;
  for (int i = 0; i < 8; ++i) bands.p[i] = (const float*)d_in[i];
  const float* qW = (const float*)d_in[8];
  const float* qb = (const float*)d_in[9];
  const float* kW = (const float*)d_in[10];
  const float* kb = (const float*)d_in[11];
  const float* vW = (const float*)d_in[12];
  const float* vb = (const float*)d_in[13];
  float* out = (float*)d_out;
  float* ws = (float*)d_ws;

  float* Qn = ws;                                        // fp32, 134.2 MB
  float* Kn = ws + (long)8 * BAND_ELEMS;                 // fp32, 134.2 MB
  // OVERLAY region (134.2 MB): bf16 Q+K during l2norm->extract, then V fp32
  float* V = ws + (long)16 * BAND_ELEMS;
  ushort* bfbuf = (ushort*)V;
  float* candv = ws + (long)24 * BAND_ELEMS;             // 39.9 MB
  ushort* candi = (ushort*)(candv + (long)NCALLS * 8192 * 64);  // 19.9 MB
  float* fp = (float*)(candi + (long)NCALLS * 8192 * 64);       // 5 MB
  int* fi = (int*)(fp + (long)NCALLS * 8192 * 8);               // 5 MB

  static const int calls[NCALLS][2] = {
      {6, 0}, {0, 6}, {5, 1}, {1, 5}, {4, 2}, {2, 4},
      {0, 3}, {1, 3}, {2, 3}, {4, 3}, {5, 3}, {6, 3},
      {0, 7}, {1, 7}, {2, 7}, {3, 7}, {4, 7}, {5, 7}, {6, 7}};

  CallTab tab;
  MergeTab mt;
  for (int i = 0; i < 8; ++i) mt.ncalls[i] = 0;
  for (int c = 0; c < NCALLS; ++c) {
    tab.qi[c] = calls[c][0];
    tab.ki[c] = calls[c][1];
    mt.kis[c] = calls[c][1];
    mt.wts[c] = (c < 6) ? 1.0f : 0.5f;
    int q = calls[c][0];
    mt.calls[q][mt.ncalls[q]++] = c;
  }

  hipLaunchKernelGGL(init_eps, dim3(1), dim3(256), 0, stream, out);

  // 1) Q,K projections (V deferred — its slot holds bf16 for now)
  dim3 gqk(D_ / BN, (B_ * N_) / BM, 16);
  hipLaunchKernelGGL(gemm_proj_qk, gqk, dim3(256), 0, stream,
                     bands, qW, kW, qb, kb, Qn, Kn);

  // 2) l2norm Qn+Kn + bf16 emission into overlay
  hipLaunchKernelGGL(l2norm_rows, dim3(2 * 8 * B_ * N_ / 4), dim3(256), 0, stream,
                     Qn, bfbuf);

  // 3) approx scores + per-tile top-8 from bf16 (4-buffer unrolled pipeline)
  dim3 gs(N_ / SBN, N_ / SBM, NCALLS * 8);
  hipLaunchKernelGGL(mfma_extract_bf, gs, dim3(256), 0, stream,
                     bfbuf, bfbuf + (long)8 * BAND_ELEMS, candv, candi, tab);

  // 4) V projection (bf16 split-2 MFMA) — overwrites the bf16 overlay
  dim3 gv(D_ / BN, (B_ * N_) / BM, 8);
  hipLaunchKernelGGL(gemm_proj_v_mfma, gv, dim3(256), 0, stream, bands, vW, vb, V);

  // 5) exact rerank + 6) merge/PV
  hipLaunchKernelGGL(rerank_exact, dim3(RRBLOCKS), dim3(256), 0, stream,
                     Qn, Kn, candv, candi, fp, fi, out, tab);

  hipLaunchKernelGGL(merge_pv, dim3(B_ * N_ / 4, 8), dim3(256), 0, stream,
                     bands, fp, fi, V, out, mt);
}